// Round 1
// baseline (4180.878 us; speedup 1.0000x reference)
//
#include <hip/hip_runtime.h>
#include <math.h>

// Problem constants
#define N0 80000
#define N1 40000
#define N2 20000
#define E1C 500000
#define E2C 250000
#define NTYPE 23
#define NTS 1158

// Workspace layout (float offsets)
#define OFF_Q1   0u            // N1*128
#define OFF_K1   5120000u      // N0*128
#define OFF_V1   15360000u     // N0*128
#define OFF_XR1  25600000u     // N1*128
#define OFF_OUT1 30720000u     // N1*128
#define OFF_EA1  35840000u     // E1*2
#define OFF_SUM1 36840000u     // N1*2
#define OFF_H    36920000u     // N1*128  (ends 42,040,000 floats = 168 MB)
// layer 2 overlays layer-1 temporaries (dead after node_epilogue1)
#define OFF_Q2   0u            // N2*128
#define OFF_K2   2560000u      // N1*128
#define OFF_V2   7680000u      // N1*128
#define OFF_XR2  12800000u     // N2*64
#define OFF_OUT2 14080000u     // N2*128
#define OFF_EA2  16640000u     // E2*2
#define OFF_SUM2 17140000u     // N2*2

// Y[row, col] = X[row,:128] . W[col,:128] + b[col]
__global__ void lin_kernel(const float* __restrict__ X, const float* __restrict__ W,
                           const float* __restrict__ b, float* __restrict__ Y,
                           int n, int kout) {
    int t = blockIdx.x * blockDim.x + threadIdx.x;
    if (t >= n * kout) return;
    int row = t / kout, col = t - row * kout;
    const float4* xr = (const float4*)(X + (size_t)row * 128);
    const float4* wr = (const float4*)(W + (size_t)col * 128);
    float acc = 0.f;
#pragma unroll
    for (int i = 0; i < 32; i++) {
        float4 a = xr[i];
        float4 w = wr[i];
        acc += a.x * w.x + a.y * w.y + a.z * w.z + a.w * w.w;
    }
    Y[t] = acc + b[col];
}

// per-lane edge-feature projection: e0 = e[lane], e1 = e[64+lane]
__device__ __forceinline__ void edge_proj(int t, int ts, int lane,
                                          const float* __restrict__ edge_W,
                                          const float* __restrict__ edge_b,
                                          const float* __restrict__ time_W,
                                          const float* __restrict__ time_b,
                                          const float* __restrict__ We,
                                          float& e0, float& e1) {
    e0 = 0.f; e1 = 0.f;
#pragma unroll
    for (int j = 0; j < 10; j++) {
        float fj = edge_W[j * NTYPE + t] + edge_b[j];
        e0 += We[lane * 20 + j] * fj;
        e1 += We[(lane + 64) * 20 + j] * fj;
    }
#pragma unroll
    for (int j = 0; j < 10; j++) {
        float fj = time_W[j * NTS + ts] + time_b[j];
        e0 += We[lane * 20 + 10 + j] * fj;
        e1 += We[(lane + 64) * 20 + 10 + j] * fj;
    }
}

// Pass A: alpha -> exp(alpha) and segment sums (one wave per edge)
__global__ void edge_alpha(const int* __restrict__ src, const int* __restrict__ dst,
                           const int* __restrict__ et, const int* __restrict__ ets,
                           const float* __restrict__ edge_W, const float* __restrict__ edge_b,
                           const float* __restrict__ time_W, const float* __restrict__ time_b,
                           const float* __restrict__ We,
                           const float* __restrict__ K, const float* __restrict__ Q,
                           float* __restrict__ exp_alpha, float* __restrict__ seg_sum,
                           int nedge) {
    int wid = (blockIdx.x * blockDim.x + threadIdx.x) >> 6;
    int lane = threadIdx.x & 63;
    if (wid >= nedge) return;
    int s = src[wid], d = dst[wid];
    float e0, e1;
    edge_proj(et[wid], ets[wid], lane, edge_W, edge_b, time_W, time_b, We, e0, e1);
    float p0 = Q[(size_t)d * 128 + lane]      * (K[(size_t)s * 128 + lane]      + e0);
    float p1 = Q[(size_t)d * 128 + 64 + lane] * (K[(size_t)s * 128 + 64 + lane] + e1);
#pragma unroll
    for (int off = 32; off; off >>= 1) {
        p0 += __shfl_down(p0, off);
        p1 += __shfl_down(p1, off);
    }
    if (lane == 0) {
        float a0 = expf(p0 * 0.125f);   // 1/sqrt(64)
        float a1 = expf(p1 * 0.125f);
        exp_alpha[(size_t)wid * 2 + 0] = a0;
        exp_alpha[(size_t)wid * 2 + 1] = a1;
        atomicAdd(&seg_sum[(size_t)d * 2 + 0], a0);
        atomicAdd(&seg_sum[(size_t)d * 2 + 1], a1);
    }
}

// Pass B: normalized message scatter-add (one wave per edge)
__global__ void edge_scatter(const int* __restrict__ src, const int* __restrict__ dst,
                             const int* __restrict__ et, const int* __restrict__ ets,
                             const float* __restrict__ edge_W, const float* __restrict__ edge_b,
                             const float* __restrict__ time_W, const float* __restrict__ time_b,
                             const float* __restrict__ We,
                             const float* __restrict__ V,
                             const float* __restrict__ exp_alpha, const float* __restrict__ seg_sum,
                             float* __restrict__ out, int nedge) {
    int wid = (blockIdx.x * blockDim.x + threadIdx.x) >> 6;
    int lane = threadIdx.x & 63;
    if (wid >= nedge) return;
    int s = src[wid], d = dst[wid];
    float e0, e1;
    edge_proj(et[wid], ets[wid], lane, edge_W, edge_b, time_W, time_b, We, e0, e1);
    float a0 = exp_alpha[(size_t)wid * 2 + 0] / (seg_sum[(size_t)d * 2 + 0] + 1e-16f);
    float a1 = exp_alpha[(size_t)wid * 2 + 1] / (seg_sum[(size_t)d * 2 + 1] + 1e-16f);
    atomicAdd(&out[(size_t)d * 128 + lane],      (V[(size_t)s * 128 + lane]      + e0) * a0);
    atomicAdd(&out[(size_t)d * 128 + 64 + lane], (V[(size_t)s * 128 + 64 + lane] + e1) * a1);
}

// Layer-1 epilogue: beta gate + LayerNorm + exact GELU (one wave per node)
__global__ void node_epilogue1(const float* __restrict__ out, const float* __restrict__ xr,
                               const float* __restrict__ Wbeta,
                               const float* __restrict__ ln_g, const float* __restrict__ ln_b,
                               float* __restrict__ h, int n) {
    int wid = (blockIdx.x * blockDim.x + threadIdx.x) >> 6;
    int lane = threadIdx.x & 63;
    if (wid >= n) return;
    float o0 = out[(size_t)wid * 128 + lane],      o1 = out[(size_t)wid * 128 + 64 + lane];
    float r0 = xr[(size_t)wid * 128 + lane],       r1 = xr[(size_t)wid * 128 + 64 + lane];
    float p = Wbeta[lane] * o0 + Wbeta[64 + lane] * o1
            + Wbeta[128 + lane] * r0 + Wbeta[192 + lane] * r1
            + Wbeta[256 + lane] * (o0 - r0) + Wbeta[320 + lane] * (o1 - r1);
#pragma unroll
    for (int off = 32; off; off >>= 1) p += __shfl_xor(p, off);
    float beta = 1.f / (1.f + expf(-p));
    float h0 = beta * r0 + (1.f - beta) * o0;
    float h1 = beta * r1 + (1.f - beta) * o1;
    float s = h0 + h1, s2 = h0 * h0 + h1 * h1;
#pragma unroll
    for (int off = 32; off; off >>= 1) {
        s  += __shfl_xor(s, off);
        s2 += __shfl_xor(s2, off);
    }
    float mu = s * (1.f / 128.f);
    float var = s2 * (1.f / 128.f) - mu * mu;
    float inv = rsqrtf(var + 1e-5f);
    float y0 = (h0 - mu) * inv * ln_g[lane] + ln_b[lane];
    float y1 = (h1 - mu) * inv * ln_g[64 + lane] + ln_b[64 + lane];
    y0 = 0.5f * y0 * (1.f + erff(y0 * 0.70710678118654752f));
    y1 = 0.5f * y1 * (1.f + erff(y1 * 0.70710678118654752f));
    h[(size_t)wid * 128 + lane] = y0;
    h[(size_t)wid * 128 + 64 + lane] = y1;
}

// Layer-2 epilogue: head-mean + beta gate + log_softmax (one wave per node)
__global__ void node_epilogue2(const float* __restrict__ out, const float* __restrict__ xr,
                               const float* __restrict__ Wbeta,
                               float* __restrict__ o, int n) {
    int wid = (blockIdx.x * blockDim.x + threadIdx.x) >> 6;
    int lane = threadIdx.x & 63;
    if (wid >= n) return;
    float om = 0.5f * (out[(size_t)wid * 128 + lane] + out[(size_t)wid * 128 + 64 + lane]);
    float r = xr[(size_t)wid * 64 + lane];
    float p = Wbeta[lane] * om + Wbeta[64 + lane] * r + Wbeta[128 + lane] * (om - r);
#pragma unroll
    for (int off = 32; off; off >>= 1) p += __shfl_xor(p, off);
    float beta = 1.f / (1.f + expf(-p));
    float v = beta * r + (1.f - beta) * om;
    float m = v;
#pragma unroll
    for (int off = 32; off; off >>= 1) m = fmaxf(m, __shfl_xor(m, off));
    float ex = expf(v - m);
    float se = ex;
#pragma unroll
    for (int off = 32; off; off >>= 1) se += __shfl_xor(se, off);
    o[(size_t)wid * 64 + lane] = v - m - logf(se);
}

extern "C" void kernel_launch(void* const* d_in, const int* in_sizes, int n_in,
                              void* d_out, int out_size, void* d_ws, size_t ws_size,
                              hipStream_t stream) {
    const float* x        = (const float*)d_in[0];
    const int*   ei1_src  = (const int*)d_in[1];
    const int*   ei1_dst  = (const int*)d_in[2];
    const int*   et1      = (const int*)d_in[3];
    const int*   ets1     = (const int*)d_in[4];
    const int*   ei2_src  = (const int*)d_in[5];
    const int*   ei2_dst  = (const int*)d_in[6];
    const int*   et2      = (const int*)d_in[7];
    const int*   ets2     = (const int*)d_in[8];
    const float* edge_W   = (const float*)d_in[9];
    const float* edge_b   = (const float*)d_in[10];
    const float* time_W   = (const float*)d_in[11];
    const float* time_b   = (const float*)d_in[12];
    const float* Wq1      = (const float*)d_in[13];
    const float* bq1      = (const float*)d_in[14];
    const float* Wk1      = (const float*)d_in[15];
    const float* bk1      = (const float*)d_in[16];
    const float* Wv1      = (const float*)d_in[17];
    const float* bv1      = (const float*)d_in[18];
    const float* We1      = (const float*)d_in[19];
    const float* Wskip1   = (const float*)d_in[20];
    const float* bskip1   = (const float*)d_in[21];
    const float* Wbeta1   = (const float*)d_in[22];
    const float* ln_g     = (const float*)d_in[23];
    const float* ln_b     = (const float*)d_in[24];
    const float* Wq2      = (const float*)d_in[25];
    const float* bq2      = (const float*)d_in[26];
    const float* Wk2      = (const float*)d_in[27];
    const float* bk2      = (const float*)d_in[28];
    const float* Wv2      = (const float*)d_in[29];
    const float* bv2      = (const float*)d_in[30];
    const float* We2      = (const float*)d_in[31];
    const float* Wskip2   = (const float*)d_in[32];
    const float* bskip2   = (const float*)d_in[33];
    const float* Wbeta2   = (const float*)d_in[34];

    float* ws = (float*)d_ws;
    float* q1   = ws + OFF_Q1;
    float* k1   = ws + OFF_K1;
    float* v1   = ws + OFF_V1;
    float* xr1  = ws + OFF_XR1;
    float* out1 = ws + OFF_OUT1;
    float* ea1  = ws + OFF_EA1;
    float* sum1 = ws + OFF_SUM1;
    float* h    = ws + OFF_H;
    float* q2   = ws + OFF_Q2;
    float* k2   = ws + OFF_K2;
    float* v2   = ws + OFF_V2;
    float* xr2  = ws + OFF_XR2;
    float* out2 = ws + OFF_OUT2;
    float* ea2  = ws + OFF_EA2;
    float* sum2 = ws + OFF_SUM2;

    const int TB = 256;
    // ---- Layer 1 projections ----
    lin_kernel<<<(N1 * 128 + TB - 1) / TB, TB, 0, stream>>>(x, Wq1, bq1, q1, N1, 128);
    lin_kernel<<<(N0 * 128 + TB - 1) / TB, TB, 0, stream>>>(x, Wk1, bk1, k1, N0, 128);
    lin_kernel<<<(N0 * 128 + TB - 1) / TB, TB, 0, stream>>>(x, Wv1, bv1, v1, N0, 128);
    lin_kernel<<<(N1 * 128 + TB - 1) / TB, TB, 0, stream>>>(x, Wskip1, bskip1, xr1, N1, 128);
    // ---- Layer 1 attention ----
    hipMemsetAsync(out1, 0, (size_t)N1 * 128 * sizeof(float), stream);
    hipMemsetAsync(sum1, 0, (size_t)N1 * 2 * sizeof(float), stream);
    edge_alpha<<<(E1C + 3) / 4, TB, 0, stream>>>(ei1_src, ei1_dst, et1, ets1,
        edge_W, edge_b, time_W, time_b, We1, k1, q1, ea1, sum1, E1C);
    edge_scatter<<<(E1C + 3) / 4, TB, 0, stream>>>(ei1_src, ei1_dst, et1, ets1,
        edge_W, edge_b, time_W, time_b, We1, v1, ea1, sum1, out1, E1C);
    node_epilogue1<<<(N1 + 3) / 4, TB, 0, stream>>>(out1, xr1, Wbeta1, ln_g, ln_b, h, N1);
    // ---- Layer 2 projections ----
    lin_kernel<<<(N2 * 128 + TB - 1) / TB, TB, 0, stream>>>(h, Wq2, bq2, q2, N2, 128);
    lin_kernel<<<(N1 * 128 + TB - 1) / TB, TB, 0, stream>>>(h, Wk2, bk2, k2, N1, 128);
    lin_kernel<<<(N1 * 128 + TB - 1) / TB, TB, 0, stream>>>(h, Wv2, bv2, v2, N1, 128);
    lin_kernel<<<(N2 * 64 + TB - 1) / TB, TB, 0, stream>>>(h, Wskip2, bskip2, xr2, N2, 64);
    // ---- Layer 2 attention ----
    hipMemsetAsync(out2, 0, (size_t)N2 * 128 * sizeof(float), stream);
    hipMemsetAsync(sum2, 0, (size_t)N2 * 2 * sizeof(float), stream);
    edge_alpha<<<(E2C + 3) / 4, TB, 0, stream>>>(ei2_src, ei2_dst, et2, ets2,
        edge_W, edge_b, time_W, time_b, We2, k2, q2, ea2, sum2, E2C);
    edge_scatter<<<(E2C + 3) / 4, TB, 0, stream>>>(ei2_src, ei2_dst, et2, ets2,
        edge_W, edge_b, time_W, time_b, We2, v2, ea2, sum2, out2, E2C);
    node_epilogue2<<<(N2 + 3) / 4, TB, 0, stream>>>(out2, xr2, Wbeta2, (float*)d_out, N2);
}

// Round 2
// 912.147 us; speedup vs baseline: 4.5836x; 4.5836x over previous
//
#include <hip/hip_runtime.h>
#include <math.h>

// Problem constants
#define N0 80000
#define N1 40000
#define N2 20000
#define E1C 500000
#define E2C 250000
#define NTYPE 23
#define NTS 1158

// Workspace layout (float offsets)
#define OFF_Q1   0u            // N1*128
#define OFF_K1   5120000u      // N0*128
#define OFF_V1   15360000u     // N0*128
#define OFF_XR1  25600000u     // N1*128
#define OFF_OUT1 30720000u     // N1*128
#define OFF_EA1  35840000u     // E1*2
#define OFF_SUM1 36840000u     // N1*2
#define OFF_H    36920000u     // N1*128  (ends 42,040,000 floats = 168 MB)
// layer 2 overlays layer-1 temporaries (dead after node_epilogue1)
#define OFF_Q2   0u            // N2*128
#define OFF_K2   2560000u      // N1*128
#define OFF_V2   7680000u      // N1*128
#define OFF_XR2  12800000u     // N2*64
#define OFF_OUT2 14080000u     // N2*128
#define OFF_EA2  16640000u     // E2*2
#define OFF_SUM2 17140000u     // N2*2
// edge-feature tables: A (23x128) + B (1158x128) per layer
// layer-1 tables live under H (H written only by node_epilogue1, after edges)
#define OFF_TA1  36920000u
#define OFF_TB1  36922944u     // +23*128
// layer-2 tables live under EA1 (dead after edge_scatter1)
#define OFF_TA2  35840000u
#define OFF_TB2  35842944u

// ---------------------------------------------------------------------------
// Tiled GEMM: Y[n, NOUT] = X[n,128] @ W[NOUT,128]^T + b
// Block: 256 threads, 64 rows x NOUT cols. W^T staged in LDS (padded).
// ---------------------------------------------------------------------------
template <int NOUT>
__global__ __launch_bounds__(256) void gemm_tile(const float* __restrict__ X,
                                                 const float* __restrict__ W,
                                                 const float* __restrict__ bias,
                                                 float* __restrict__ Y, int n) {
    constexpr int PAD = (NOUT == 128) ? 132 : 68;   // 4-aligned, breaks bank stride
    __shared__ float wt[128 * PAD];
    int tid = threadIdx.x;
    for (int idx = tid; idx < NOUT * 128; idx += 256) {
        int c = idx >> 7, k = idx & 127;
        wt[k * PAD + c] = W[idx];
    }
    __syncthreads();

    int cg = tid & 15, rg = tid >> 4;
    int row0 = blockIdx.x * 64;
    int r[4];
#pragma unroll
    for (int i = 0; i < 4; i++) {
        int rr = row0 + rg + 16 * i;
        r[i] = rr < n ? rr : (n - 1);
    }

    if constexpr (NOUT == 128) {
        float acc[4][8];
#pragma unroll
        for (int i = 0; i < 4; i++)
#pragma unroll
            for (int j = 0; j < 8; j++) acc[i][j] = 0.f;

        for (int k0 = 0; k0 < 128; k0 += 4) {
            float4 xv[4];
#pragma unroll
            for (int i = 0; i < 4; i++)
                xv[i] = *(const float4*)(X + (size_t)r[i] * 128 + k0);
#pragma unroll
            for (int kk = 0; kk < 4; kk++) {
                float4 w0 = *(const float4*)&wt[(k0 + kk) * PAD + 4 * cg];
                float4 w1 = *(const float4*)&wt[(k0 + kk) * PAD + 64 + 4 * cg];
#pragma unroll
                for (int i = 0; i < 4; i++) {
                    float xs = ((const float*)&xv[i])[kk];
                    acc[i][0] += xs * w0.x; acc[i][1] += xs * w0.y;
                    acc[i][2] += xs * w0.z; acc[i][3] += xs * w0.w;
                    acc[i][4] += xs * w1.x; acc[i][5] += xs * w1.y;
                    acc[i][6] += xs * w1.z; acc[i][7] += xs * w1.w;
                }
            }
        }
        float4 b0 = *(const float4*)&bias[4 * cg];
        float4 b1 = *(const float4*)&bias[64 + 4 * cg];
#pragma unroll
        for (int i = 0; i < 4; i++) {
            int rr = row0 + rg + 16 * i;
            if (rr < n) {
                float4 o0 = make_float4(acc[i][0] + b0.x, acc[i][1] + b0.y,
                                        acc[i][2] + b0.z, acc[i][3] + b0.w);
                float4 o1 = make_float4(acc[i][4] + b1.x, acc[i][5] + b1.y,
                                        acc[i][6] + b1.z, acc[i][7] + b1.w);
                *(float4*)(Y + (size_t)rr * 128 + 4 * cg) = o0;
                *(float4*)(Y + (size_t)rr * 128 + 64 + 4 * cg) = o1;
            }
        }
    } else {  // NOUT == 64
        float acc[4][4];
#pragma unroll
        for (int i = 0; i < 4; i++)
#pragma unroll
            for (int j = 0; j < 4; j++) acc[i][j] = 0.f;

        for (int k0 = 0; k0 < 128; k0 += 4) {
            float4 xv[4];
#pragma unroll
            for (int i = 0; i < 4; i++)
                xv[i] = *(const float4*)(X + (size_t)r[i] * 128 + k0);
#pragma unroll
            for (int kk = 0; kk < 4; kk++) {
                float4 w0 = *(const float4*)&wt[(k0 + kk) * PAD + 4 * cg];
#pragma unroll
                for (int i = 0; i < 4; i++) {
                    float xs = ((const float*)&xv[i])[kk];
                    acc[i][0] += xs * w0.x; acc[i][1] += xs * w0.y;
                    acc[i][2] += xs * w0.z; acc[i][3] += xs * w0.w;
                }
            }
        }
        float4 b0 = *(const float4*)&bias[4 * cg];
#pragma unroll
        for (int i = 0; i < 4; i++) {
            int rr = row0 + rg + 16 * i;
            if (rr < n) {
                float4 o0 = make_float4(acc[i][0] + b0.x, acc[i][1] + b0.y,
                                        acc[i][2] + b0.z, acc[i][3] + b0.w);
                *(float4*)(Y + (size_t)rr * 64 + 4 * cg) = o0;
            }
        }
    }
}

// ---------------------------------------------------------------------------
// Edge-feature tables: e(et,ets)[c] = TA[et][c] + TB[ets][c]
// TA[t][c] = sum_j (edge_W[j][t]+edge_b[j]) * We[c][j]
// TB[ts][c] = sum_j (time_W[j][ts]+time_b[j]) * We[c][10+j]
// ---------------------------------------------------------------------------
__global__ void build_tables(const float* __restrict__ edge_W, const float* __restrict__ edge_b,
                             const float* __restrict__ time_W, const float* __restrict__ time_b,
                             const float* __restrict__ We,
                             float* __restrict__ TA, float* __restrict__ TB) {
    int t = blockIdx.x * blockDim.x + threadIdx.x;
    if (t < NTYPE * 128) {
        int e = t >> 7, c = t & 127;
        float s = 0.f;
#pragma unroll
        for (int j = 0; j < 10; j++)
            s += (edge_W[j * NTYPE + e] + edge_b[j]) * We[c * 20 + j];
        TA[t] = s;
    } else {
        int u = t - NTYPE * 128;
        if (u < NTS * 128) {
            int ts = u >> 7, c = u & 127;
            float s = 0.f;
#pragma unroll
            for (int j = 0; j < 10; j++)
                s += (time_W[j * NTS + ts] + time_b[j]) * We[c * 20 + 10 + j];
            TB[u] = s;
        }
    }
}

// Pass A: alpha -> exp(alpha) and segment sums (one wave per edge)
__global__ void edge_alpha(const int* __restrict__ src, const int* __restrict__ dst,
                           const int* __restrict__ et, const int* __restrict__ ets,
                           const float* __restrict__ TA, const float* __restrict__ TB,
                           const float* __restrict__ K, const float* __restrict__ Q,
                           float* __restrict__ exp_alpha, float* __restrict__ seg_sum,
                           int nedge) {
    int wid = (blockIdx.x * blockDim.x + threadIdx.x) >> 6;
    int lane = threadIdx.x & 63;
    if (wid >= nedge) return;
    int s = src[wid], d = dst[wid];
    int t = et[wid], ts = ets[wid];
    float e0 = TA[t * 128 + lane] + TB[ts * 128 + lane];
    float e1 = TA[t * 128 + 64 + lane] + TB[ts * 128 + 64 + lane];
    float p0 = Q[(size_t)d * 128 + lane]      * (K[(size_t)s * 128 + lane]      + e0);
    float p1 = Q[(size_t)d * 128 + 64 + lane] * (K[(size_t)s * 128 + 64 + lane] + e1);
#pragma unroll
    for (int off = 32; off; off >>= 1) {
        p0 += __shfl_down(p0, off);
        p1 += __shfl_down(p1, off);
    }
    if (lane == 0) {
        float a0 = expf(p0 * 0.125f);   // 1/sqrt(64)
        float a1 = expf(p1 * 0.125f);
        exp_alpha[(size_t)wid * 2 + 0] = a0;
        exp_alpha[(size_t)wid * 2 + 1] = a1;
        atomicAdd(&seg_sum[(size_t)d * 2 + 0], a0);
        atomicAdd(&seg_sum[(size_t)d * 2 + 1], a1);
    }
}

// Pass B: normalized message scatter-add (one wave per edge)
__global__ void edge_scatter(const int* __restrict__ src, const int* __restrict__ dst,
                             const int* __restrict__ et, const int* __restrict__ ets,
                             const float* __restrict__ TA, const float* __restrict__ TB,
                             const float* __restrict__ V,
                             const float* __restrict__ exp_alpha, const float* __restrict__ seg_sum,
                             float* __restrict__ out, int nedge) {
    int wid = (blockIdx.x * blockDim.x + threadIdx.x) >> 6;
    int lane = threadIdx.x & 63;
    if (wid >= nedge) return;
    int s = src[wid], d = dst[wid];
    int t = et[wid], ts = ets[wid];
    float e0 = TA[t * 128 + lane] + TB[ts * 128 + lane];
    float e1 = TA[t * 128 + 64 + lane] + TB[ts * 128 + 64 + lane];
    float a0 = exp_alpha[(size_t)wid * 2 + 0] / (seg_sum[(size_t)d * 2 + 0] + 1e-16f);
    float a1 = exp_alpha[(size_t)wid * 2 + 1] / (seg_sum[(size_t)d * 2 + 1] + 1e-16f);
    atomicAdd(&out[(size_t)d * 128 + lane],      (V[(size_t)s * 128 + lane]      + e0) * a0);
    atomicAdd(&out[(size_t)d * 128 + 64 + lane], (V[(size_t)s * 128 + 64 + lane] + e1) * a1);
}

// Layer-1 epilogue: beta gate + LayerNorm + exact GELU (one wave per node)
__global__ void node_epilogue1(const float* __restrict__ out, const float* __restrict__ xr,
                               const float* __restrict__ Wbeta,
                               const float* __restrict__ ln_g, const float* __restrict__ ln_b,
                               float* __restrict__ h, int n) {
    int wid = (blockIdx.x * blockDim.x + threadIdx.x) >> 6;
    int lane = threadIdx.x & 63;
    if (wid >= n) return;
    float o0 = out[(size_t)wid * 128 + lane],      o1 = out[(size_t)wid * 128 + 64 + lane];
    float r0 = xr[(size_t)wid * 128 + lane],       r1 = xr[(size_t)wid * 128 + 64 + lane];
    float p = Wbeta[lane] * o0 + Wbeta[64 + lane] * o1
            + Wbeta[128 + lane] * r0 + Wbeta[192 + lane] * r1
            + Wbeta[256 + lane] * (o0 - r0) + Wbeta[320 + lane] * (o1 - r1);
#pragma unroll
    for (int off = 32; off; off >>= 1) p += __shfl_xor(p, off);
    float beta = 1.f / (1.f + expf(-p));
    float h0 = beta * r0 + (1.f - beta) * o0;
    float h1 = beta * r1 + (1.f - beta) * o1;
    float s = h0 + h1, s2 = h0 * h0 + h1 * h1;
#pragma unroll
    for (int off = 32; off; off >>= 1) {
        s  += __shfl_xor(s, off);
        s2 += __shfl_xor(s2, off);
    }
    float mu = s * (1.f / 128.f);
    float var = s2 * (1.f / 128.f) - mu * mu;
    float inv = rsqrtf(var + 1e-5f);
    float y0 = (h0 - mu) * inv * ln_g[lane] + ln_b[lane];
    float y1 = (h1 - mu) * inv * ln_g[64 + lane] + ln_b[64 + lane];
    y0 = 0.5f * y0 * (1.f + erff(y0 * 0.70710678118654752f));
    y1 = 0.5f * y1 * (1.f + erff(y1 * 0.70710678118654752f));
    h[(size_t)wid * 128 + lane] = y0;
    h[(size_t)wid * 128 + 64 + lane] = y1;
}

// Layer-2 epilogue: head-mean + beta gate + log_softmax (one wave per node)
__global__ void node_epilogue2(const float* __restrict__ out, const float* __restrict__ xr,
                               const float* __restrict__ Wbeta,
                               float* __restrict__ o, int n) {
    int wid = (blockIdx.x * blockDim.x + threadIdx.x) >> 6;
    int lane = threadIdx.x & 63;
    if (wid >= n) return;
    float om = 0.5f * (out[(size_t)wid * 128 + lane] + out[(size_t)wid * 128 + 64 + lane]);
    float r = xr[(size_t)wid * 64 + lane];
    float p = Wbeta[lane] * om + Wbeta[64 + lane] * r + Wbeta[128 + lane] * (om - r);
#pragma unroll
    for (int off = 32; off; off >>= 1) p += __shfl_xor(p, off);
    float beta = 1.f / (1.f + expf(-p));
    float v = beta * r + (1.f - beta) * om;
    float m = v;
#pragma unroll
    for (int off = 32; off; off >>= 1) m = fmaxf(m, __shfl_xor(m, off));
    float ex = expf(v - m);
    float se = ex;
#pragma unroll
    for (int off = 32; off; off >>= 1) se += __shfl_xor(se, off);
    o[(size_t)wid * 64 + lane] = v - m - logf(se);
}

extern "C" void kernel_launch(void* const* d_in, const int* in_sizes, int n_in,
                              void* d_out, int out_size, void* d_ws, size_t ws_size,
                              hipStream_t stream) {
    const float* x        = (const float*)d_in[0];
    const int*   ei1_src  = (const int*)d_in[1];
    const int*   ei1_dst  = (const int*)d_in[2];
    const int*   et1      = (const int*)d_in[3];
    const int*   ets1     = (const int*)d_in[4];
    const int*   ei2_src  = (const int*)d_in[5];
    const int*   ei2_dst  = (const int*)d_in[6];
    const int*   et2      = (const int*)d_in[7];
    const int*   ets2     = (const int*)d_in[8];
    const float* edge_W   = (const float*)d_in[9];
    const float* edge_b   = (const float*)d_in[10];
    const float* time_W   = (const float*)d_in[11];
    const float* time_b   = (const float*)d_in[12];
    const float* Wq1      = (const float*)d_in[13];
    const float* bq1      = (const float*)d_in[14];
    const float* Wk1      = (const float*)d_in[15];
    const float* bk1      = (const float*)d_in[16];
    const float* Wv1      = (const float*)d_in[17];
    const float* bv1      = (const float*)d_in[18];
    const float* We1      = (const float*)d_in[19];
    const float* Wskip1   = (const float*)d_in[20];
    const float* bskip1   = (const float*)d_in[21];
    const float* Wbeta1   = (const float*)d_in[22];
    const float* ln_g     = (const float*)d_in[23];
    const float* ln_b     = (const float*)d_in[24];
    const float* Wq2      = (const float*)d_in[25];
    const float* bq2      = (const float*)d_in[26];
    const float* Wk2      = (const float*)d_in[27];
    const float* bk2      = (const float*)d_in[28];
    const float* Wv2      = (const float*)d_in[29];
    const float* bv2      = (const float*)d_in[30];
    const float* We2      = (const float*)d_in[31];
    const float* Wskip2   = (const float*)d_in[32];
    const float* bskip2   = (const float*)d_in[33];
    const float* Wbeta2   = (const float*)d_in[34];

    float* ws = (float*)d_ws;
    float* q1   = ws + OFF_Q1;
    float* k1   = ws + OFF_K1;
    float* v1   = ws + OFF_V1;
    float* xr1  = ws + OFF_XR1;
    float* out1 = ws + OFF_OUT1;
    float* ea1  = ws + OFF_EA1;
    float* sum1 = ws + OFF_SUM1;
    float* h    = ws + OFF_H;
    float* q2   = ws + OFF_Q2;
    float* k2   = ws + OFF_K2;
    float* v2   = ws + OFF_V2;
    float* xr2  = ws + OFF_XR2;
    float* out2 = ws + OFF_OUT2;
    float* ea2  = ws + OFF_EA2;
    float* sum2 = ws + OFF_SUM2;
    float* ta1  = ws + OFF_TA1;
    float* tb1  = ws + OFF_TB1;
    float* ta2  = ws + OFF_TA2;
    float* tb2  = ws + OFF_TB2;

    const int TB = 256;
    const int TBL_THREADS = (NTYPE + NTS) * 128;

    // ---- Layer 1 ----
    build_tables<<<(TBL_THREADS + TB - 1) / TB, TB, 0, stream>>>(
        edge_W, edge_b, time_W, time_b, We1, ta1, tb1);
    gemm_tile<128><<<(N1 + 63) / 64, TB, 0, stream>>>(x, Wq1, bq1, q1, N1);
    gemm_tile<128><<<(N0 + 63) / 64, TB, 0, stream>>>(x, Wk1, bk1, k1, N0);
    gemm_tile<128><<<(N0 + 63) / 64, TB, 0, stream>>>(x, Wv1, bv1, v1, N0);
    gemm_tile<128><<<(N1 + 63) / 64, TB, 0, stream>>>(x, Wskip1, bskip1, xr1, N1);
    hipMemsetAsync(out1, 0, (size_t)N1 * 128 * sizeof(float), stream);
    hipMemsetAsync(sum1, 0, (size_t)N1 * 2 * sizeof(float), stream);
    edge_alpha<<<(E1C + 3) / 4, TB, 0, stream>>>(ei1_src, ei1_dst, et1, ets1,
        ta1, tb1, k1, q1, ea1, sum1, E1C);
    edge_scatter<<<(E1C + 3) / 4, TB, 0, stream>>>(ei1_src, ei1_dst, et1, ets1,
        ta1, tb1, v1, ea1, sum1, out1, E1C);
    node_epilogue1<<<(N1 + 3) / 4, TB, 0, stream>>>(out1, xr1, Wbeta1, ln_g, ln_b, h, N1);

    // ---- Layer 2 ----
    build_tables<<<(TBL_THREADS + TB - 1) / TB, TB, 0, stream>>>(
        edge_W, edge_b, time_W, time_b, We2, ta2, tb2);
    gemm_tile<128><<<(N2 + 63) / 64, TB, 0, stream>>>(h, Wq2, bq2, q2, N2);
    gemm_tile<128><<<(N1 + 63) / 64, TB, 0, stream>>>(h, Wk2, bk2, k2, N1);
    gemm_tile<128><<<(N1 + 63) / 64, TB, 0, stream>>>(h, Wv2, bv2, v2, N1);
    gemm_tile<64><<<(N2 + 63) / 64, TB, 0, stream>>>(h, Wskip2, bskip2, xr2, N2);
    hipMemsetAsync(out2, 0, (size_t)N2 * 128 * sizeof(float), stream);
    hipMemsetAsync(sum2, 0, (size_t)N2 * 2 * sizeof(float), stream);
    edge_alpha<<<(E2C + 3) / 4, TB, 0, stream>>>(ei2_src, ei2_dst, et2, ets2,
        ta2, tb2, k2, q2, ea2, sum2, E2C);
    edge_scatter<<<(E2C + 3) / 4, TB, 0, stream>>>(ei2_src, ei2_dst, et2, ets2,
        ta2, tb2, v2, ea2, sum2, out2, E2C);
    node_epilogue2<<<(N2 + 3) / 4, TB, 0, stream>>>(out2, xr2, Wbeta2, (float*)d_out, N2);
}

// Round 3
// 685.680 us; speedup vs baseline: 6.0974x; 1.3303x over previous
//
#include <hip/hip_runtime.h>
#include <math.h>

// Problem constants
#define N0 80000
#define N1 40000
#define N2 20000
#define E1C 500000
#define E2C 250000
#define NTYPE 23
#define NTS 1158

// ---------------- Workspace layout (float offsets) ----------------
// Layer 1 phase
#define OFF_Q1    0u           // N1*128 = 5,120,000
#define OFF_K1    5120000u     // N0*128 = 10,240,000
#define OFF_V1    15360000u    // N0*128
#define OFF_XR1   25600000u    // N1*128
#define OFF_H     30720000u    // N1*128 (output of layer1, live through layer2)
#define OFF_TA1   35840000u    // 23*128
#define OFF_TB1   35842944u    // 1158*128 = 148,224
#define OFF_RP1   36000000u    // rowptr1: N1+1 ints
#define OFF_CUR1  36050000u    // cursor1: N1 ints
#define OFF_EIX1  36100000u    // eidx1: E1 ints
#define OFF_BS1   36650000u    // bsum: 256 ints
// Layer 2 phase overlays [0, OFF_H)
#define OFF_Q2    0u           // N2*128 = 2,560,000
#define OFF_K2    2560000u     // N1*128
#define OFF_V2    7680000u     // N1*128
#define OFF_XR2   12800000u    // N2*64 = 1,280,000
#define OFF_TA2   14080000u
#define OFF_TB2   14082944u
#define OFF_RP2   14240000u    // N2+1 ints
#define OFF_CUR2  14270000u    // N2 ints
#define OFF_EIX2  14300000u    // E2 ints
#define OFF_BS2   14560000u    // 256 ints
// total ws use: 36,650,256 floats ≈ 146.6 MB (< round-1's 168 MB)

// ---------------------------------------------------------------------------
// Tiled GEMM: Y[n, NOUT] = X[n,128] @ W[NOUT,128]^T + b  (unchanged from R1)
// ---------------------------------------------------------------------------
template <int NOUT>
__global__ __launch_bounds__(256) void gemm_tile(const float* __restrict__ X,
                                                 const float* __restrict__ W,
                                                 const float* __restrict__ bias,
                                                 float* __restrict__ Y, int n) {
    constexpr int PAD = (NOUT == 128) ? 132 : 68;
    __shared__ float wt[128 * PAD];
    int tid = threadIdx.x;
    for (int idx = tid; idx < NOUT * 128; idx += 256) {
        int c = idx >> 7, k = idx & 127;
        wt[k * PAD + c] = W[idx];
    }
    __syncthreads();

    int cg = tid & 15, rg = tid >> 4;
    int row0 = blockIdx.x * 64;
    int r[4];
#pragma unroll
    for (int i = 0; i < 4; i++) {
        int rr = row0 + rg + 16 * i;
        r[i] = rr < n ? rr : (n - 1);
    }

    if constexpr (NOUT == 128) {
        float acc[4][8];
#pragma unroll
        for (int i = 0; i < 4; i++)
#pragma unroll
            for (int j = 0; j < 8; j++) acc[i][j] = 0.f;

        for (int k0 = 0; k0 < 128; k0 += 4) {
            float4 xv[4];
#pragma unroll
            for (int i = 0; i < 4; i++)
                xv[i] = *(const float4*)(X + (size_t)r[i] * 128 + k0);
#pragma unroll
            for (int kk = 0; kk < 4; kk++) {
                float4 w0 = *(const float4*)&wt[(k0 + kk) * PAD + 4 * cg];
                float4 w1 = *(const float4*)&wt[(k0 + kk) * PAD + 64 + 4 * cg];
#pragma unroll
                for (int i = 0; i < 4; i++) {
                    float xs = ((const float*)&xv[i])[kk];
                    acc[i][0] += xs * w0.x; acc[i][1] += xs * w0.y;
                    acc[i][2] += xs * w0.z; acc[i][3] += xs * w0.w;
                    acc[i][4] += xs * w1.x; acc[i][5] += xs * w1.y;
                    acc[i][6] += xs * w1.z; acc[i][7] += xs * w1.w;
                }
            }
        }
        float4 b0 = *(const float4*)&bias[4 * cg];
        float4 b1 = *(const float4*)&bias[64 + 4 * cg];
#pragma unroll
        for (int i = 0; i < 4; i++) {
            int rr = row0 + rg + 16 * i;
            if (rr < n) {
                float4 o0 = make_float4(acc[i][0] + b0.x, acc[i][1] + b0.y,
                                        acc[i][2] + b0.z, acc[i][3] + b0.w);
                float4 o1 = make_float4(acc[i][4] + b1.x, acc[i][5] + b1.y,
                                        acc[i][6] + b1.z, acc[i][7] + b1.w);
                *(float4*)(Y + (size_t)rr * 128 + 4 * cg) = o0;
                *(float4*)(Y + (size_t)rr * 128 + 64 + 4 * cg) = o1;
            }
        }
    } else {  // NOUT == 64
        float acc[4][4];
#pragma unroll
        for (int i = 0; i < 4; i++)
#pragma unroll
            for (int j = 0; j < 4; j++) acc[i][j] = 0.f;

        for (int k0 = 0; k0 < 128; k0 += 4) {
            float4 xv[4];
#pragma unroll
            for (int i = 0; i < 4; i++)
                xv[i] = *(const float4*)(X + (size_t)r[i] * 128 + k0);
#pragma unroll
            for (int kk = 0; kk < 4; kk++) {
                float4 w0 = *(const float4*)&wt[(k0 + kk) * PAD + 4 * cg];
#pragma unroll
                for (int i = 0; i < 4; i++) {
                    float xs = ((const float*)&xv[i])[kk];
                    acc[i][0] += xs * w0.x; acc[i][1] += xs * w0.y;
                    acc[i][2] += xs * w0.z; acc[i][3] += xs * w0.w;
                }
            }
        }
        float4 b0 = *(const float4*)&bias[4 * cg];
#pragma unroll
        for (int i = 0; i < 4; i++) {
            int rr = row0 + rg + 16 * i;
            if (rr < n) {
                float4 o0 = make_float4(acc[i][0] + b0.x, acc[i][1] + b0.y,
                                        acc[i][2] + b0.z, acc[i][3] + b0.w);
                *(float4*)(Y + (size_t)rr * 64 + 4 * cg) = o0;
            }
        }
    }
}

// ---------------------------------------------------------------------------
// Edge-feature tables: e(et,ets)[c] = TA[et][c] + TB[ets][c]
// ---------------------------------------------------------------------------
__global__ void build_tables(const float* __restrict__ edge_W, const float* __restrict__ edge_b,
                             const float* __restrict__ time_W, const float* __restrict__ time_b,
                             const float* __restrict__ We,
                             float* __restrict__ TA, float* __restrict__ TB) {
    int t = blockIdx.x * blockDim.x + threadIdx.x;
    if (t < NTYPE * 128) {
        int e = t >> 7, c = t & 127;
        float s = 0.f;
#pragma unroll
        for (int j = 0; j < 10; j++)
            s += (edge_W[j * NTYPE + e] + edge_b[j]) * We[c * 20 + j];
        TA[t] = s;
    } else {
        int u = t - NTYPE * 128;
        if (u < NTS * 128) {
            int ts = u >> 7, c = u & 127;
            float s = 0.f;
#pragma unroll
            for (int j = 0; j < 10; j++)
                s += (time_W[j * NTS + ts] + time_b[j]) * We[c * 20 + 10 + j];
            TB[u] = s;
        }
    }
}

// ---------------------------------------------------------------------------
// CSR build: count -> block_sum -> scan_bsum -> block_scan -> fill
// ---------------------------------------------------------------------------
__global__ void count_kernel(const int* __restrict__ dst, int* __restrict__ cnt, int nedge) {
    int t = blockIdx.x * blockDim.x + threadIdx.x;
    if (t < nedge) atomicAdd(&cnt[dst[t]], 1);
}

__global__ void block_sum(const int* __restrict__ cnt, int* __restrict__ bsum, int n) {
    __shared__ int s[256];
    int t = blockIdx.x * 256 + threadIdx.x;
    s[threadIdx.x] = (t < n) ? cnt[t] : 0;
    __syncthreads();
    for (int off = 128; off; off >>= 1) {
        if (threadIdx.x < off) s[threadIdx.x] += s[threadIdx.x + off];
        __syncthreads();
    }
    if (threadIdx.x == 0) bsum[blockIdx.x] = s[0];
}

// single block: in-place exclusive scan of bsum[nb], nb <= 256
__global__ void scan_bsum(int* __restrict__ bsum, int nb) {
    __shared__ int s[256];
    int t = threadIdx.x;
    s[t] = (t < nb) ? bsum[t] : 0;
    __syncthreads();
    for (int off = 1; off < 256; off <<= 1) {
        int v = (t >= off) ? s[t - off] : 0;
        __syncthreads();
        s[t] += v;
        __syncthreads();
    }
    if (t < nb) bsum[t] = (t > 0) ? s[t - 1] : 0;
}

__global__ void block_scan(const int* __restrict__ cnt, const int* __restrict__ bsum,
                           int* __restrict__ rowptr, int n) {
    __shared__ int s[256];
    int t = blockIdx.x * 256 + threadIdx.x;
    int v = (t < n) ? cnt[t] : 0;
    s[threadIdx.x] = v;
    __syncthreads();
    for (int off = 1; off < 256; off <<= 1) {
        int u = (threadIdx.x >= off) ? s[threadIdx.x - off] : 0;
        __syncthreads();
        s[threadIdx.x] += u;
        __syncthreads();
    }
    int incl = s[threadIdx.x];
    int base = bsum[blockIdx.x];
    if (t < n) rowptr[t] = base + incl - v;
    if (t == n - 1) rowptr[n] = base + incl;
}

__global__ void fill_csr(const int* __restrict__ dst, const int* __restrict__ rowptr,
                         int* __restrict__ cursor, int* __restrict__ eidx, int nedge) {
    int t = blockIdx.x * blockDim.x + threadIdx.x;
    if (t >= nedge) return;
    int d = dst[t];
    int pos = rowptr[d] + atomicAdd(&cursor[d], 1);
    eidx[pos] = t;
}

// ---------------------------------------------------------------------------
// Fused per-node aggregation, layer 1: online softmax (no max-sub; |alpha|
// small) + beta gate + LayerNorm + exact GELU. One wave per dst node.
// ---------------------------------------------------------------------------
__global__ __launch_bounds__(256) void agg_layer1(
    const int* __restrict__ rowptr, const int* __restrict__ eidx,
    const int* __restrict__ src, const int* __restrict__ et, const int* __restrict__ ets,
    const float* __restrict__ TA, const float* __restrict__ TB,
    const float* __restrict__ Q, const float* __restrict__ K, const float* __restrict__ V,
    const float* __restrict__ xr, const float* __restrict__ Wbeta,
    const float* __restrict__ ln_g, const float* __restrict__ ln_b,
    float* __restrict__ h, int n) {
    int wid = (blockIdx.x * blockDim.x + threadIdx.x) >> 6;
    int lane = threadIdx.x & 63;
    if (wid >= n) return;
    int beg = rowptr[wid], end = rowptr[wid + 1];
    float q0 = Q[(size_t)wid * 128 + lane];
    float q1 = Q[(size_t)wid * 128 + 64 + lane];
    float acc0 = 0.f, acc1 = 0.f, s0 = 0.f, s1 = 0.f;
    for (int p = beg; p < end; p++) {
        int e = eidx[p];
        int sn = src[e], t = et[e], ts = ets[e];
        float e0 = TA[t * 128 + lane] + TB[ts * 128 + lane];
        float e1 = TA[t * 128 + 64 + lane] + TB[ts * 128 + 64 + lane];
        float p0 = q0 * (K[(size_t)sn * 128 + lane] + e0);
        float p1 = q1 * (K[(size_t)sn * 128 + 64 + lane] + e1);
#pragma unroll
        for (int off = 32; off; off >>= 1) {
            p0 += __shfl_xor(p0, off);
            p1 += __shfl_xor(p1, off);
        }
        float a0 = expf(p0 * 0.125f);   // 1/sqrt(64)
        float a1 = expf(p1 * 0.125f);
        acc0 += a0 * (V[(size_t)sn * 128 + lane] + e0);
        acc1 += a1 * (V[(size_t)sn * 128 + 64 + lane] + e1);
        s0 += a0; s1 += a1;
    }
    float o0 = acc0 / (s0 + 1e-16f);
    float o1 = acc1 / (s1 + 1e-16f);
    // ---- epilogue: beta gate + LN + GELU ----
    float r0 = xr[(size_t)wid * 128 + lane];
    float r1 = xr[(size_t)wid * 128 + 64 + lane];
    float p = Wbeta[lane] * o0 + Wbeta[64 + lane] * o1
            + Wbeta[128 + lane] * r0 + Wbeta[192 + lane] * r1
            + Wbeta[256 + lane] * (o0 - r0) + Wbeta[320 + lane] * (o1 - r1);
#pragma unroll
    for (int off = 32; off; off >>= 1) p += __shfl_xor(p, off);
    float beta = 1.f / (1.f + expf(-p));
    float h0 = beta * r0 + (1.f - beta) * o0;
    float h1 = beta * r1 + (1.f - beta) * o1;
    float s = h0 + h1, s2 = h0 * h0 + h1 * h1;
#pragma unroll
    for (int off = 32; off; off >>= 1) {
        s  += __shfl_xor(s, off);
        s2 += __shfl_xor(s2, off);
    }
    float mu = s * (1.f / 128.f);
    float var = s2 * (1.f / 128.f) - mu * mu;
    float inv = rsqrtf(var + 1e-5f);
    float y0 = (h0 - mu) * inv * ln_g[lane] + ln_b[lane];
    float y1 = (h1 - mu) * inv * ln_g[64 + lane] + ln_b[64 + lane];
    y0 = 0.5f * y0 * (1.f + erff(y0 * 0.70710678118654752f));
    y1 = 0.5f * y1 * (1.f + erff(y1 * 0.70710678118654752f));
    h[(size_t)wid * 128 + lane] = y0;
    h[(size_t)wid * 128 + 64 + lane] = y1;
}

// ---------------------------------------------------------------------------
// Fused per-node aggregation, layer 2: online softmax + head mean + beta gate
// + log_softmax. One wave per dst node. Writes d_out.
// ---------------------------------------------------------------------------
__global__ __launch_bounds__(256) void agg_layer2(
    const int* __restrict__ rowptr, const int* __restrict__ eidx,
    const int* __restrict__ src, const int* __restrict__ et, const int* __restrict__ ets,
    const float* __restrict__ TA, const float* __restrict__ TB,
    const float* __restrict__ Q, const float* __restrict__ K, const float* __restrict__ V,
    const float* __restrict__ xr, const float* __restrict__ Wbeta,
    float* __restrict__ o, int n) {
    int wid = (blockIdx.x * blockDim.x + threadIdx.x) >> 6;
    int lane = threadIdx.x & 63;
    if (wid >= n) return;
    int beg = rowptr[wid], end = rowptr[wid + 1];
    float q0 = Q[(size_t)wid * 128 + lane];
    float q1 = Q[(size_t)wid * 128 + 64 + lane];
    float acc0 = 0.f, acc1 = 0.f, s0 = 0.f, s1 = 0.f;
    for (int p = beg; p < end; p++) {
        int e = eidx[p];
        int sn = src[e], t = et[e], ts = ets[e];
        float e0 = TA[t * 128 + lane] + TB[ts * 128 + lane];
        float e1 = TA[t * 128 + 64 + lane] + TB[ts * 128 + 64 + lane];
        float p0 = q0 * (K[(size_t)sn * 128 + lane] + e0);
        float p1 = q1 * (K[(size_t)sn * 128 + 64 + lane] + e1);
#pragma unroll
        for (int off = 32; off; off >>= 1) {
            p0 += __shfl_xor(p0, off);
            p1 += __shfl_xor(p1, off);
        }
        float a0 = expf(p0 * 0.125f);
        float a1 = expf(p1 * 0.125f);
        acc0 += a0 * (V[(size_t)sn * 128 + lane] + e0);
        acc1 += a1 * (V[(size_t)sn * 128 + 64 + lane] + e1);
        s0 += a0; s1 += a1;
    }
    float om = 0.5f * (acc0 / (s0 + 1e-16f) + acc1 / (s1 + 1e-16f));
    // ---- epilogue: beta gate + log_softmax ----
    float r = xr[(size_t)wid * 64 + lane];
    float p = Wbeta[lane] * om + Wbeta[64 + lane] * r + Wbeta[128 + lane] * (om - r);
#pragma unroll
    for (int off = 32; off; off >>= 1) p += __shfl_xor(p, off);
    float beta = 1.f / (1.f + expf(-p));
    float v = beta * r + (1.f - beta) * om;
    float m = v;
#pragma unroll
    for (int off = 32; off; off >>= 1) m = fmaxf(m, __shfl_xor(m, off));
    float se = expf(v - m);
#pragma unroll
    for (int off = 32; off; off >>= 1) se += __shfl_xor(se, off);
    o[(size_t)wid * 64 + lane] = v - m - logf(se);
}

extern "C" void kernel_launch(void* const* d_in, const int* in_sizes, int n_in,
                              void* d_out, int out_size, void* d_ws, size_t ws_size,
                              hipStream_t stream) {
    const float* x        = (const float*)d_in[0];
    const int*   ei1_src  = (const int*)d_in[1];
    const int*   ei1_dst  = (const int*)d_in[2];
    const int*   et1      = (const int*)d_in[3];
    const int*   ets1     = (const int*)d_in[4];
    const int*   ei2_src  = (const int*)d_in[5];
    const int*   ei2_dst  = (const int*)d_in[6];
    const int*   et2      = (const int*)d_in[7];
    const int*   ets2     = (const int*)d_in[8];
    const float* edge_W   = (const float*)d_in[9];
    const float* edge_b   = (const float*)d_in[10];
    const float* time_W   = (const float*)d_in[11];
    const float* time_b   = (const float*)d_in[12];
    const float* Wq1      = (const float*)d_in[13];
    const float* bq1      = (const float*)d_in[14];
    const float* Wk1      = (const float*)d_in[15];
    const float* bk1      = (const float*)d_in[16];
    const float* Wv1      = (const float*)d_in[17];
    const float* bv1      = (const float*)d_in[18];
    const float* We1      = (const float*)d_in[19];
    const float* Wskip1   = (const float*)d_in[20];
    const float* bskip1   = (const float*)d_in[21];
    const float* Wbeta1   = (const float*)d_in[22];
    const float* ln_g     = (const float*)d_in[23];
    const float* ln_b     = (const float*)d_in[24];
    const float* Wq2      = (const float*)d_in[25];
    const float* bq2      = (const float*)d_in[26];
    const float* Wk2      = (const float*)d_in[27];
    const float* bk2      = (const float*)d_in[28];
    const float* Wv2      = (const float*)d_in[29];
    const float* bv2      = (const float*)d_in[30];
    const float* We2      = (const float*)d_in[31];
    const float* Wskip2   = (const float*)d_in[32];
    const float* bskip2   = (const float*)d_in[33];
    const float* Wbeta2   = (const float*)d_in[34];

    float* ws = (float*)d_ws;
    float* q1   = ws + OFF_Q1;
    float* k1   = ws + OFF_K1;
    float* v1   = ws + OFF_V1;
    float* xr1  = ws + OFF_XR1;
    float* h    = ws + OFF_H;
    float* ta1  = ws + OFF_TA1;
    float* tb1  = ws + OFF_TB1;
    int*   rp1  = (int*)(ws + OFF_RP1);
    int*   cur1 = (int*)(ws + OFF_CUR1);
    int*   eix1 = (int*)(ws + OFF_EIX1);
    int*   bs1  = (int*)(ws + OFF_BS1);
    float* q2   = ws + OFF_Q2;
    float* k2   = ws + OFF_K2;
    float* v2   = ws + OFF_V2;
    float* xr2  = ws + OFF_XR2;
    float* ta2  = ws + OFF_TA2;
    float* tb2  = ws + OFF_TB2;
    int*   rp2  = (int*)(ws + OFF_RP2);
    int*   cur2 = (int*)(ws + OFF_CUR2);
    int*   eix2 = (int*)(ws + OFF_EIX2);
    int*   bs2  = (int*)(ws + OFF_BS2);

    const int TB = 256;
    const int TBL_THREADS = (NTYPE + NTS) * 128;
    const int NB1 = (N1 + 255) / 256;   // 157
    const int NB2 = (N2 + 255) / 256;   // 79

    // ================= Layer 1 =================
    build_tables<<<(TBL_THREADS + TB - 1) / TB, TB, 0, stream>>>(
        edge_W, edge_b, time_W, time_b, We1, ta1, tb1);
    gemm_tile<128><<<(N1 + 63) / 64, TB, 0, stream>>>(x, Wq1, bq1, q1, N1);
    gemm_tile<128><<<(N0 + 63) / 64, TB, 0, stream>>>(x, Wk1, bk1, k1, N0);
    gemm_tile<128><<<(N0 + 63) / 64, TB, 0, stream>>>(x, Wv1, bv1, v1, N0);
    gemm_tile<128><<<(N1 + 63) / 64, TB, 0, stream>>>(x, Wskip1, bskip1, xr1, N1);
    // CSR build for (dst1 -> edges)
    hipMemsetAsync(cur1, 0, N1 * sizeof(int), stream);
    count_kernel<<<(E1C + TB - 1) / TB, TB, 0, stream>>>(ei1_dst, cur1, E1C);
    block_sum<<<NB1, 256, 0, stream>>>(cur1, bs1, N1);
    scan_bsum<<<1, 256, 0, stream>>>(bs1, NB1);
    block_scan<<<NB1, 256, 0, stream>>>(cur1, bs1, rp1, N1);
    hipMemsetAsync(cur1, 0, N1 * sizeof(int), stream);
    fill_csr<<<(E1C + TB - 1) / TB, TB, 0, stream>>>(ei1_dst, rp1, cur1, eix1, E1C);
    // fused aggregation + epilogue
    agg_layer1<<<(N1 + 3) / 4, TB, 0, stream>>>(rp1, eix1, ei1_src, et1, ets1,
        ta1, tb1, q1, k1, v1, xr1, Wbeta1, ln_g, ln_b, h, N1);

    // ================= Layer 2 =================
    build_tables<<<(TBL_THREADS + TB - 1) / TB, TB, 0, stream>>>(
        edge_W, edge_b, time_W, time_b, We2, ta2, tb2);
    gemm_tile<128><<<(N2 + 63) / 64, TB, 0, stream>>>(h, Wq2, bq2, q2, N2);
    gemm_tile<128><<<(N1 + 63) / 64, TB, 0, stream>>>(h, Wk2, bk2, k2, N1);
    gemm_tile<128><<<(N1 + 63) / 64, TB, 0, stream>>>(h, Wv2, bv2, v2, N1);
    gemm_tile<64><<<(N2 + 63) / 64, TB, 0, stream>>>(h, Wskip2, bskip2, xr2, N2);
    // CSR build for (dst2 -> edges)
    hipMemsetAsync(cur2, 0, N2 * sizeof(int), stream);
    count_kernel<<<(E2C + TB - 1) / TB, TB, 0, stream>>>(ei2_dst, cur2, E2C);
    block_sum<<<NB2, 256, 0, stream>>>(cur2, bs2, N2);
    scan_bsum<<<1, 256, 0, stream>>>(bs2, NB2);
    block_scan<<<NB2, 256, 0, stream>>>(cur2, bs2, rp2, N2);
    hipMemsetAsync(cur2, 0, N2 * sizeof(int), stream);
    fill_csr<<<(E2C + TB - 1) / TB, TB, 0, stream>>>(ei2_dst, rp2, cur2, eix2, E2C);
    // fused aggregation + epilogue -> d_out
    agg_layer2<<<(N2 + 3) / 4, TB, 0, stream>>>(rp2, eix2, ei2_src, et2, ets2,
        ta2, tb2, q2, k2, v2, xr2, Wbeta2, (float*)d_out, N2);
}

// Round 4
// 590.037 us; speedup vs baseline: 7.0858x; 1.1621x over previous
//
#include <hip/hip_runtime.h>
#include <math.h>

// Problem constants
#define N0 80000
#define N1 40000
#define N2 20000
#define E1C 500000
#define E2C 250000
#define NTYPE 23
#define NTS 1158

// ---------------- Workspace layout (float offsets) ----------------
// Layer 1 phase
#define OFF_Q1    0u           // N1*128 f32 = 5,120,000
#define OFF_KV1   5120000u     // N0*256 bf16 = 10,240,000 float-slots
#define OFF_XR1   15360000u    // N1*128 f32
#define OFF_H     20480000u    // N1*128 f32 (live through layer 2)
#define OFF_TA1   25600000u    // 23*128
#define OFF_TB1   25602944u    // 1158*128 -> ends 25,751,168
#define OFF_RP1   25800000u    // N1+1 ints
#define OFF_CUR1  25850000u    // N1 ints
#define OFF_EIX1  25900000u    // E1 ints -> ends 26,400,000
#define OFF_BS1   26450000u    // 256 ints
// Layer 2 phase overlays [0, OFF_H)
#define OFF_Q2    0u           // N2*128 f32 = 2,560,000
#define OFF_KV2   2560000u     // N1*256 bf16 = 5,120,000 float-slots
#define OFF_XR2   7680000u     // N2*64 f32
#define OFF_TA2   8960000u
#define OFF_TB2   8962944u
#define OFF_RP2   9200000u     // N2+1 ints
#define OFF_CUR2  9250000u     // N2 ints
#define OFF_EIX2  9300000u     // E2 ints
#define OFF_BS2   9600000u     // 256 ints
// total ws ≈ 26.45M floats ≈ 106 MB

static __device__ __forceinline__ float b2f(unsigned short u) {
    union { unsigned int i; float f; } c;
    c.i = ((unsigned int)u) << 16;
    return c.f;
}
static __device__ __forceinline__ unsigned short f2b(float f) {
    unsigned int u = __float_as_uint(f);
    unsigned int r = (u + 0x7fffu + ((u >> 16) & 1u)) >> 16;
    return (unsigned short)r;
}

// ---------------------------------------------------------------------------
// Tiled GEMM (f32 out): Y[n, NOUT] = X[n,128] @ W[NOUT,128]^T + b
// ---------------------------------------------------------------------------
template <int NOUT>
__global__ __launch_bounds__(256) void gemm_tile(const float* __restrict__ X,
                                                 const float* __restrict__ W,
                                                 const float* __restrict__ bias,
                                                 float* __restrict__ Y, int n) {
    constexpr int PAD = (NOUT == 128) ? 132 : 68;
    __shared__ float wt[128 * PAD];
    int tid = threadIdx.x;
    for (int idx = tid; idx < NOUT * 128; idx += 256) {
        int c = idx >> 7, k = idx & 127;
        wt[k * PAD + c] = W[idx];
    }
    __syncthreads();

    int cg = tid & 15, rg = tid >> 4;
    int row0 = blockIdx.x * 64;
    int r[4];
#pragma unroll
    for (int i = 0; i < 4; i++) {
        int rr = row0 + rg + 16 * i;
        r[i] = rr < n ? rr : (n - 1);
    }

    if constexpr (NOUT == 128) {
        float acc[4][8];
#pragma unroll
        for (int i = 0; i < 4; i++)
#pragma unroll
            for (int j = 0; j < 8; j++) acc[i][j] = 0.f;

        for (int k0 = 0; k0 < 128; k0 += 4) {
            float4 xv[4];
#pragma unroll
            for (int i = 0; i < 4; i++)
                xv[i] = *(const float4*)(X + (size_t)r[i] * 128 + k0);
#pragma unroll
            for (int kk = 0; kk < 4; kk++) {
                float4 w0 = *(const float4*)&wt[(k0 + kk) * PAD + 4 * cg];
                float4 w1 = *(const float4*)&wt[(k0 + kk) * PAD + 64 + 4 * cg];
#pragma unroll
                for (int i = 0; i < 4; i++) {
                    float xs = ((const float*)&xv[i])[kk];
                    acc[i][0] += xs * w0.x; acc[i][1] += xs * w0.y;
                    acc[i][2] += xs * w0.z; acc[i][3] += xs * w0.w;
                    acc[i][4] += xs * w1.x; acc[i][5] += xs * w1.y;
                    acc[i][6] += xs * w1.z; acc[i][7] += xs * w1.w;
                }
            }
        }
        float4 b0 = *(const float4*)&bias[4 * cg];
        float4 b1 = *(const float4*)&bias[64 + 4 * cg];
#pragma unroll
        for (int i = 0; i < 4; i++) {
            int rr = row0 + rg + 16 * i;
            if (rr < n) {
                float4 o0 = make_float4(acc[i][0] + b0.x, acc[i][1] + b0.y,
                                        acc[i][2] + b0.z, acc[i][3] + b0.w);
                float4 o1 = make_float4(acc[i][4] + b1.x, acc[i][5] + b1.y,
                                        acc[i][6] + b1.z, acc[i][7] + b1.w);
                *(float4*)(Y + (size_t)rr * 128 + 4 * cg) = o0;
                *(float4*)(Y + (size_t)rr * 128 + 64 + 4 * cg) = o1;
            }
        }
    } else {  // NOUT == 64
        float acc[4][4];
#pragma unroll
        for (int i = 0; i < 4; i++)
#pragma unroll
            for (int j = 0; j < 4; j++) acc[i][j] = 0.f;

        for (int k0 = 0; k0 < 128; k0 += 4) {
            float4 xv[4];
#pragma unroll
            for (int i = 0; i < 4; i++)
                xv[i] = *(const float4*)(X + (size_t)r[i] * 128 + k0);
#pragma unroll
            for (int kk = 0; kk < 4; kk++) {
                float4 w0 = *(const float4*)&wt[(k0 + kk) * PAD + 4 * cg];
#pragma unroll
                for (int i = 0; i < 4; i++) {
                    float xs = ((const float*)&xv[i])[kk];
                    acc[i][0] += xs * w0.x; acc[i][1] += xs * w0.y;
                    acc[i][2] += xs * w0.z; acc[i][3] += xs * w0.w;
                }
            }
        }
        float4 b0 = *(const float4*)&bias[4 * cg];
#pragma unroll
        for (int i = 0; i < 4; i++) {
            int rr = row0 + rg + 16 * i;
            if (rr < n) {
                float4 o0 = make_float4(acc[i][0] + b0.x, acc[i][1] + b0.y,
                                        acc[i][2] + b0.z, acc[i][3] + b0.w);
                *(float4*)(Y + (size_t)rr * 64 + 4 * cg) = o0;
            }
        }
    }
}

// ---------------------------------------------------------------------------
// Tiled GEMM writing bf16 into packed KV row [row*256 + COLOFS + col]
// ---------------------------------------------------------------------------
template <int COLOFS>
__global__ __launch_bounds__(256) void gemm_tile_kv(const float* __restrict__ X,
                                                    const float* __restrict__ W,
                                                    const float* __restrict__ bias,
                                                    unsigned short* __restrict__ KV, int n) {
    constexpr int PAD = 132;
    __shared__ float wt[128 * PAD];
    int tid = threadIdx.x;
    for (int idx = tid; idx < 128 * 128; idx += 256) {
        int c = idx >> 7, k = idx & 127;
        wt[k * PAD + c] = W[idx];
    }
    __syncthreads();

    int cg = tid & 15, rg = tid >> 4;
    int row0 = blockIdx.x * 64;
    int r[4];
#pragma unroll
    for (int i = 0; i < 4; i++) {
        int rr = row0 + rg + 16 * i;
        r[i] = rr < n ? rr : (n - 1);
    }
    float acc[4][8];
#pragma unroll
    for (int i = 0; i < 4; i++)
#pragma unroll
        for (int j = 0; j < 8; j++) acc[i][j] = 0.f;

    for (int k0 = 0; k0 < 128; k0 += 4) {
        float4 xv[4];
#pragma unroll
        for (int i = 0; i < 4; i++)
            xv[i] = *(const float4*)(X + (size_t)r[i] * 128 + k0);
#pragma unroll
        for (int kk = 0; kk < 4; kk++) {
            float4 w0 = *(const float4*)&wt[(k0 + kk) * PAD + 4 * cg];
            float4 w1 = *(const float4*)&wt[(k0 + kk) * PAD + 64 + 4 * cg];
#pragma unroll
            for (int i = 0; i < 4; i++) {
                float xs = ((const float*)&xv[i])[kk];
                acc[i][0] += xs * w0.x; acc[i][1] += xs * w0.y;
                acc[i][2] += xs * w0.z; acc[i][3] += xs * w0.w;
                acc[i][4] += xs * w1.x; acc[i][5] += xs * w1.y;
                acc[i][6] += xs * w1.z; acc[i][7] += xs * w1.w;
            }
        }
    }
    float4 b0 = *(const float4*)&bias[4 * cg];
    float4 b1 = *(const float4*)&bias[64 + 4 * cg];
#pragma unroll
    for (int i = 0; i < 4; i++) {
        int rr = row0 + rg + 16 * i;
        if (rr < n) {
            ushort4 p0, p1;
            p0.x = f2b(acc[i][0] + b0.x); p0.y = f2b(acc[i][1] + b0.y);
            p0.z = f2b(acc[i][2] + b0.z); p0.w = f2b(acc[i][3] + b0.w);
            p1.x = f2b(acc[i][4] + b1.x); p1.y = f2b(acc[i][5] + b1.y);
            p1.z = f2b(acc[i][6] + b1.z); p1.w = f2b(acc[i][7] + b1.w);
            unsigned short* row = KV + (size_t)rr * 256 + COLOFS;
            *(ushort4*)(row + 4 * cg) = p0;
            *(ushort4*)(row + 64 + 4 * cg) = p1;
        }
    }
}

// ---------------------------------------------------------------------------
// Edge-feature tables: e(et,ets)[c] = TA[et][c] + TB[ets][c]
// ---------------------------------------------------------------------------
__global__ void build_tables(const float* __restrict__ edge_W, const float* __restrict__ edge_b,
                             const float* __restrict__ time_W, const float* __restrict__ time_b,
                             const float* __restrict__ We,
                             float* __restrict__ TA, float* __restrict__ TB) {
    int t = blockIdx.x * blockDim.x + threadIdx.x;
    if (t < NTYPE * 128) {
        int e = t >> 7, c = t & 127;
        float s = 0.f;
#pragma unroll
        for (int j = 0; j < 10; j++)
            s += (edge_W[j * NTYPE + e] + edge_b[j]) * We[c * 20 + j];
        TA[t] = s;
    } else {
        int u = t - NTYPE * 128;
        if (u < NTS * 128) {
            int ts = u >> 7, c = u & 127;
            float s = 0.f;
#pragma unroll
            for (int j = 0; j < 10; j++)
                s += (time_W[j * NTS + ts] + time_b[j]) * We[c * 20 + 10 + j];
            TB[u] = s;
        }
    }
}

// ---------------------------------------------------------------------------
// CSR build: count -> block_sum -> scan_bsum -> block_scan -> fill
// ---------------------------------------------------------------------------
__global__ void count_kernel(const int* __restrict__ dst, int* __restrict__ cnt, int nedge) {
    int t = blockIdx.x * blockDim.x + threadIdx.x;
    if (t < nedge) atomicAdd(&cnt[dst[t]], 1);
}

__global__ void block_sum(const int* __restrict__ cnt, int* __restrict__ bsum, int n) {
    __shared__ int s[256];
    int t = blockIdx.x * 256 + threadIdx.x;
    s[threadIdx.x] = (t < n) ? cnt[t] : 0;
    __syncthreads();
    for (int off = 128; off; off >>= 1) {
        if (threadIdx.x < off) s[threadIdx.x] += s[threadIdx.x + off];
        __syncthreads();
    }
    if (threadIdx.x == 0) bsum[blockIdx.x] = s[0];
}

__global__ void scan_bsum(int* __restrict__ bsum, int nb) {
    __shared__ int s[256];
    int t = threadIdx.x;
    s[t] = (t < nb) ? bsum[t] : 0;
    __syncthreads();
    for (int off = 1; off < 256; off <<= 1) {
        int v = (t >= off) ? s[t - off] : 0;
        __syncthreads();
        s[t] += v;
        __syncthreads();
    }
    if (t < nb) bsum[t] = (t > 0) ? s[t - 1] : 0;
}

__global__ void block_scan(const int* __restrict__ cnt, const int* __restrict__ bsum,
                           int* __restrict__ rowptr, int n) {
    __shared__ int s[256];
    int t = blockIdx.x * 256 + threadIdx.x;
    int v = (t < n) ? cnt[t] : 0;
    s[threadIdx.x] = v;
    __syncthreads();
    for (int off = 1; off < 256; off <<= 1) {
        int u = (threadIdx.x >= off) ? s[threadIdx.x - off] : 0;
        __syncthreads();
        s[threadIdx.x] += u;
        __syncthreads();
    }
    int incl = s[threadIdx.x];
    int base = bsum[blockIdx.x];
    if (t < n) rowptr[t] = base + incl - v;
    if (t == n - 1) rowptr[n] = base + incl;
}

__global__ void fill_csr(const int* __restrict__ dst, const int* __restrict__ rowptr,
                         int* __restrict__ cursor, int* __restrict__ eidx, int nedge) {
    int t = blockIdx.x * blockDim.x + threadIdx.x;
    if (t >= nedge) return;
    int d = dst[t];
    int pos = rowptr[d] + atomicAdd(&cursor[d], 1);
    eidx[pos] = t;
}

// ---------------------------------------------------------------------------
// Fused aggregation. Wave layout: s=lane>>5 (edge parity), h=(lane>>4)&1
// (head), cg=lane&15 (4 channels each). 2 edges per iteration.
// ---------------------------------------------------------------------------
__global__ __launch_bounds__(256) void agg_layer1(
    const int* __restrict__ rowptr, const int* __restrict__ eidx,
    const int* __restrict__ src, const int* __restrict__ et, const int* __restrict__ ets,
    const float* __restrict__ TA, const float* __restrict__ TB,
    const float* __restrict__ Q, const unsigned short* __restrict__ KV,
    const float* __restrict__ xr, const float* __restrict__ Wbeta,
    const float* __restrict__ ln_g, const float* __restrict__ ln_b,
    float* __restrict__ hout, int n) {
    int wid = (blockIdx.x * blockDim.x + threadIdx.x) >> 6;
    int lane = threadIdx.x & 63;
    if (wid >= n) return;
    int s = lane >> 5, cg = lane & 15;
    int co = ((lane >> 4) & 1) * 64 + 4 * cg;     // channel offset in [0,128)
    int beg = rowptr[wid], end = rowptr[wid + 1];
    float4 q4 = *(const float4*)(Q + (size_t)wid * 128 + co);
    float ax = 0.f, ay = 0.f, az = 0.f, aw = 0.f, suma = 0.f;
    for (int p = beg + s; p < end; p += 2) {
        int e = eidx[p];
        int sn = src[e], t = et[e], ts = ets[e];
        float4 ta = *(const float4*)(TA + t * 128 + co);
        float4 tb = *(const float4*)(TB + ts * 128 + co);
        float e0 = ta.x + tb.x, e1 = ta.y + tb.y, e2 = ta.z + tb.z, e3 = ta.w + tb.w;
        const unsigned short* kv = KV + (size_t)sn * 256;
        ushort4 ku = *(const ushort4*)(kv + co);
        ushort4 vu = *(const ushort4*)(kv + 128 + co);
        float pp = q4.x * (b2f(ku.x) + e0) + q4.y * (b2f(ku.y) + e1)
                 + q4.z * (b2f(ku.z) + e2) + q4.w * (b2f(ku.w) + e3);
        pp += __shfl_xor(pp, 1); pp += __shfl_xor(pp, 2);
        pp += __shfl_xor(pp, 4); pp += __shfl_xor(pp, 8);
        float a = expf(pp * 0.125f);
        ax += a * (b2f(vu.x) + e0); ay += a * (b2f(vu.y) + e1);
        az += a * (b2f(vu.z) + e2); aw += a * (b2f(vu.w) + e3);
        suma += a;
    }
    // merge edge-parity subwaves
    ax += __shfl_xor(ax, 32); ay += __shfl_xor(ay, 32);
    az += __shfl_xor(az, 32); aw += __shfl_xor(aw, 32);
    suma += __shfl_xor(suma, 32);
    float inv_s = 1.f / (suma + 1e-16f);
    float ox = ax * inv_s, oy = ay * inv_s, oz = az * inv_s, ow = aw * inv_s;
    // ---- epilogue: beta gate + LN + GELU (each 32-lane subwave identical) ----
    float4 r4 = *(const float4*)(xr + (size_t)wid * 128 + co);
    float4 wo = *(const float4*)(Wbeta + co);
    float4 wr = *(const float4*)(Wbeta + 128 + co);
    float4 wd = *(const float4*)(Wbeta + 256 + co);
    float pb = wo.x * ox + wr.x * r4.x + wd.x * (ox - r4.x)
             + wo.y * oy + wr.y * r4.y + wd.y * (oy - r4.y)
             + wo.z * oz + wr.z * r4.z + wd.z * (oz - r4.z)
             + wo.w * ow + wr.w * r4.w + wd.w * (ow - r4.w);
    pb += __shfl_xor(pb, 1); pb += __shfl_xor(pb, 2); pb += __shfl_xor(pb, 4);
    pb += __shfl_xor(pb, 8); pb += __shfl_xor(pb, 16);
    float beta = 1.f / (1.f + expf(-pb));
    float gx = beta * r4.x + (1.f - beta) * ox;
    float gy = beta * r4.y + (1.f - beta) * oy;
    float gz = beta * r4.z + (1.f - beta) * oz;
    float gw = beta * r4.w + (1.f - beta) * ow;
    float sm = gx + gy + gz + gw;
    float sq = gx * gx + gy * gy + gz * gz + gw * gw;
    sm += __shfl_xor(sm, 1); sq += __shfl_xor(sq, 1);
    sm += __shfl_xor(sm, 2); sq += __shfl_xor(sq, 2);
    sm += __shfl_xor(sm, 4); sq += __shfl_xor(sq, 4);
    sm += __shfl_xor(sm, 8); sq += __shfl_xor(sq, 8);
    sm += __shfl_xor(sm, 16); sq += __shfl_xor(sq, 16);
    float mu = sm * (1.f / 128.f);
    float var = sq * (1.f / 128.f) - mu * mu;
    float inv = rsqrtf(var + 1e-5f);
    float4 lg = *(const float4*)(ln_g + co);
    float4 lb = *(const float4*)(ln_b + co);
    float yx = (gx - mu) * inv * lg.x + lb.x;
    float yy = (gy - mu) * inv * lg.y + lb.y;
    float yz = (gz - mu) * inv * lg.z + lb.z;
    float yw = (gw - mu) * inv * lg.w + lb.w;
    const float ISQ2 = 0.70710678118654752f;
    yx = 0.5f * yx * (1.f + erff(yx * ISQ2));
    yy = 0.5f * yy * (1.f + erff(yy * ISQ2));
    yz = 0.5f * yz * (1.f + erff(yz * ISQ2));
    yw = 0.5f * yw * (1.f + erff(yw * ISQ2));
    if (s == 0)
        *(float4*)(hout + (size_t)wid * 128 + co) = make_float4(yx, yy, yz, yw);
}

__global__ __launch_bounds__(256) void agg_layer2(
    const int* __restrict__ rowptr, const int* __restrict__ eidx,
    const int* __restrict__ src, const int* __restrict__ et, const int* __restrict__ ets,
    const float* __restrict__ TA, const float* __restrict__ TB,
    const float* __restrict__ Q, const unsigned short* __restrict__ KV,
    const float* __restrict__ xr, const float* __restrict__ Wbeta,
    float* __restrict__ o, int n) {
    int wid = (blockIdx.x * blockDim.x + threadIdx.x) >> 6;
    int lane = threadIdx.x & 63;
    if (wid >= n) return;
    int s = lane >> 5, cg = lane & 15;
    int co = ((lane >> 4) & 1) * 64 + 4 * cg;
    int beg = rowptr[wid], end = rowptr[wid + 1];
    float4 q4 = *(const float4*)(Q + (size_t)wid * 128 + co);
    float ax = 0.f, ay = 0.f, az = 0.f, aw = 0.f, suma = 0.f;
    for (int p = beg + s; p < end; p += 2) {
        int e = eidx[p];
        int sn = src[e], t = et[e], ts = ets[e];
        float4 ta = *(const float4*)(TA + t * 128 + co);
        float4 tb = *(const float4*)(TB + ts * 128 + co);
        float e0 = ta.x + tb.x, e1 = ta.y + tb.y, e2 = ta.z + tb.z, e3 = ta.w + tb.w;
        const unsigned short* kv = KV + (size_t)sn * 256;
        ushort4 ku = *(const ushort4*)(kv + co);
        ushort4 vu = *(const ushort4*)(kv + 128 + co);
        float pp = q4.x * (b2f(ku.x) + e0) + q4.y * (b2f(ku.y) + e1)
                 + q4.z * (b2f(ku.z) + e2) + q4.w * (b2f(ku.w) + e3);
        pp += __shfl_xor(pp, 1); pp += __shfl_xor(pp, 2);
        pp += __shfl_xor(pp, 4); pp += __shfl_xor(pp, 8);
        float a = expf(pp * 0.125f);
        ax += a * (b2f(vu.x) + e0); ay += a * (b2f(vu.y) + e1);
        az += a * (b2f(vu.z) + e2); aw += a * (b2f(vu.w) + e3);
        suma += a;
    }
    ax += __shfl_xor(ax, 32); ay += __shfl_xor(ay, 32);
    az += __shfl_xor(az, 32); aw += __shfl_xor(aw, 32);
    suma += __shfl_xor(suma, 32);
    float inv_s = 1.f / (suma + 1e-16f);
    float ox = ax * inv_s, oy = ay * inv_s, oz = az * inv_s, ow = aw * inv_s;
    // head mean: partner lane differs in h bit (xor 16)
    ox = 0.5f * (ox + __shfl_xor(ox, 16));
    oy = 0.5f * (oy + __shfl_xor(oy, 16));
    oz = 0.5f * (oz + __shfl_xor(oz, 16));
    ow = 0.5f * (ow + __shfl_xor(ow, 16));
    // ---- epilogue: beta gate + log_softmax over 64 channels (4*cg..) ----
    float4 r4 = *(const float4*)(xr + (size_t)wid * 64 + 4 * cg);
    float4 wo = *(const float4*)(Wbeta + 4 * cg);
    float4 wr = *(const float4*)(Wbeta + 64 + 4 * cg);
    float4 wd = *(const float4*)(Wbeta + 128 + 4 * cg);
    float pb = wo.x * ox + wr.x * r4.x + wd.x * (ox - r4.x)
             + wo.y * oy + wr.y * r4.y + wd.y * (oy - r4.y)
             + wo.z * oz + wr.z * r4.z + wd.z * (oz - r4.z)
             + wo.w * ow + wr.w * r4.w + wd.w * (ow - r4.w);
    pb += __shfl_xor(pb, 1); pb += __shfl_xor(pb, 2);
    pb += __shfl_xor(pb, 4); pb += __shfl_xor(pb, 8);
    float beta = 1.f / (1.f + expf(-pb));
    float vx = beta * r4.x + (1.f - beta) * ox;
    float vy = beta * r4.y + (1.f - beta) * oy;
    float vz = beta * r4.z + (1.f - beta) * oz;
    float vw = beta * r4.w + (1.f - beta) * ow;
    float m = fmaxf(fmaxf(vx, vy), fmaxf(vz, vw));
    m = fmaxf(m, __shfl_xor(m, 1)); m = fmaxf(m, __shfl_xor(m, 2));
    m = fmaxf(m, __shfl_xor(m, 4)); m = fmaxf(m, __shfl_xor(m, 8));
    float se = expf(vx - m) + expf(vy - m) + expf(vz - m) + expf(vw - m);
    se += __shfl_xor(se, 1); se += __shfl_xor(se, 2);
    se += __shfl_xor(se, 4); se += __shfl_xor(se, 8);
    float lse = m + logf(se);
    if (lane < 16)
        *(float4*)(o + (size_t)wid * 64 + 4 * cg) =
            make_float4(vx - lse, vy - lse, vz - lse, vw - lse);
}

extern "C" void kernel_launch(void* const* d_in, const int* in_sizes, int n_in,
                              void* d_out, int out_size, void* d_ws, size_t ws_size,
                              hipStream_t stream) {
    const float* x        = (const float*)d_in[0];
    const int*   ei1_src  = (const int*)d_in[1];
    const int*   ei1_dst  = (const int*)d_in[2];
    const int*   et1      = (const int*)d_in[3];
    const int*   ets1     = (const int*)d_in[4];
    const int*   ei2_src  = (const int*)d_in[5];
    const int*   ei2_dst  = (const int*)d_in[6];
    const int*   et2      = (const int*)d_in[7];
    const int*   ets2     = (const int*)d_in[8];
    const float* edge_W   = (const float*)d_in[9];
    const float* edge_b   = (const float*)d_in[10];
    const float* time_W   = (const float*)d_in[11];
    const float* time_b   = (const float*)d_in[12];
    const float* Wq1      = (const float*)d_in[13];
    const float* bq1      = (const float*)d_in[14];
    const float* Wk1      = (const float*)d_in[15];
    const float* bk1      = (const float*)d_in[16];
    const float* Wv1      = (const float*)d_in[17];
    const float* bv1      = (const float*)d_in[18];
    const float* We1      = (const float*)d_in[19];
    const float* Wskip1   = (const float*)d_in[20];
    const float* bskip1   = (const float*)d_in[21];
    const float* Wbeta1   = (const float*)d_in[22];
    const float* ln_g     = (const float*)d_in[23];
    const float* ln_b     = (const float*)d_in[24];
    const float* Wq2      = (const float*)d_in[25];
    const float* bq2      = (const float*)d_in[26];
    const float* Wk2      = (const float*)d_in[27];
    const float* bk2      = (const float*)d_in[28];
    const float* Wv2      = (const float*)d_in[29];
    const float* bv2      = (const float*)d_in[30];
    const float* We2      = (const float*)d_in[31];
    const float* Wskip2   = (const float*)d_in[32];
    const float* bskip2   = (const float*)d_in[33];
    const float* Wbeta2   = (const float*)d_in[34];

    float* ws = (float*)d_ws;
    float* q1            = ws + OFF_Q1;
    unsigned short* kv1  = (unsigned short*)(ws + OFF_KV1);
    float* xr1           = ws + OFF_XR1;
    float* h             = ws + OFF_H;
    float* ta1           = ws + OFF_TA1;
    float* tb1           = ws + OFF_TB1;
    int*   rp1           = (int*)(ws + OFF_RP1);
    int*   cur1          = (int*)(ws + OFF_CUR1);
    int*   eix1          = (int*)(ws + OFF_EIX1);
    int*   bs1           = (int*)(ws + OFF_BS1);
    float* q2            = ws + OFF_Q2;
    unsigned short* kv2  = (unsigned short*)(ws + OFF_KV2);
    float* xr2           = ws + OFF_XR2;
    float* ta2           = ws + OFF_TA2;
    float* tb2           = ws + OFF_TB2;
    int*   rp2           = (int*)(ws + OFF_RP2);
    int*   cur2          = (int*)(ws + OFF_CUR2);
    int*   eix2          = (int*)(ws + OFF_EIX2);
    int*   bs2           = (int*)(ws + OFF_BS2);

    const int TB = 256;
    const int TBL_THREADS = (NTYPE + NTS) * 128;
    const int NB1 = (N1 + 255) / 256;
    const int NB2 = (N2 + 255) / 256;

    // ================= Layer 1 =================
    build_tables<<<(TBL_THREADS + TB - 1) / TB, TB, 0, stream>>>(
        edge_W, edge_b, time_W, time_b, We1, ta1, tb1);
    gemm_tile<128><<<(N1 + 63) / 64, TB, 0, stream>>>(x, Wq1, bq1, q1, N1);
    gemm_tile_kv<0><<<(N0 + 63) / 64, TB, 0, stream>>>(x, Wk1, bk1, kv1, N0);
    gemm_tile_kv<128><<<(N0 + 63) / 64, TB, 0, stream>>>(x, Wv1, bv1, kv1, N0);
    gemm_tile<128><<<(N1 + 63) / 64, TB, 0, stream>>>(x, Wskip1, bskip1, xr1, N1);
    hipMemsetAsync(cur1, 0, N1 * sizeof(int), stream);
    count_kernel<<<(E1C + TB - 1) / TB, TB, 0, stream>>>(ei1_dst, cur1, E1C);
    block_sum<<<NB1, 256, 0, stream>>>(cur1, bs1, N1);
    scan_bsum<<<1, 256, 0, stream>>>(bs1, NB1);
    block_scan<<<NB1, 256, 0, stream>>>(cur1, bs1, rp1, N1);
    hipMemsetAsync(cur1, 0, N1 * sizeof(int), stream);
    fill_csr<<<(E1C + TB - 1) / TB, TB, 0, stream>>>(ei1_dst, rp1, cur1, eix1, E1C);
    agg_layer1<<<(N1 + 3) / 4, TB, 0, stream>>>(rp1, eix1, ei1_src, et1, ets1,
        ta1, tb1, q1, kv1, xr1, Wbeta1, ln_g, ln_b, h, N1);

    // ================= Layer 2 =================
    build_tables<<<(TBL_THREADS + TB - 1) / TB, TB, 0, stream>>>(
        edge_W, edge_b, time_W, time_b, We2, ta2, tb2);
    gemm_tile<128><<<(N2 + 63) / 64, TB, 0, stream>>>(h, Wq2, bq2, q2, N2);
    gemm_tile_kv<0><<<(N1 + 63) / 64, TB, 0, stream>>>(h, Wk2, bk2, kv2, N1);
    gemm_tile_kv<128><<<(N1 + 63) / 64, TB, 0, stream>>>(h, Wv2, bv2, kv2, N1);
    gemm_tile<64><<<(N2 + 63) / 64, TB, 0, stream>>>(h, Wskip2, bskip2, xr2, N2);
    hipMemsetAsync(cur2, 0, N2 * sizeof(int), stream);
    count_kernel<<<(E2C + TB - 1) / TB, TB, 0, stream>>>(ei2_dst, cur2, E2C);
    block_sum<<<NB2, 256, 0, stream>>>(cur2, bs2, N2);
    scan_bsum<<<1, 256, 0, stream>>>(bs2, NB2);
    block_scan<<<NB2, 256, 0, stream>>>(cur2, bs2, rp2, N2);
    hipMemsetAsync(cur2, 0, N2 * sizeof(int), stream);
    fill_csr<<<(E2C + TB - 1) / TB, TB, 0, stream>>>(ei2_dst, rp2, cur2, eix2, E2C);
    agg_layer2<<<(N2 + 3) / 4, TB, 0, stream>>>(rp2, eix2, ei2_src, et2, ets2,
        ta2, tb2, q2, kv2, xr2, Wbeta2, (float*)d_out, N2);
}

// Round 5
// 521.599 us; speedup vs baseline: 8.0155x; 1.1312x over previous
//
#include <hip/hip_runtime.h>
#include <math.h>

// Problem constants
#define N0 80000
#define N1 40000
#define N2 20000
#define E1C 500000
#define E2C 250000
#define NTYPE 23
#define NTS 1158

// ---------------- Workspace layout (float offsets), no overlays ----------------
#define OFF_XB    0u           // N0*128 bf16 = 5,120,000 slots
#define OFF_QR1   5120000u     // N1*256 f32 (q|xr) = 10,240,000
#define OFF_KV1   15360000u    // N0*256 bf16 = 10,240,000 slots
#define OFF_H     25600000u    // N1*128 bf16 = 2,560,000 slots
#define OFF_QR2   28160000u    // N2*192 f32 = 3,840,000
#define OFF_KV2   32000000u    // N1*256 bf16 = 5,120,000 slots
#define OFF_WB1   37120000u    // 512*128 bf16 = 32,768 slots
#define OFF_BP1   37160000u    // 512 f32
#define OFF_WB2   37170000u    // 448*128 bf16 = 28,672 slots
#define OFF_BP2   37200000u    // 448 f32
#define OFF_TA1   37210000u    // 23*128 = 2944
#define OFF_TB1   37213000u    // 1158*128 = 148,224 -> ends 37,361,224
#define OFF_TA2   37370000u
#define OFF_TB2   37373000u    // ends 37,521,224
#define OFF_RP1   37530000u    // N1+1 ints
#define OFF_CUR1  37580000u    // N1 ints
#define OFF_EIX1  37630000u    // E1 ints -> ends 38,130,000
#define OFF_BS1   38140000u    // 256 ints
#define OFF_RP2   38150000u    // N2+1 ints
#define OFF_CUR2  38180000u    // N2 ints
#define OFF_EIX2  38210000u    // E2 ints -> ends 38,460,000
#define OFF_BS2   38470000u
// total ≈ 38.47M floats ≈ 154 MB (round-1 used 168 MB OK)

typedef __bf16 bf16x8 __attribute__((ext_vector_type(8)));
typedef float f32x4 __attribute__((ext_vector_type(4)));

static __device__ __forceinline__ float b2f(unsigned short u) {
    union { unsigned int i; float f; } c;
    c.i = ((unsigned int)u) << 16;
    return c.f;
}
static __device__ __forceinline__ unsigned short f2b(float f) {
    unsigned int u = __float_as_uint(f);
    unsigned int r = (u + 0x7fffu + ((u >> 16) & 1u)) >> 16;
    return (unsigned short)r;
}
static __device__ __forceinline__ bf16x8 ldfrag(const unsigned short* p) {
    return *reinterpret_cast<const bf16x8*>(p);
}

// ---------------------------------------------------------------------------
// MFMA GEMM, bf16 output (KV): Y[n][NTILES*16] = XB[n][128] @ WB^T + BP
// Block 256 = 4 waves x 16 rows. LDS repack for coalesced bf16 stores.
// ---------------------------------------------------------------------------
template <int NTILES>
__global__ __launch_bounds__(256) void gemm_mfma_bf16out(
    const unsigned short* __restrict__ XB, const unsigned short* __restrict__ WB,
    const float* __restrict__ BP, unsigned short* __restrict__ Y, int n) {
    constexpr int COLS = NTILES * 16;
    constexpr int LDSS = COLS + 8;
    __shared__ unsigned short sbuf[4][16 * LDSS];
    int wave = threadIdx.x >> 6, lane = threadIdx.x & 63;
    int m = lane & 15, quad = lane >> 4;
    int rowbase = blockIdx.x * 64 + wave * 16;
    int arow = rowbase + m; if (arow >= n) arow = n - 1;
    const unsigned short* xrow = XB + (size_t)arow * 128 + quad * 8;
    bf16x8 a0 = ldfrag(xrow), a1 = ldfrag(xrow + 32);
    bf16x8 a2 = ldfrag(xrow + 64), a3 = ldfrag(xrow + 96);
    f32x4 acc[NTILES];
#pragma unroll
    for (int t = 0; t < NTILES; t++) acc[t] = (f32x4){0.f, 0.f, 0.f, 0.f};
#pragma unroll
    for (int t = 0; t < NTILES; t++) {
        const unsigned short* wrow = WB + (size_t)(t * 16 + m) * 128 + quad * 8;
        acc[t] = __builtin_amdgcn_mfma_f32_16x16x32_bf16(a0, ldfrag(wrow), acc[t], 0, 0, 0);
        acc[t] = __builtin_amdgcn_mfma_f32_16x16x32_bf16(a1, ldfrag(wrow + 32), acc[t], 0, 0, 0);
        acc[t] = __builtin_amdgcn_mfma_f32_16x16x32_bf16(a2, ldfrag(wrow + 64), acc[t], 0, 0, 0);
        acc[t] = __builtin_amdgcn_mfma_f32_16x16x32_bf16(a3, ldfrag(wrow + 96), acc[t], 0, 0, 0);
    }
#pragma unroll
    for (int t = 0; t < NTILES; t++) {
        float b = BP[t * 16 + m];
#pragma unroll
        for (int r = 0; r < 4; r++)
            sbuf[wave][(quad * 4 + r) * LDSS + t * 16 + m] = f2b(acc[t][r] + b);
    }
    // per-wave LDS, no cross-wave sharing -> no barrier needed
    for (int i = lane; i < 16 * (COLS / 8); i += 64) {
        int r = i / (COLS / 8), g = i % (COLS / 8);
        int grow = rowbase + r;
        if (grow < n) {
            uint4 v = *(const uint4*)&sbuf[wave][r * LDSS + g * 8];
            *(uint4*)(Y + (size_t)grow * COLS + g * 8) = v;
        }
    }
}

// ---------------------------------------------------------------------------
// MFMA GEMM, f32 output (QR): direct stores
// ---------------------------------------------------------------------------
template <int NTILES>
__global__ __launch_bounds__(256) void gemm_mfma_f32out(
    const unsigned short* __restrict__ XB, const unsigned short* __restrict__ WB,
    const float* __restrict__ BP, float* __restrict__ Y, int n) {
    constexpr int COLS = NTILES * 16;
    int wave = threadIdx.x >> 6, lane = threadIdx.x & 63;
    int m = lane & 15, quad = lane >> 4;
    int rowbase = blockIdx.x * 64 + wave * 16;
    int arow = rowbase + m; if (arow >= n) arow = n - 1;
    const unsigned short* xrow = XB + (size_t)arow * 128 + quad * 8;
    bf16x8 a0 = ldfrag(xrow), a1 = ldfrag(xrow + 32);
    bf16x8 a2 = ldfrag(xrow + 64), a3 = ldfrag(xrow + 96);
    f32x4 acc[NTILES];
#pragma unroll
    for (int t = 0; t < NTILES; t++) acc[t] = (f32x4){0.f, 0.f, 0.f, 0.f};
#pragma unroll
    for (int t = 0; t < NTILES; t++) {
        const unsigned short* wrow = WB + (size_t)(t * 16 + m) * 128 + quad * 8;
        acc[t] = __builtin_amdgcn_mfma_f32_16x16x32_bf16(a0, ldfrag(wrow), acc[t], 0, 0, 0);
        acc[t] = __builtin_amdgcn_mfma_f32_16x16x32_bf16(a1, ldfrag(wrow + 32), acc[t], 0, 0, 0);
        acc[t] = __builtin_amdgcn_mfma_f32_16x16x32_bf16(a2, ldfrag(wrow + 64), acc[t], 0, 0, 0);
        acc[t] = __builtin_amdgcn_mfma_f32_16x16x32_bf16(a3, ldfrag(wrow + 96), acc[t], 0, 0, 0);
    }
#pragma unroll
    for (int t = 0; t < NTILES; t++) {
        float b = BP[t * 16 + m];
#pragma unroll
        for (int r = 0; r < 4; r++) {
            int grow = rowbase + quad * 4 + r;
            if (grow < n) Y[(size_t)grow * COLS + t * 16 + m] = acc[t][r] + b;
        }
    }
}

// ---------------------------------------------------------------------------
// Conversions / packing
// ---------------------------------------------------------------------------
__global__ void conv_bf16(const float* __restrict__ X, unsigned short* __restrict__ XB, int n4) {
    int t = blockIdx.x * blockDim.x + threadIdx.x;
    if (t >= n4) return;
    float4 v = *(const float4*)(X + (size_t)t * 4);
    ushort4 u;
    u.x = f2b(v.x); u.y = f2b(v.y); u.z = f2b(v.z); u.w = f2b(v.w);
    *(ushort4*)(XB + (size_t)t * 4) = u;
}

struct PackArgs {
    const float *w0, *w1, *w2, *w3;
    const float *b0, *b1, *b2, *b3;
    int r0, r1, r2, r3;
};
__global__ void pack_weights(PackArgs pa, unsigned short* __restrict__ WB, float* __restrict__ BP) {
    int total = pa.r0 + pa.r1 + pa.r2 + pa.r3;
    int t = blockIdx.x * blockDim.x + threadIdx.x;
    if (t < total) {
        const float* b; int off;
        if (t < pa.r0) { b = pa.b0; off = 0; }
        else if (t < pa.r0 + pa.r1) { b = pa.b1; off = pa.r0; }
        else if (t < pa.r0 + pa.r1 + pa.r2) { b = pa.b2; off = pa.r0 + pa.r1; }
        else { b = pa.b3; off = pa.r0 + pa.r1 + pa.r2; }
        BP[t] = b[t - off];
    }
    if (t < total * 128) {
        int row = t >> 7, c = t & 127;
        const float* w; int off;
        if (row < pa.r0) { w = pa.w0; off = 0; }
        else if (row < pa.r0 + pa.r1) { w = pa.w1; off = pa.r0; }
        else if (row < pa.r0 + pa.r1 + pa.r2) { w = pa.w2; off = pa.r0 + pa.r1; }
        else { w = pa.w3; off = pa.r0 + pa.r1 + pa.r2; }
        WB[t] = f2b(w[(size_t)(row - off) * 128 + c]);
    }
}

// ---------------------------------------------------------------------------
// Edge-feature tables
// ---------------------------------------------------------------------------
__global__ void build_tables(const float* __restrict__ edge_W, const float* __restrict__ edge_b,
                             const float* __restrict__ time_W, const float* __restrict__ time_b,
                             const float* __restrict__ We,
                             float* __restrict__ TA, float* __restrict__ TB) {
    int t = blockIdx.x * blockDim.x + threadIdx.x;
    if (t < NTYPE * 128) {
        int e = t >> 7, c = t & 127;
        float s = 0.f;
#pragma unroll
        for (int j = 0; j < 10; j++)
            s += (edge_W[j * NTYPE + e] + edge_b[j]) * We[c * 20 + j];
        TA[t] = s;
    } else {
        int u = t - NTYPE * 128;
        if (u < NTS * 128) {
            int ts = u >> 7, c = u & 127;
            float s = 0.f;
#pragma unroll
            for (int j = 0; j < 10; j++)
                s += (time_W[j * NTS + ts] + time_b[j]) * We[c * 20 + 10 + j];
            TB[u] = s;
        }
    }
}

// ---------------------------------------------------------------------------
// CSR build
// ---------------------------------------------------------------------------
__global__ void count_kernel(const int* __restrict__ dst, int* __restrict__ cnt, int nedge) {
    int t = blockIdx.x * blockDim.x + threadIdx.x;
    if (t < nedge) atomicAdd(&cnt[dst[t]], 1);
}

__global__ void block_sum(const int* __restrict__ cnt, int* __restrict__ bsum, int n) {
    __shared__ int s[256];
    int t = blockIdx.x * 256 + threadIdx.x;
    s[threadIdx.x] = (t < n) ? cnt[t] : 0;
    __syncthreads();
    for (int off = 128; off; off >>= 1) {
        if (threadIdx.x < off) s[threadIdx.x] += s[threadIdx.x + off];
        __syncthreads();
    }
    if (threadIdx.x == 0) bsum[blockIdx.x] = s[0];
}

__global__ void scan_bsum(int* __restrict__ bsum, int nb) {
    __shared__ int s[256];
    int t = threadIdx.x;
    s[t] = (t < nb) ? bsum[t] : 0;
    __syncthreads();
    for (int off = 1; off < 256; off <<= 1) {
        int v = (t >= off) ? s[t - off] : 0;
        __syncthreads();
        s[t] += v;
        __syncthreads();
    }
    if (t < nb) bsum[t] = (t > 0) ? s[t - 1] : 0;
}

__global__ void block_scan(const int* __restrict__ cnt, const int* __restrict__ bsum,
                           int* __restrict__ rowptr, int n) {
    __shared__ int s[256];
    int t = blockIdx.x * 256 + threadIdx.x;
    int v = (t < n) ? cnt[t] : 0;
    s[threadIdx.x] = v;
    __syncthreads();
    for (int off = 1; off < 256; off <<= 1) {
        int u = (threadIdx.x >= off) ? s[threadIdx.x - off] : 0;
        __syncthreads();
        s[threadIdx.x] += u;
        __syncthreads();
    }
    int incl = s[threadIdx.x];
    int base = bsum[blockIdx.x];
    if (t < n) rowptr[t] = base + incl - v;
    if (t == n - 1) rowptr[n] = base + incl;
}

__global__ void fill_csr(const int* __restrict__ dst, const int* __restrict__ rowptr,
                         int* __restrict__ cursor, int* __restrict__ eidx, int nedge) {
    int t = blockIdx.x * blockDim.x + threadIdx.x;
    if (t >= nedge) return;
    int d = dst[t];
    int pos = rowptr[d] + atomicAdd(&cursor[d], 1);
    eidx[pos] = t;
}

// ---------------------------------------------------------------------------
// Fused aggregation. Wave layout: s=lane>>5 (edge parity), h=(lane>>4)&1,
// cg=lane&15. QR row: [q(128) | xr(128)] f32. Writes h as bf16.
// ---------------------------------------------------------------------------
__global__ __launch_bounds__(256) void agg_layer1(
    const int* __restrict__ rowptr, const int* __restrict__ eidx,
    const int* __restrict__ src, const int* __restrict__ et, const int* __restrict__ ets,
    const float* __restrict__ TA, const float* __restrict__ TB,
    const float* __restrict__ QR, const unsigned short* __restrict__ KV,
    const float* __restrict__ Wbeta,
    const float* __restrict__ ln_g, const float* __restrict__ ln_b,
    unsigned short* __restrict__ hout, int n) {
    int wid = (blockIdx.x * blockDim.x + threadIdx.x) >> 6;
    int lane = threadIdx.x & 63;
    if (wid >= n) return;
    int s = lane >> 5, cg = lane & 15;
    int co = ((lane >> 4) & 1) * 64 + 4 * cg;
    int beg = rowptr[wid], end = rowptr[wid + 1];
    float4 q4 = *(const float4*)(QR + (size_t)wid * 256 + co);
    float ax = 0.f, ay = 0.f, az = 0.f, aw = 0.f, suma = 0.f;
    for (int p = beg + s; p < end; p += 2) {
        int e = eidx[p];
        int sn = src[e], t = et[e], ts = ets[e];
        float4 ta = *(const float4*)(TA + t * 128 + co);
        float4 tb = *(const float4*)(TB + ts * 128 + co);
        float e0 = ta.x + tb.x, e1 = ta.y + tb.y, e2 = ta.z + tb.z, e3 = ta.w + tb.w;
        const unsigned short* kv = KV + (size_t)sn * 256;
        ushort4 ku = *(const ushort4*)(kv + co);
        ushort4 vu = *(const ushort4*)(kv + 128 + co);
        float pp = q4.x * (b2f(ku.x) + e0) + q4.y * (b2f(ku.y) + e1)
                 + q4.z * (b2f(ku.z) + e2) + q4.w * (b2f(ku.w) + e3);
        pp += __shfl_xor(pp, 1); pp += __shfl_xor(pp, 2);
        pp += __shfl_xor(pp, 4); pp += __shfl_xor(pp, 8);
        float a = expf(pp * 0.125f);
        ax += a * (b2f(vu.x) + e0); ay += a * (b2f(vu.y) + e1);
        az += a * (b2f(vu.z) + e2); aw += a * (b2f(vu.w) + e3);
        suma += a;
    }
    ax += __shfl_xor(ax, 32); ay += __shfl_xor(ay, 32);
    az += __shfl_xor(az, 32); aw += __shfl_xor(aw, 32);
    suma += __shfl_xor(suma, 32);
    float inv_s = 1.f / (suma + 1e-16f);
    float ox = ax * inv_s, oy = ay * inv_s, oz = az * inv_s, ow = aw * inv_s;
    float4 r4 = *(const float4*)(QR + (size_t)wid * 256 + 128 + co);
    float4 wo = *(const float4*)(Wbeta + co);
    float4 wr = *(const float4*)(Wbeta + 128 + co);
    float4 wd = *(const float4*)(Wbeta + 256 + co);
    float pb = wo.x * ox + wr.x * r4.x + wd.x * (ox - r4.x)
             + wo.y * oy + wr.y * r4.y + wd.y * (oy - r4.y)
             + wo.z * oz + wr.z * r4.z + wd.z * (oz - r4.z)
             + wo.w * ow + wr.w * r4.w + wd.w * (ow - r4.w);
    pb += __shfl_xor(pb, 1); pb += __shfl_xor(pb, 2); pb += __shfl_xor(pb, 4);
    pb += __shfl_xor(pb, 8); pb += __shfl_xor(pb, 16);
    float beta = 1.f / (1.f + expf(-pb));
    float gx = beta * r4.x + (1.f - beta) * ox;
    float gy = beta * r4.y + (1.f - beta) * oy;
    float gz = beta * r4.z + (1.f - beta) * oz;
    float gw = beta * r4.w + (1.f - beta) * ow;
    float sm = gx + gy + gz + gw;
    float sq = gx * gx + gy * gy + gz * gz + gw * gw;
    sm += __shfl_xor(sm, 1); sq += __shfl_xor(sq, 1);
    sm += __shfl_xor(sm, 2); sq += __shfl_xor(sq, 2);
    sm += __shfl_xor(sm, 4); sq += __shfl_xor(sq, 4);
    sm += __shfl_xor(sm, 8); sq += __shfl_xor(sq, 8);
    sm += __shfl_xor(sm, 16); sq += __shfl_xor(sq, 16);
    float mu = sm * (1.f / 128.f);
    float var = sq * (1.f / 128.f) - mu * mu;
    float inv = rsqrtf(var + 1e-5f);
    float4 lg = *(const float4*)(ln_g + co);
    float4 lb = *(const float4*)(ln_b + co);
    float yx = (gx - mu) * inv * lg.x + lb.x;
    float yy = (gy - mu) * inv * lg.y + lb.y;
    float yz = (gz - mu) * inv * lg.z + lb.z;
    float yw = (gw - mu) * inv * lg.w + lb.w;
    const float ISQ2 = 0.70710678118654752f;
    yx = 0.5f * yx * (1.f + erff(yx * ISQ2));
    yy = 0.5f * yy * (1.f + erff(yy * ISQ2));
    yz = 0.5f * yz * (1.f + erff(yz * ISQ2));
    yw = 0.5f * yw * (1.f + erff(yw * ISQ2));
    if (s == 0) {
        ushort4 hv;
        hv.x = f2b(yx); hv.y = f2b(yy); hv.z = f2b(yz); hv.w = f2b(yw);
        *(ushort4*)(hout + (size_t)wid * 128 + co) = hv;
    }
}

__global__ __launch_bounds__(256) void agg_layer2(
    const int* __restrict__ rowptr, const int* __restrict__ eidx,
    const int* __restrict__ src, const int* __restrict__ et, const int* __restrict__ ets,
    const float* __restrict__ TA, const float* __restrict__ TB,
    const float* __restrict__ QR, const unsigned short* __restrict__ KV,
    const float* __restrict__ Wbeta,
    float* __restrict__ o, int n) {
    int wid = (blockIdx.x * blockDim.x + threadIdx.x) >> 6;
    int lane = threadIdx.x & 63;
    if (wid >= n) return;
    int s = lane >> 5, cg = lane & 15;
    int co = ((lane >> 4) & 1) * 64 + 4 * cg;
    int beg = rowptr[wid], end = rowptr[wid + 1];
    float4 q4 = *(const float4*)(QR + (size_t)wid * 192 + co);
    float ax = 0.f, ay = 0.f, az = 0.f, aw = 0.f, suma = 0.f;
    for (int p = beg + s; p < end; p += 2) {
        int e = eidx[p];
        int sn = src[e], t = et[e], ts = ets[e];
        float4 ta = *(const float4*)(TA + t * 128 + co);
        float4 tb = *(const float4*)(TB + ts * 128 + co);
        float e0 = ta.x + tb.x, e1 = ta.y + tb.y, e2 = ta.z + tb.z, e3 = ta.w + tb.w;
        const unsigned short* kv = KV + (size_t)sn * 256;
        ushort4 ku = *(const ushort4*)(kv + co);
        ushort4 vu = *(const ushort4*)(kv + 128 + co);
        float pp = q4.x * (b2f(ku.x) + e0) + q4.y * (b2f(ku.y) + e1)
                 + q4.z * (b2f(ku.z) + e2) + q4.w * (b2f(ku.w) + e3);
        pp += __shfl_xor(pp, 1); pp += __shfl_xor(pp, 2);
        pp += __shfl_xor(pp, 4); pp += __shfl_xor(pp, 8);
        float a = expf(pp * 0.125f);
        ax += a * (b2f(vu.x) + e0); ay += a * (b2f(vu.y) + e1);
        az += a * (b2f(vu.z) + e2); aw += a * (b2f(vu.w) + e3);
        suma += a;
    }
    ax += __shfl_xor(ax, 32); ay += __shfl_xor(ay, 32);
    az += __shfl_xor(az, 32); aw += __shfl_xor(aw, 32);
    suma += __shfl_xor(suma, 32);
    float inv_s = 1.f / (suma + 1e-16f);
    float ox = ax * inv_s, oy = ay * inv_s, oz = az * inv_s, ow = aw * inv_s;
    ox = 0.5f * (ox + __shfl_xor(ox, 16));
    oy = 0.5f * (oy + __shfl_xor(oy, 16));
    oz = 0.5f * (oz + __shfl_xor(oz, 16));
    ow = 0.5f * (ow + __shfl_xor(ow, 16));
    float4 r4 = *(const float4*)(QR + (size_t)wid * 192 + 128 + 4 * cg);
    float4 wo = *(const float4*)(Wbeta + 4 * cg);
    float4 wr = *(const float4*)(Wbeta + 64 + 4 * cg);
    float4 wd = *(const float4*)(Wbeta + 128 + 4 * cg);
    float pb = wo.x * ox + wr.x * r4.x + wd.x * (ox - r4.x)
             + wo.y * oy + wr.y * r4.y + wd.y * (oy - r4.y)
             + wo.z * oz + wr.z * r4.z + wd.z * (oz - r4.z)
             + wo.w * ow + wr.w * r4.w + wd.w * (ow - r4.w);
    pb += __shfl_xor(pb, 1); pb += __shfl_xor(pb, 2);
    pb += __shfl_xor(pb, 4); pb += __shfl_xor(pb, 8);
    float beta = 1.f / (1.f + expf(-pb));
    float vx = beta * r4.x + (1.f - beta) * ox;
    float vy = beta * r4.y + (1.f - beta) * oy;
    float vz = beta * r4.z + (1.f - beta) * oz;
    float vw = beta * r4.w + (1.f - beta) * ow;
    float m = fmaxf(fmaxf(vx, vy), fmaxf(vz, vw));
    m = fmaxf(m, __shfl_xor(m, 1)); m = fmaxf(m, __shfl_xor(m, 2));
    m = fmaxf(m, __shfl_xor(m, 4)); m = fmaxf(m, __shfl_xor(m, 8));
    float se = expf(vx - m) + expf(vy - m) + expf(vz - m) + expf(vw - m);
    se += __shfl_xor(se, 1); se += __shfl_xor(se, 2);
    se += __shfl_xor(se, 4); se += __shfl_xor(se, 8);
    float lse = m + logf(se);
    if (lane < 16)
        *(float4*)(o + (size_t)wid * 64 + 4 * cg) =
            make_float4(vx - lse, vy - lse, vz - lse, vw - lse);
}

extern "C" void kernel_launch(void* const* d_in, const int* in_sizes, int n_in,
                              void* d_out, int out_size, void* d_ws, size_t ws_size,
                              hipStream_t stream) {
    const float* x        = (const float*)d_in[0];
    const int*   ei1_src  = (const int*)d_in[1];
    const int*   ei1_dst  = (const int*)d_in[2];
    const int*   et1      = (const int*)d_in[3];
    const int*   ets1     = (const int*)d_in[4];
    const int*   ei2_src  = (const int*)d_in[5];
    const int*   ei2_dst  = (const int*)d_in[6];
    const int*   et2      = (const int*)d_in[7];
    const int*   ets2     = (const int*)d_in[8];
    const float* edge_W   = (const float*)d_in[9];
    const float* edge_b   = (const float*)d_in[10];
    const float* time_W   = (const float*)d_in[11];
    const float* time_b   = (const float*)d_in[12];
    const float* Wq1      = (const float*)d_in[13];
    const float* bq1      = (const float*)d_in[14];
    const float* Wk1      = (const float*)d_in[15];
    const float* bk1      = (const float*)d_in[16];
    const float* Wv1      = (const float*)d_in[17];
    const float* bv1      = (const float*)d_in[18];
    const float* We1      = (const float*)d_in[19];
    const float* Wskip1   = (const float*)d_in[20];
    const float* bskip1   = (const float*)d_in[21];
    const float* Wbeta1   = (const float*)d_in[22];
    const float* ln_g     = (const float*)d_in[23];
    const float* ln_b     = (const float*)d_in[24];
    const float* Wq2      = (const float*)d_in[25];
    const float* bq2      = (const float*)d_in[26];
    const float* Wk2      = (const float*)d_in[27];
    const float* bk2      = (const float*)d_in[28];
    const float* Wv2      = (const float*)d_in[29];
    const float* bv2      = (const float*)d_in[30];
    const float* We2      = (const float*)d_in[31];
    const float* Wskip2   = (const float*)d_in[32];
    const float* bskip2   = (const float*)d_in[33];
    const float* Wbeta2   = (const float*)d_in[34];

    float* ws = (float*)d_ws;
    unsigned short* xb  = (unsigned short*)(ws + OFF_XB);
    float* qr1          = ws + OFF_QR1;
    unsigned short* kv1 = (unsigned short*)(ws + OFF_KV1);
    unsigned short* h   = (unsigned short*)(ws + OFF_H);
    float* qr2          = ws + OFF_QR2;
    unsigned short* kv2 = (unsigned short*)(ws + OFF_KV2);
    unsigned short* wb1 = (unsigned short*)(ws + OFF_WB1);
    float* bp1          = ws + OFF_BP1;
    unsigned short* wb2 = (unsigned short*)(ws + OFF_WB2);
    float* bp2          = ws + OFF_BP2;
    float* ta1          = ws + OFF_TA1;
    float* tb1          = ws + OFF_TB1;
    float* ta2          = ws + OFF_TA2;
    float* tb2          = ws + OFF_TB2;
    int*   rp1          = (int*)(ws + OFF_RP1);
    int*   cur1         = (int*)(ws + OFF_CUR1);
    int*   eix1         = (int*)(ws + OFF_EIX1);
    int*   bs1          = (int*)(ws + OFF_BS1);
    int*   rp2          = (int*)(ws + OFF_RP2);
    int*   cur2         = (int*)(ws + OFF_CUR2);
    int*   eix2         = (int*)(ws + OFF_EIX2);
    int*   bs2          = (int*)(ws + OFF_BS2);

    const int TB = 256;
    const int TBL_THREADS = (NTYPE + NTS) * 128;
    const int NB1 = (N1 + 255) / 256;
    const int NB2 = (N2 + 255) / 256;

    // ---- weight packing: [k | v | q | skip] per layer ----
    PackArgs pa1 = { Wk1, Wv1, Wq1, Wskip1, bk1, bv1, bq1, bskip1, 128, 128, 128, 128 };
    PackArgs pa2 = { Wk2, Wv2, Wq2, Wskip2, bk2, bv2, bq2, bskip2, 128, 128, 128, 64 };
    pack_weights<<<(512 * 128 + TB - 1) / TB, TB, 0, stream>>>(pa1, wb1, bp1);
    pack_weights<<<(448 * 128 + TB - 1) / TB, TB, 0, stream>>>(pa2, wb2, bp2);
    conv_bf16<<<(N0 * 32 + TB - 1) / TB, TB, 0, stream>>>(x, xb, N0 * 32);

    // ================= Layer 1 =================
    build_tables<<<(TBL_THREADS + TB - 1) / TB, TB, 0, stream>>>(
        edge_W, edge_b, time_W, time_b, We1, ta1, tb1);
    gemm_mfma_bf16out<16><<<(N0 + 63) / 64, TB, 0, stream>>>(xb, wb1, bp1, kv1, N0);
    gemm_mfma_f32out<16><<<(N1 + 63) / 64, TB, 0, stream>>>(xb, wb1 + 256 * 128, bp1 + 256, qr1, N1);
    hipMemsetAsync(cur1, 0, N1 * sizeof(int), stream);
    count_kernel<<<(E1C + TB - 1) / TB, TB, 0, stream>>>(ei1_dst, cur1, E1C);
    block_sum<<<NB1, 256, 0, stream>>>(cur1, bs1, N1);
    scan_bsum<<<1, 256, 0, stream>>>(bs1, NB1);
    block_scan<<<NB1, 256, 0, stream>>>(cur1, bs1, rp1, N1);
    hipMemsetAsync(cur1, 0, N1 * sizeof(int), stream);
    fill_csr<<<(E1C + TB - 1) / TB, TB, 0, stream>>>(ei1_dst, rp1, cur1, eix1, E1C);
    agg_layer1<<<(N1 + 3) / 4, TB, 0, stream>>>(rp1, eix1, ei1_src, et1, ets1,
        ta1, tb1, qr1, kv1, Wbeta1, ln_g, ln_b, h, N1);

    // ================= Layer 2 =================
    build_tables<<<(TBL_THREADS + TB - 1) / TB, TB, 0, stream>>>(
        edge_W, edge_b, time_W, time_b, We2, ta2, tb2);
    gemm_mfma_bf16out<16><<<(N1 + 63) / 64, TB, 0, stream>>>(h, wb2, bp2, kv2, N1);
    gemm_mfma_f32out<12><<<(N2 + 63) / 64, TB, 0, stream>>>(h, wb2 + 256 * 128, bp2 + 256, qr2, N2);
    hipMemsetAsync(cur2, 0, N2 * sizeof(int), stream);
    count_kernel<<<(E2C + TB - 1) / TB, TB, 0, stream>>>(ei2_dst, cur2, E2C);
    block_sum<<<NB2, 256, 0, stream>>>(cur2, bs2, N2);
    scan_bsum<<<1, 256, 0, stream>>>(bs2, NB2);
    block_scan<<<NB2, 256, 0, stream>>>(cur2, bs2, rp2, N2);
    hipMemsetAsync(cur2, 0, N2 * sizeof(int), stream);
    fill_csr<<<(E2C + TB - 1) / TB, TB, 0, stream>>>(ei2_dst, rp2, cur2, eix2, E2C);
    agg_layer2<<<(N2 + 3) / 4, TB, 0, stream>>>(rp2, eix2, ei2_src, et2, ets2,
        ta2, tb2, qr2, kv2, Wbeta2, (float*)d_out, N2);
}

// Round 6
// 463.893 us; speedup vs baseline: 9.0126x; 1.1244x over previous
//
#include <hip/hip_runtime.h>
#include <math.h>

// Problem constants
#define N0 80000
#define N1 40000
#define N2 20000
#define E1C 500000
#define E2C 250000
#define NTYPE 23
#define NTS 1158

// derived grid constants
#define NB1 157           // ceil(N1/256)
#define NB2 79            // ceil(N2/256)
#define KV1B 1250         // ceil(N0/64)
#define QR1B 625          // ceil(N1/64)
#define CNTB 2930         // ceil((E1C+E2C)/256)
#define KV2B 625          // ceil(N1/64)
#define QR2B 313          // ceil(N2/64)
#define FILLB 2930        // ceil((E1C+E2C)/256)

// ---------------- Workspace layout (float offsets) ----------------
#define OFF_XB    0u           // N0*128 bf16
#define OFF_QR1   5120000u     // N1*256 f32 (q|xr)
#define OFF_KV1   15360000u    // N0*256 bf16
#define OFF_H     25600000u    // N1*128 bf16
#define OFF_QR2   28160000u    // N2*192 f32
#define OFF_KV2   32000000u    // N1*256 bf16
#define OFF_WB1   37120000u    // 512*128 bf16
#define OFF_BP1   37160000u    // 512 f32
#define OFF_WB2   37170000u    // 448*128 bf16
#define OFF_BP2   37200000u    // 448 f32
#define OFF_TA1   37210000u
#define OFF_TB1   37213000u
#define OFF_TA2   37370000u
#define OFF_TB2   37373000u
#define OFF_RP1   37530000u    // N1+1 ints
#define OFF_CUR1  37580000u    // N1 ints
#define OFF_EIX1  37630000u    // E1 ints
#define OFF_BS1   38140000u    // 256 ints
#define OFF_RP2   38150000u    // N2+1 ints
#define OFF_CUR2  38180000u    // N2 ints
#define OFF_EIX2  38210000u    // E2 ints
#define OFF_BS2   38470000u    // 256 ints
#define OFF_DONE  38480000u    // 1 int

typedef __bf16 bf16x8 __attribute__((ext_vector_type(8)));
typedef float f32x4 __attribute__((ext_vector_type(4)));

static __device__ __forceinline__ float b2f(unsigned short u) {
    union { unsigned int i; float f; } c;
    c.i = ((unsigned int)u) << 16;
    return c.f;
}
static __device__ __forceinline__ unsigned short f2b(float f) {
    unsigned int u = __float_as_uint(f);
    unsigned int r = (u + 0x7fffu + ((u >> 16) & 1u)) >> 16;
    return (unsigned short)r;
}
static __device__ __forceinline__ bf16x8 ldfrag(const unsigned short* p) {
    return *reinterpret_cast<const bf16x8*>(p);
}

// ---------------------------------------------------------------------------
// Device GEMM bodies (MFMA 16x16x32 bf16), parameterized by block index
// ---------------------------------------------------------------------------
template <int NTILES>
static __device__ __forceinline__ void dev_gemm_bf16out(
    const unsigned short* __restrict__ XB, const unsigned short* __restrict__ WB,
    const float* __restrict__ BP, unsigned short* __restrict__ Y, int n, int blk,
    unsigned short* sb /* 16*(NTILES*16+8) per wave */) {
    constexpr int COLS = NTILES * 16;
    constexpr int LDSS = COLS + 8;
    int wave = threadIdx.x >> 6, lane = threadIdx.x & 63;
    int m = lane & 15, quad = lane >> 4;
    int rowbase = blk * 64 + wave * 16;
    int arow = rowbase + m; if (arow >= n) arow = n - 1;
    unsigned short* swave = sb + wave * 16 * LDSS;
    const unsigned short* xrow = XB + (size_t)arow * 128 + quad * 8;
    bf16x8 a0 = ldfrag(xrow), a1 = ldfrag(xrow + 32);
    bf16x8 a2 = ldfrag(xrow + 64), a3 = ldfrag(xrow + 96);
    f32x4 acc[NTILES];
#pragma unroll
    for (int t = 0; t < NTILES; t++) acc[t] = (f32x4){0.f, 0.f, 0.f, 0.f};
#pragma unroll
    for (int t = 0; t < NTILES; t++) {
        const unsigned short* wrow = WB + (size_t)(t * 16 + m) * 128 + quad * 8;
        acc[t] = __builtin_amdgcn_mfma_f32_16x16x32_bf16(a0, ldfrag(wrow), acc[t], 0, 0, 0);
        acc[t] = __builtin_amdgcn_mfma_f32_16x16x32_bf16(a1, ldfrag(wrow + 32), acc[t], 0, 0, 0);
        acc[t] = __builtin_amdgcn_mfma_f32_16x16x32_bf16(a2, ldfrag(wrow + 64), acc[t], 0, 0, 0);
        acc[t] = __builtin_amdgcn_mfma_f32_16x16x32_bf16(a3, ldfrag(wrow + 96), acc[t], 0, 0, 0);
    }
#pragma unroll
    for (int t = 0; t < NTILES; t++) {
        float b = BP[t * 16 + m];
#pragma unroll
        for (int r = 0; r < 4; r++)
            swave[(quad * 4 + r) * LDSS + t * 16 + m] = f2b(acc[t][r] + b);
    }
    // per-wave LDS only -> no barrier
    for (int i = lane; i < 16 * (COLS / 8); i += 64) {
        int r = i / (COLS / 8), g = i % (COLS / 8);
        int grow = rowbase + r;
        if (grow < n) {
            uint4 v = *(const uint4*)&swave[r * LDSS + g * 8];
            *(uint4*)(Y + (size_t)grow * COLS + g * 8) = v;
        }
    }
}

template <int NTILES>
static __device__ __forceinline__ void dev_gemm_f32out(
    const unsigned short* __restrict__ XB, const unsigned short* __restrict__ WB,
    const float* __restrict__ BP, float* __restrict__ Y, int n, int blk) {
    constexpr int COLS = NTILES * 16;
    int wave = threadIdx.x >> 6, lane = threadIdx.x & 63;
    int m = lane & 15, quad = lane >> 4;
    int rowbase = blk * 64 + wave * 16;
    int arow = rowbase + m; if (arow >= n) arow = n - 1;
    const unsigned short* xrow = XB + (size_t)arow * 128 + quad * 8;
    bf16x8 a0 = ldfrag(xrow), a1 = ldfrag(xrow + 32);
    bf16x8 a2 = ldfrag(xrow + 64), a3 = ldfrag(xrow + 96);
    f32x4 acc[NTILES];
#pragma unroll
    for (int t = 0; t < NTILES; t++) acc[t] = (f32x4){0.f, 0.f, 0.f, 0.f};
#pragma unroll
    for (int t = 0; t < NTILES; t++) {
        const unsigned short* wrow = WB + (size_t)(t * 16 + m) * 128 + quad * 8;
        acc[t] = __builtin_amdgcn_mfma_f32_16x16x32_bf16(a0, ldfrag(wrow), acc[t], 0, 0, 0);
        acc[t] = __builtin_amdgcn_mfma_f32_16x16x32_bf16(a1, ldfrag(wrow + 32), acc[t], 0, 0, 0);
        acc[t] = __builtin_amdgcn_mfma_f32_16x16x32_bf16(a2, ldfrag(wrow + 64), acc[t], 0, 0, 0);
        acc[t] = __builtin_amdgcn_mfma_f32_16x16x32_bf16(a3, ldfrag(wrow + 96), acc[t], 0, 0, 0);
    }
#pragma unroll
    for (int t = 0; t < NTILES; t++) {
        float b = BP[t * 16 + m];
#pragma unroll
        for (int r = 0; r < 4; r++) {
            int grow = rowbase + quad * 4 + r;
            if (grow < n) Y[(size_t)grow * COLS + t * 16 + m] = acc[t][r] + b;
        }
    }
}

// ---------------------------------------------------------------------------
// prep: pack weights (both layers), convert x->bf16, build all edge tables,
// zero counters. Grid-stride sections.
// ---------------------------------------------------------------------------
__global__ __launch_bounds__(256) void prep(
    const float* __restrict__ x, unsigned short* __restrict__ XB,
    const float* __restrict__ Wk1, const float* __restrict__ Wv1,
    const float* __restrict__ Wq1, const float* __restrict__ Wskip1,
    const float* __restrict__ bk1, const float* __restrict__ bv1,
    const float* __restrict__ bq1, const float* __restrict__ bskip1,
    const float* __restrict__ Wk2, const float* __restrict__ Wv2,
    const float* __restrict__ Wq2, const float* __restrict__ Wskip2,
    const float* __restrict__ bk2, const float* __restrict__ bv2,
    const float* __restrict__ bq2, const float* __restrict__ bskip2,
    unsigned short* __restrict__ WB1, float* __restrict__ BP1,
    unsigned short* __restrict__ WB2, float* __restrict__ BP2,
    const float* __restrict__ edge_W, const float* __restrict__ edge_b,
    const float* __restrict__ time_W, const float* __restrict__ time_b,
    const float* __restrict__ We1, const float* __restrict__ We2,
    float* __restrict__ TA1, float* __restrict__ TB1,
    float* __restrict__ TA2, float* __restrict__ TB2,
    int* __restrict__ cnt1, int* __restrict__ cnt2, int* __restrict__ done) {
    int tid = blockIdx.x * blockDim.x + threadIdx.x;
    int stride = gridDim.x * blockDim.x;
    // x -> bf16 (float4 chunks)
    for (int i = tid; i < N0 * 32; i += stride) {
        float4 v = *(const float4*)(x + (size_t)i * 4);
        ushort4 u;
        u.x = f2b(v.x); u.y = f2b(v.y); u.z = f2b(v.z); u.w = f2b(v.w);
        *(ushort4*)(XB + (size_t)i * 4) = u;
    }
    // pack layer-1 weights [k|v|q|skip] (512 rows)
    for (int i = tid; i < 512 * 128; i += stride) {
        int row = i >> 7, c = i & 127;
        const float* w; int off;
        if (row < 128) { w = Wk1; off = 0; }
        else if (row < 256) { w = Wv1; off = 128; }
        else if (row < 384) { w = Wq1; off = 256; }
        else { w = Wskip1; off = 384; }
        WB1[i] = f2b(w[(size_t)(row - off) * 128 + c]);
    }
    for (int i = tid; i < 512; i += stride) {
        const float* b; int off;
        if (i < 128) { b = bk1; off = 0; }
        else if (i < 256) { b = bv1; off = 128; }
        else if (i < 384) { b = bq1; off = 256; }
        else { b = bskip1; off = 384; }
        BP1[i] = b[i - off];
    }
    // pack layer-2 weights [k|v|q|skip64] (448 rows)
    for (int i = tid; i < 448 * 128; i += stride) {
        int row = i >> 7, c = i & 127;
        const float* w; int off;
        if (row < 128) { w = Wk2; off = 0; }
        else if (row < 256) { w = Wv2; off = 128; }
        else if (row < 384) { w = Wq2; off = 256; }
        else { w = Wskip2; off = 384; }
        WB2[i] = f2b(w[(size_t)(row - off) * 128 + c]);
    }
    for (int i = tid; i < 448; i += stride) {
        const float* b; int off;
        if (i < 128) { b = bk2; off = 0; }
        else if (i < 256) { b = bv2; off = 128; }
        else if (i < 384) { b = bq2; off = 256; }
        else { b = bskip2; off = 384; }
        BP2[i] = b[i - off];
    }
    // edge tables (both layers)
    const int TBL = (NTYPE + NTS) * 128;
    for (int i = tid; i < TBL; i += stride) {
        if (i < NTYPE * 128) {
            int e = i >> 7, c = i & 127;
            float s1 = 0.f, s2 = 0.f;
#pragma unroll
            for (int j = 0; j < 10; j++) {
                float fj = edge_W[j * NTYPE + e] + edge_b[j];
                s1 += fj * We1[c * 20 + j];
                s2 += fj * We2[c * 20 + j];
            }
            TA1[i] = s1; TA2[i] = s2;
        } else {
            int u = i - NTYPE * 128;
            int ts = u >> 7, c = u & 127;
            float s1 = 0.f, s2 = 0.f;
#pragma unroll
            for (int j = 0; j < 10; j++) {
                float fj = time_W[j * NTS + ts] + time_b[j];
                s1 += fj * We1[c * 20 + 10 + j];
                s2 += fj * We2[c * 20 + 10 + j];
            }
            TB1[u] = s1; TB2[u] = s2;
        }
    }
    // zero counters + done flag
    for (int i = tid; i < N1 + N2 + 1; i += stride) {
        if (i < N1) cnt1[i] = 0;
        else if (i < N1 + N2) cnt2[i - N1] = 0;
        else *done = 0;
    }
}

// ---------------------------------------------------------------------------
// mega_l1: KV1 GEMM | QR1 GEMM | degree count (both layers), block-partitioned
// ---------------------------------------------------------------------------
__global__ __launch_bounds__(256) void mega_l1(
    const unsigned short* __restrict__ XB,
    const unsigned short* __restrict__ WB1, const float* __restrict__ BP1,
    unsigned short* __restrict__ KV1, float* __restrict__ QR1,
    const int* __restrict__ d1, const int* __restrict__ d2,
    int* __restrict__ cnt1, int* __restrict__ cnt2) {
    __shared__ unsigned short sbuf[4 * 16 * 264];
    int b = blockIdx.x;
    if (b < KV1B) {
        dev_gemm_bf16out<16>(XB, WB1, BP1, KV1, N0, b, sbuf);
    } else if (b < KV1B + QR1B) {
        dev_gemm_f32out<16>(XB, WB1 + 256 * 128, BP1 + 256, QR1, N1, b - KV1B);
    } else {
        int t = (b - KV1B - QR1B) * 256 + threadIdx.x;
        if (t < E1C) atomicAdd(&cnt1[d1[t]], 1);
        else {
            t -= E1C;
            if (t < E2C) atomicAdd(&cnt2[d2[t]], 1);
        }
    }
}

// ---------------------------------------------------------------------------
// gemm_l2: KV2 GEMM | QR2 GEMM
// ---------------------------------------------------------------------------
__global__ __launch_bounds__(256) void gemm_l2(
    const unsigned short* __restrict__ H,
    const unsigned short* __restrict__ WB2, const float* __restrict__ BP2,
    unsigned short* __restrict__ KV2, float* __restrict__ QR2) {
    __shared__ unsigned short sbuf[4 * 16 * 264];
    int b = blockIdx.x;
    if (b < KV2B) dev_gemm_bf16out<16>(H, WB2, BP2, KV2, N1, b, sbuf);
    else dev_gemm_f32out<12>(H, WB2 + 256 * 128, BP2 + 256, QR2, N2, b - KV2B);
}

// ---------------------------------------------------------------------------
// bsum_scan: per-block sums of both cnt arrays; last block scans bsums
// (device-scope atomics across XCDs)
// ---------------------------------------------------------------------------
__global__ __launch_bounds__(256) void bsum_scan(
    const int* __restrict__ cnt1, int* __restrict__ bs1,
    const int* __restrict__ cnt2, int* __restrict__ bs2, int* __restrict__ done) {
    __shared__ int s[256];
    __shared__ int amlast;
    int b = blockIdx.x;
    const int* cnt; int* bs; int n, lb;
    if (b < NB1) { cnt = cnt1; bs = bs1; n = N1; lb = b; }
    else { cnt = cnt2; bs = bs2; n = N2; lb = b - NB1; }
    int t = lb * 256 + threadIdx.x;
    s[threadIdx.x] = (t < n) ? cnt[t] : 0;
    __syncthreads();
    for (int off = 128; off; off >>= 1) {
        if (threadIdx.x < off) s[threadIdx.x] += s[threadIdx.x + off];
        __syncthreads();
    }
    if (threadIdx.x == 0) {
        atomicExch(&bs[lb], s[0]);
        __threadfence();
        int prev = atomicAdd(done, 1);
        amlast = (prev == NB1 + NB2 - 1) ? 1 : 0;
    }
    __syncthreads();
    if (!amlast) return;
    // exclusive scan of bs1[NB1] and bs2[NB2] (atomic reads for coherence)
    int tt = threadIdx.x;
    int v1 = (tt < NB1) ? atomicAdd(&bs1[tt], 0) : 0;
    s[tt] = v1;
    __syncthreads();
    for (int off = 1; off < 256; off <<= 1) {
        int u = (tt >= off) ? s[tt - off] : 0;
        __syncthreads();
        s[tt] += u;
        __syncthreads();
    }
    if (tt < NB1) bs1[tt] = s[tt] - v1;
    __syncthreads();
    int v2 = (tt < NB2) ? atomicAdd(&bs2[tt], 0) : 0;
    s[tt] = v2;
    __syncthreads();
    for (int off = 1; off < 256; off <<= 1) {
        int u = (tt >= off) ? s[tt - off] : 0;
        __syncthreads();
        s[tt] += u;
        __syncthreads();
    }
    if (tt < NB2) bs2[tt] = s[tt] - v2;
}

// ---------------------------------------------------------------------------
// bscan_both: rowptr for both layers; re-zeroes cnt (becomes fill cursor)
// ---------------------------------------------------------------------------
__global__ __launch_bounds__(256) void bscan_both(
    int* __restrict__ cnt1, const int* __restrict__ bs1, int* __restrict__ rp1,
    int* __restrict__ cnt2, const int* __restrict__ bs2, int* __restrict__ rp2) {
    __shared__ int s[256];
    int b = blockIdx.x;
    int* cnt; const int* bs; int* rp; int n, lb;
    if (b < NB1) { cnt = cnt1; bs = bs1; rp = rp1; n = N1; lb = b; }
    else { cnt = cnt2; bs = bs2; rp = rp2; n = N2; lb = b - NB1; }
    int t = lb * 256 + threadIdx.x;
    int v = (t < n) ? cnt[t] : 0;
    if (t < n) cnt[t] = 0;
    s[threadIdx.x] = v;
    __syncthreads();
    for (int off = 1; off < 256; off <<= 1) {
        int u = (threadIdx.x >= off) ? s[threadIdx.x - off] : 0;
        __syncthreads();
        s[threadIdx.x] += u;
        __syncthreads();
    }
    int incl = s[threadIdx.x];
    int base = bs[lb];
    if (t < n) rp[t] = base + incl - v;
    if (t == n - 1) rp[n] = base + incl;
}

// ---------------------------------------------------------------------------
// fill_both: CSR fill for both layers
// ---------------------------------------------------------------------------
__global__ __launch_bounds__(256) void fill_both(
    const int* __restrict__ d1, const int* __restrict__ rp1,
    int* __restrict__ cur1, int* __restrict__ eix1,
    const int* __restrict__ d2, const int* __restrict__ rp2,
    int* __restrict__ cur2, int* __restrict__ eix2) {
    int t = blockIdx.x * 256 + threadIdx.x;
    if (t < E1C) {
        int d = d1[t];
        eix1[rp1[d] + atomicAdd(&cur1[d], 1)] = t;
    } else {
        t -= E1C;
        if (t < E2C) {
            int d = d2[t];
            eix2[rp2[d] + atomicAdd(&cur2[d], 1)] = t;
        }
    }
}

// ---------------------------------------------------------------------------
// Fused aggregation (unchanged from round 5)
// ---------------------------------------------------------------------------
__global__ __launch_bounds__(256) void agg_layer1(
    const int* __restrict__ rowptr, const int* __restrict__ eidx,
    const int* __restrict__ src, const int* __restrict__ et, const int* __restrict__ ets,
    const float* __restrict__ TA, const float* __restrict__ TB,
    const float* __restrict__ QR, const unsigned short* __restrict__ KV,
    const float* __restrict__ Wbeta,
    const float* __restrict__ ln_g, const float* __restrict__ ln_b,
    unsigned short* __restrict__ hout, int n) {
    int wid = (blockIdx.x * blockDim.x + threadIdx.x) >> 6;
    int lane = threadIdx.x & 63;
    if (wid >= n) return;
    int s = lane >> 5, cg = lane & 15;
    int co = ((lane >> 4) & 1) * 64 + 4 * cg;
    int beg = rowptr[wid], end = rowptr[wid + 1];
    float4 q4 = *(const float4*)(QR + (size_t)wid * 256 + co);
    float ax = 0.f, ay = 0.f, az = 0.f, aw = 0.f, suma = 0.f;
    for (int p = beg + s; p < end; p += 2) {
        int e = eidx[p];
        int sn = src[e], t = et[e], ts = ets[e];
        float4 ta = *(const float4*)(TA + t * 128 + co);
        float4 tb = *(const float4*)(TB + ts * 128 + co);
        float e0 = ta.x + tb.x, e1 = ta.y + tb.y, e2 = ta.z + tb.z, e3 = ta.w + tb.w;
        const unsigned short* kv = KV + (size_t)sn * 256;
        ushort4 ku = *(const ushort4*)(kv + co);
        ushort4 vu = *(const ushort4*)(kv + 128 + co);
        float pp = q4.x * (b2f(ku.x) + e0) + q4.y * (b2f(ku.y) + e1)
                 + q4.z * (b2f(ku.z) + e2) + q4.w * (b2f(ku.w) + e3);
        pp += __shfl_xor(pp, 1); pp += __shfl_xor(pp, 2);
        pp += __shfl_xor(pp, 4); pp += __shfl_xor(pp, 8);
        float a = expf(pp * 0.125f);
        ax += a * (b2f(vu.x) + e0); ay += a * (b2f(vu.y) + e1);
        az += a * (b2f(vu.z) + e2); aw += a * (b2f(vu.w) + e3);
        suma += a;
    }
    ax += __shfl_xor(ax, 32); ay += __shfl_xor(ay, 32);
    az += __shfl_xor(az, 32); aw += __shfl_xor(aw, 32);
    suma += __shfl_xor(suma, 32);
    float inv_s = 1.f / (suma + 1e-16f);
    float ox = ax * inv_s, oy = ay * inv_s, oz = az * inv_s, ow = aw * inv_s;
    float4 r4 = *(const float4*)(QR + (size_t)wid * 256 + 128 + co);
    float4 wo = *(const float4*)(Wbeta + co);
    float4 wr = *(const float4*)(Wbeta + 128 + co);
    float4 wd = *(const float4*)(Wbeta + 256 + co);
    float pb = wo.x * ox + wr.x * r4.x + wd.x * (ox - r4.x)
             + wo.y * oy + wr.y * r4.y + wd.y * (oy - r4.y)
             + wo.z * oz + wr.z * r4.z + wd.z * (oz - r4.z)
             + wo.w * ow + wr.w * r4.w + wd.w * (ow - r4.w);
    pb += __shfl_xor(pb, 1); pb += __shfl_xor(pb, 2); pb += __shfl_xor(pb, 4);
    pb += __shfl_xor(pb, 8); pb += __shfl_xor(pb, 16);
    float beta = 1.f / (1.f + expf(-pb));
    float gx = beta * r4.x + (1.f - beta) * ox;
    float gy = beta * r4.y + (1.f - beta) * oy;
    float gz = beta * r4.z + (1.f - beta) * oz;
    float gw = beta * r4.w + (1.f - beta) * ow;
    float sm = gx + gy + gz + gw;
    float sq = gx * gx + gy * gy + gz * gz + gw * gw;
    sm += __shfl_xor(sm, 1); sq += __shfl_xor(sq, 1);
    sm += __shfl_xor(sm, 2); sq += __shfl_xor(sq, 2);
    sm += __shfl_xor(sm, 4); sq += __shfl_xor(sq, 4);
    sm += __shfl_xor(sm, 8); sq += __shfl_xor(sq, 8);
    sm += __shfl_xor(sm, 16); sq += __shfl_xor(sq, 16);
    float mu = sm * (1.f / 128.f);
    float var = sq * (1.f / 128.f) - mu * mu;
    float inv = rsqrtf(var + 1e-5f);
    float4 lg = *(const float4*)(ln_g + co);
    float4 lb = *(const float4*)(ln_b + co);
    float yx = (gx - mu) * inv * lg.x + lb.x;
    float yy = (gy - mu) * inv * lg.y + lb.y;
    float yz = (gz - mu) * inv * lg.z + lb.z;
    float yw = (gw - mu) * inv * lg.w + lb.w;
    const float ISQ2 = 0.70710678118654752f;
    yx = 0.5f * yx * (1.f + erff(yx * ISQ2));
    yy = 0.5f * yy * (1.f + erff(yy * ISQ2));
    yz = 0.5f * yz * (1.f + erff(yz * ISQ2));
    yw = 0.5f * yw * (1.f + erff(yw * ISQ2));
    if (s == 0) {
        ushort4 hv;
        hv.x = f2b(yx); hv.y = f2b(yy); hv.z = f2b(yz); hv.w = f2b(yw);
        *(ushort4*)(hout + (size_t)wid * 128 + co) = hv;
    }
}

__global__ __launch_bounds__(256) void agg_layer2(
    const int* __restrict__ rowptr, const int* __restrict__ eidx,
    const int* __restrict__ src, const int* __restrict__ et, const int* __restrict__ ets,
    const float* __restrict__ TA, const float* __restrict__ TB,
    const float* __restrict__ QR, const unsigned short* __restrict__ KV,
    const float* __restrict__ Wbeta,
    float* __restrict__ o, int n) {
    int wid = (blockIdx.x * blockDim.x + threadIdx.x) >> 6;
    int lane = threadIdx.x & 63;
    if (wid >= n) return;
    int s = lane >> 5, cg = lane & 15;
    int co = ((lane >> 4) & 1) * 64 + 4 * cg;
    int beg = rowptr[wid], end = rowptr[wid + 1];
    float4 q4 = *(const float4*)(QR + (size_t)wid * 192 + co);
    float ax = 0.f, ay = 0.f, az = 0.f, aw = 0.f, suma = 0.f;
    for (int p = beg + s; p < end; p += 2) {
        int e = eidx[p];
        int sn = src[e], t = et[e], ts = ets[e];
        float4 ta = *(const float4*)(TA + t * 128 + co);
        float4 tb = *(const float4*)(TB + ts * 128 + co);
        float e0 = ta.x + tb.x, e1 = ta.y + tb.y, e2 = ta.z + tb.z, e3 = ta.w + tb.w;
        const unsigned short* kv = KV + (size_t)sn * 256;
        ushort4 ku = *(const ushort4*)(kv + co);
        ushort4 vu = *(const ushort4*)(kv + 128 + co);
        float pp = q4.x * (b2f(ku.x) + e0) + q4.y * (b2f(ku.y) + e1)
                 + q4.z * (b2f(ku.z) + e2) + q4.w * (b2f(ku.w) + e3);
        pp += __shfl_xor(pp, 1); pp += __shfl_xor(pp, 2);
        pp += __shfl_xor(pp, 4); pp += __shfl_xor(pp, 8);
        float a = expf(pp * 0.125f);
        ax += a * (b2f(vu.x) + e0); ay += a * (b2f(vu.y) + e1);
        az += a * (b2f(vu.z) + e2); aw += a * (b2f(vu.w) + e3);
        suma += a;
    }
    ax += __shfl_xor(ax, 32); ay += __shfl_xor(ay, 32);
    az += __shfl_xor(az, 32); aw += __shfl_xor(aw, 32);
    suma += __shfl_xor(suma, 32);
    float inv_s = 1.f / (suma + 1e-16f);
    float ox = ax * inv_s, oy = ay * inv_s, oz = az * inv_s, ow = aw * inv_s;
    ox = 0.5f * (ox + __shfl_xor(ox, 16));
    oy = 0.5f * (oy + __shfl_xor(oy, 16));
    oz = 0.5f * (oz + __shfl_xor(oz, 16));
    ow = 0.5f * (ow + __shfl_xor(ow, 16));
    float4 r4 = *(const float4*)(QR + (size_t)wid * 192 + 128 + 4 * cg);
    float4 wo = *(const float4*)(Wbeta + 4 * cg);
    float4 wr = *(const float4*)(Wbeta + 64 + 4 * cg);
    float4 wd = *(const float4*)(Wbeta + 128 + 4 * cg);
    float pb = wo.x * ox + wr.x * r4.x + wd.x * (ox - r4.x)
             + wo.y * oy + wr.y * r4.y + wd.y * (oy - r4.y)
             + wo.z * oz + wr.z * r4.z + wd.z * (oz - r4.z)
             + wo.w * ow + wr.w * r4.w + wd.w * (ow - r4.w);
    pb += __shfl_xor(pb, 1); pb += __shfl_xor(pb, 2);
    pb += __shfl_xor(pb, 4); pb += __shfl_xor(pb, 8);
    float beta = 1.f / (1.f + expf(-pb));
    float vx = beta * r4.x + (1.f - beta) * ox;
    float vy = beta * r4.y + (1.f - beta) * oy;
    float vz = beta * r4.z + (1.f - beta) * oz;
    float vw = beta * r4.w + (1.f - beta) * ow;
    float m = fmaxf(fmaxf(vx, vy), fmaxf(vz, vw));
    m = fmaxf(m, __shfl_xor(m, 1)); m = fmaxf(m, __shfl_xor(m, 2));
    m = fmaxf(m, __shfl_xor(m, 4)); m = fmaxf(m, __shfl_xor(m, 8));
    float se = expf(vx - m) + expf(vy - m) + expf(vz - m) + expf(vw - m);
    se += __shfl_xor(se, 1); se += __shfl_xor(se, 2);
    se += __shfl_xor(se, 4); se += __shfl_xor(se, 8);
    float lse = m + logf(se);
    if (lane < 16)
        *(float4*)(o + (size_t)wid * 64 + 4 * cg) =
            make_float4(vx - lse, vy - lse, vz - lse, vw - lse);
}

extern "C" void kernel_launch(void* const* d_in, const int* in_sizes, int n_in,
                              void* d_out, int out_size, void* d_ws, size_t ws_size,
                              hipStream_t stream) {
    const float* x        = (const float*)d_in[0];
    const int*   ei1_src  = (const int*)d_in[1];
    const int*   ei1_dst  = (const int*)d_in[2];
    const int*   et1      = (const int*)d_in[3];
    const int*   ets1     = (const int*)d_in[4];
    const int*   ei2_src  = (const int*)d_in[5];
    const int*   ei2_dst  = (const int*)d_in[6];
    const int*   et2      = (const int*)d_in[7];
    const int*   ets2     = (const int*)d_in[8];
    const float* edge_W   = (const float*)d_in[9];
    const float* edge_b   = (const float*)d_in[10];
    const float* time_W   = (const float*)d_in[11];
    const float* time_b   = (const float*)d_in[12];
    const float* Wq1      = (const float*)d_in[13];
    const float* bq1      = (const float*)d_in[14];
    const float* Wk1      = (const float*)d_in[15];
    const float* bk1      = (const float*)d_in[16];
    const float* Wv1      = (const float*)d_in[17];
    const float* bv1      = (const float*)d_in[18];
    const float* We1      = (const float*)d_in[19];
    const float* Wskip1   = (const float*)d_in[20];
    const float* bskip1   = (const float*)d_in[21];
    const float* Wbeta1   = (const float*)d_in[22];
    const float* ln_g     = (const float*)d_in[23];
    const float* ln_b     = (const float*)d_in[24];
    const float* Wq2      = (const float*)d_in[25];
    const float* bq2      = (const float*)d_in[26];
    const float* Wk2      = (const float*)d_in[27];
    const float* bk2      = (const float*)d_in[28];
    const float* Wv2      = (const float*)d_in[29];
    const float* bv2      = (const float*)d_in[30];
    const float* We2      = (const float*)d_in[31];
    const float* Wskip2   = (const float*)d_in[32];
    const float* bskip2   = (const float*)d_in[33];
    const float* Wbeta2   = (const float*)d_in[34];

    float* ws = (float*)d_ws;
    unsigned short* xb  = (unsigned short*)(ws + OFF_XB);
    float* qr1          = ws + OFF_QR1;
    unsigned short* kv1 = (unsigned short*)(ws + OFF_KV1);
    unsigned short* h   = (unsigned short*)(ws + OFF_H);
    float* qr2          = ws + OFF_QR2;
    unsigned short* kv2 = (unsigned short*)(ws + OFF_KV2);
    unsigned short* wb1 = (unsigned short*)(ws + OFF_WB1);
    float* bp1          = ws + OFF_BP1;
    unsigned short* wb2 = (unsigned short*)(ws + OFF_WB2);
    float* bp2          = ws + OFF_BP2;
    float* ta1          = ws + OFF_TA1;
    float* tb1          = ws + OFF_TB1;
    float* ta2          = ws + OFF_TA2;
    float* tb2          = ws + OFF_TB2;
    int*   rp1          = (int*)(ws + OFF_RP1);
    int*   cur1         = (int*)(ws + OFF_CUR1);
    int*   eix1         = (int*)(ws + OFF_EIX1);
    int*   bs1          = (int*)(ws + OFF_BS1);
    int*   rp2          = (int*)(ws + OFF_RP2);
    int*   cur2         = (int*)(ws + OFF_CUR2);
    int*   eix2         = (int*)(ws + OFF_EIX2);
    int*   bs2          = (int*)(ws + OFF_BS2);
    int*   done         = (int*)(ws + OFF_DONE);

    // 1. prep
    prep<<<2048, 256, 0, stream>>>(
        x, xb,
        Wk1, Wv1, Wq1, Wskip1, bk1, bv1, bq1, bskip1,
        Wk2, Wv2, Wq2, Wskip2, bk2, bv2, bq2, bskip2,
        wb1, bp1, wb2, bp2,
        edge_W, edge_b, time_W, time_b, We1, We2,
        ta1, tb1, ta2, tb2, cur1, cur2, done);
    // 2. layer-1 GEMMs + degree count
    mega_l1<<<KV1B + QR1B + CNTB, 256, 0, stream>>>(
        xb, wb1, bp1, kv1, qr1, ei1_dst, ei2_dst, cur1, cur2);
    // 3. block sums + scan (fused via atomic ticket)
    bsum_scan<<<NB1 + NB2, 256, 0, stream>>>(cur1, bs1, cur2, bs2, done);
    // 4. rowptrs (re-zeroes cursors)
    bscan_both<<<NB1 + NB2, 256, 0, stream>>>(cur1, bs1, rp1, cur2, bs2, rp2);
    // 5. CSR fill (both layers)
    fill_both<<<FILLB, 256, 0, stream>>>(ei1_dst, rp1, cur1, eix1,
                                         ei2_dst, rp2, cur2, eix2);
    // 6. layer-1 aggregation -> h (bf16)
    agg_layer1<<<(N1 + 3) / 4, 256, 0, stream>>>(rp1, eix1, ei1_src, et1, ets1,
        ta1, tb1, qr1, kv1, Wbeta1, ln_g, ln_b, h, N1);
    // 7. layer-2 GEMMs
    gemm_l2<<<KV2B + QR2B, 256, 0, stream>>>(h, wb2, bp2, kv2, qr2);
    // 8. layer-2 aggregation -> output
    agg_layer2<<<(N2 + 3) / 4, 256, 0, stream>>>(rp2, eix2, ei2_src, et2, ets2,
        ta2, tb2, qr2, kv2, Wbeta2, (float*)d_out, N2);
}

// Round 7
// 443.311 us; speedup vs baseline: 9.4310x; 1.0464x over previous
//
#include <hip/hip_runtime.h>
#include <math.h>

// Problem constants
#define N0 80000
#define N1 40000
#define N2 20000
#define E1C 500000
#define E2C 250000
#define NTYPE 23
#define NTS 1158

// derived grid constants
#define NB1 157           // ceil(N1/256)
#define NB2 79            // ceil(N2/256)
#define KV1B 1250         // ceil(N0/64)
#define QR1B 625          // ceil(N1/64)
#define CNTB 2930         // ceil((E1C+E2C)/256)
#define KV2B 625          // ceil(N1/64)
#define QR2B 313          // ceil(N2/64)
#define FILLB 2930        // ceil((E1C+E2C)/256)

// ---------------- Workspace layout (float offsets) ----------------
#define OFF_XB    0u           // N0*128 bf16
#define OFF_QR1   5120000u     // N1*256 f32 (q|xr)
#define OFF_KV1   15360000u    // N0*256 bf16
#define OFF_H     25600000u    // N1*128 bf16
#define OFF_QR2   28160000u    // N2*192 f32
#define OFF_KV2   32000000u    // N1*256 bf16
#define OFF_WB1   37120000u    // 512*128 bf16
#define OFF_BP1   37160000u    // 512 f32
#define OFF_WB2   37170000u    // 448*128 bf16
#define OFF_BP2   37200000u    // 448 f32
#define OFF_TA1   37210000u
#define OFF_TB1   37213000u
#define OFF_TA2   37370000u
#define OFF_TB2   37373000u
#define OFF_RP1   37530000u    // N1+1 ints
#define OFF_CUR1  37580000u    // N1 ints
#define OFF_EIX1  37630000u    // E1 ints
#define OFF_BS1   38140000u    // 256 ints
#define OFF_RP2   38150000u    // N2+1 ints
#define OFF_CUR2  38180000u    // N2 ints
#define OFF_EIX2  38210000u    // E2 ints
#define OFF_BS2   38470000u    // 256 ints
#define OFF_DONE  38480000u    // 1 int

typedef __bf16 bf16x8 __attribute__((ext_vector_type(8)));
typedef float f32x4 __attribute__((ext_vector_type(4)));

static __device__ __forceinline__ float b2f(unsigned short u) {
    union { unsigned int i; float f; } c;
    c.i = ((unsigned int)u) << 16;
    return c.f;
}
static __device__ __forceinline__ unsigned short f2b(float f) {
    unsigned int u = __float_as_uint(f);
    unsigned int r = (u + 0x7fffu + ((u >> 16) & 1u)) >> 16;
    return (unsigned short)r;
}
static __device__ __forceinline__ bf16x8 ldfrag(const unsigned short* p) {
    return *reinterpret_cast<const bf16x8*>(p);
}

// ---------------------------------------------------------------------------
// Device GEMM bodies (MFMA 16x16x32 bf16)
// bf16out: 2-pass LDS repack (8 tiles/pass) -> 4352 B/wave, 17408 B/block
// ---------------------------------------------------------------------------
#define LDSS 136   // 128 cols + 8 pad (ushorts)

template <int NTILES>
static __device__ __forceinline__ void dev_gemm_bf16out(
    const unsigned short* __restrict__ XB, const unsigned short* __restrict__ WB,
    const float* __restrict__ BP, unsigned short* __restrict__ Y, int n, int blk,
    unsigned short* sb) {
    constexpr int COLS = NTILES * 16;
    constexpr int HALF = NTILES / 2;
    constexpr int HCOLS = HALF * 16;
    int wave = threadIdx.x >> 6, lane = threadIdx.x & 63;
    int m = lane & 15, quad = lane >> 4;
    int rowbase = blk * 64 + wave * 16;
    int arow = rowbase + m; if (arow >= n) arow = n - 1;
    unsigned short* swave = sb + wave * 16 * LDSS;
    const unsigned short* xrow = XB + (size_t)arow * 128 + quad * 8;
    bf16x8 a0 = ldfrag(xrow), a1 = ldfrag(xrow + 32);
    bf16x8 a2 = ldfrag(xrow + 64), a3 = ldfrag(xrow + 96);
    f32x4 acc[NTILES];
#pragma unroll
    for (int t = 0; t < NTILES; t++) acc[t] = (f32x4){0.f, 0.f, 0.f, 0.f};
#pragma unroll
    for (int t = 0; t < NTILES; t++) {
        const unsigned short* wrow = WB + (size_t)(t * 16 + m) * 128 + quad * 8;
        acc[t] = __builtin_amdgcn_mfma_f32_16x16x32_bf16(a0, ldfrag(wrow), acc[t], 0, 0, 0);
        acc[t] = __builtin_amdgcn_mfma_f32_16x16x32_bf16(a1, ldfrag(wrow + 32), acc[t], 0, 0, 0);
        acc[t] = __builtin_amdgcn_mfma_f32_16x16x32_bf16(a2, ldfrag(wrow + 64), acc[t], 0, 0, 0);
        acc[t] = __builtin_amdgcn_mfma_f32_16x16x32_bf16(a3, ldfrag(wrow + 96), acc[t], 0, 0, 0);
    }
#pragma unroll
    for (int half = 0; half < 2; half++) {
#pragma unroll
        for (int t = 0; t < HALF; t++) {
            int tt = half * HALF + t;
            float b = BP[tt * 16 + m];
#pragma unroll
            for (int r = 0; r < 4; r++)
                swave[(quad * 4 + r) * LDSS + t * 16 + m] = f2b(acc[tt][r] + b);
        }
        // per-wave LDS; DS ops execute in order per wave -> no barrier
#pragma unroll
        for (int i = 0; i < 4; i++) {
            int idx = i * 64 + lane;
            int r = idx / (HCOLS / 8), g = idx % (HCOLS / 8);
            int grow = rowbase + r;
            if (grow < n) {
                uint4 v = *(const uint4*)&swave[r * LDSS + g * 8];
                *(uint4*)(Y + (size_t)grow * COLS + half * HCOLS + g * 8) = v;
            }
        }
    }
}

template <int NTILES>
static __device__ __forceinline__ void dev_gemm_f32out(
    const unsigned short* __restrict__ XB, const unsigned short* __restrict__ WB,
    const float* __restrict__ BP, float* __restrict__ Y, int n, int blk) {
    constexpr int COLS = NTILES * 16;
    int wave = threadIdx.x >> 6, lane = threadIdx.x & 63;
    int m = lane & 15, quad = lane >> 4;
    int rowbase = blk * 64 + wave * 16;
    int arow = rowbase + m; if (arow >= n) arow = n - 1;
    const unsigned short* xrow = XB + (size_t)arow * 128 + quad * 8;
    bf16x8 a0 = ldfrag(xrow), a1 = ldfrag(xrow + 32);
    bf16x8 a2 = ldfrag(xrow + 64), a3 = ldfrag(xrow + 96);
    f32x4 acc[NTILES];
#pragma unroll
    for (int t = 0; t < NTILES; t++) acc[t] = (f32x4){0.f, 0.f, 0.f, 0.f};
#pragma unroll
    for (int t = 0; t < NTILES; t++) {
        const unsigned short* wrow = WB + (size_t)(t * 16 + m) * 128 + quad * 8;
        acc[t] = __builtin_amdgcn_mfma_f32_16x16x32_bf16(a0, ldfrag(wrow), acc[t], 0, 0, 0);
        acc[t] = __builtin_amdgcn_mfma_f32_16x16x32_bf16(a1, ldfrag(wrow + 32), acc[t], 0, 0, 0);
        acc[t] = __builtin_amdgcn_mfma_f32_16x16x32_bf16(a2, ldfrag(wrow + 64), acc[t], 0, 0, 0);
        acc[t] = __builtin_amdgcn_mfma_f32_16x16x32_bf16(a3, ldfrag(wrow + 96), acc[t], 0, 0, 0);
    }
#pragma unroll
    for (int t = 0; t < NTILES; t++) {
        float b = BP[t * 16 + m];
#pragma unroll
        for (int r = 0; r < 4; r++) {
            int grow = rowbase + quad * 4 + r;
            if (grow < n) Y[(size_t)grow * COLS + t * 16 + m] = acc[t][r] + b;
        }
    }
}

// ---------------------------------------------------------------------------
// prep: pack weights, convert x->bf16, build edge tables, zero counters
// ---------------------------------------------------------------------------
__global__ __launch_bounds__(256) void prep(
    const float* __restrict__ x, unsigned short* __restrict__ XB,
    const float* __restrict__ Wk1, const float* __restrict__ Wv1,
    const float* __restrict__ Wq1, const float* __restrict__ Wskip1,
    const float* __restrict__ bk1, const float* __restrict__ bv1,
    const float* __restrict__ bq1, const float* __restrict__ bskip1,
    const float* __restrict__ Wk2, const float* __restrict__ Wv2,
    const float* __restrict__ Wq2, const float* __restrict__ Wskip2,
    const float* __restrict__ bk2, const float* __restrict__ bv2,
    const float* __restrict__ bq2, const float* __restrict__ bskip2,
    unsigned short* __restrict__ WB1, float* __restrict__ BP1,
    unsigned short* __restrict__ WB2, float* __restrict__ BP2,
    const float* __restrict__ edge_W, const float* __restrict__ edge_b,
    const float* __restrict__ time_W, const float* __restrict__ time_b,
    const float* __restrict__ We1, const float* __restrict__ We2,
    float* __restrict__ TA1, float* __restrict__ TB1,
    float* __restrict__ TA2, float* __restrict__ TB2,
    int* __restrict__ cnt1, int* __restrict__ cnt2, int* __restrict__ done) {
    int tid = blockIdx.x * blockDim.x + threadIdx.x;
    int stride = gridDim.x * blockDim.x;
    for (int i = tid; i < N0 * 32; i += stride) {
        float4 v = *(const float4*)(x + (size_t)i * 4);
        ushort4 u;
        u.x = f2b(v.x); u.y = f2b(v.y); u.z = f2b(v.z); u.w = f2b(v.w);
        *(ushort4*)(XB + (size_t)i * 4) = u;
    }
    for (int i = tid; i < 512 * 128; i += stride) {
        int row = i >> 7, c = i & 127;
        const float* w; int off;
        if (row < 128) { w = Wk1; off = 0; }
        else if (row < 256) { w = Wv1; off = 128; }
        else if (row < 384) { w = Wq1; off = 256; }
        else { w = Wskip1; off = 384; }
        WB1[i] = f2b(w[(size_t)(row - off) * 128 + c]);
    }
    for (int i = tid; i < 512; i += stride) {
        const float* b; int off;
        if (i < 128) { b = bk1; off = 0; }
        else if (i < 256) { b = bv1; off = 128; }
        else if (i < 384) { b = bq1; off = 256; }
        else { b = bskip1; off = 384; }
        BP1[i] = b[i - off];
    }
    for (int i = tid; i < 448 * 128; i += stride) {
        int row = i >> 7, c = i & 127;
        const float* w; int off;
        if (row < 128) { w = Wk2; off = 0; }
        else if (row < 256) { w = Wv2; off = 128; }
        else if (row < 384) { w = Wq2; off = 256; }
        else { w = Wskip2; off = 384; }
        WB2[i] = f2b(w[(size_t)(row - off) * 128 + c]);
    }
    for (int i = tid; i < 448; i += stride) {
        const float* b; int off;
        if (i < 128) { b = bk2; off = 0; }
        else if (i < 256) { b = bv2; off = 128; }
        else if (i < 384) { b = bq2; off = 256; }
        else { b = bskip2; off = 384; }
        BP2[i] = b[i - off];
    }
    const int TBL = (NTYPE + NTS) * 128;
    for (int i = tid; i < TBL; i += stride) {
        if (i < NTYPE * 128) {
            int e = i >> 7, c = i & 127;
            float s1 = 0.f, s2 = 0.f;
#pragma unroll
            for (int j = 0; j < 10; j++) {
                float fj = edge_W[j * NTYPE + e] + edge_b[j];
                s1 += fj * We1[c * 20 + j];
                s2 += fj * We2[c * 20 + j];
            }
            TA1[i] = s1; TA2[i] = s2;
        } else {
            int u = i - NTYPE * 128;
            int ts = u >> 7, c = u & 127;
            float s1 = 0.f, s2 = 0.f;
#pragma unroll
            for (int j = 0; j < 10; j++) {
                float fj = time_W[j * NTS + ts] + time_b[j];
                s1 += fj * We1[c * 20 + 10 + j];
                s2 += fj * We2[c * 20 + 10 + j];
            }
            TB1[u] = s1; TB2[u] = s2;
        }
    }
    for (int i = tid; i < N1 + N2 + 1; i += stride) {
        if (i < N1) cnt1[i] = 0;
        else if (i < N1 + N2) cnt2[i - N1] = 0;
        else *done = 0;
    }
}

// ---------------------------------------------------------------------------
// mega_l1: KV1 GEMM | QR1 GEMM | degree count, block-partitioned
// ---------------------------------------------------------------------------
__global__ __launch_bounds__(256) void mega_l1(
    const unsigned short* __restrict__ XB,
    const unsigned short* __restrict__ WB1, const float* __restrict__ BP1,
    unsigned short* __restrict__ KV1, float* __restrict__ QR1,
    const int* __restrict__ d1, const int* __restrict__ d2,
    int* __restrict__ cnt1, int* __restrict__ cnt2) {
    __shared__ unsigned short sbuf[4 * 16 * LDSS];
    int b = blockIdx.x;
    if (b < KV1B) {
        dev_gemm_bf16out<16>(XB, WB1, BP1, KV1, N0, b, sbuf);
    } else if (b < KV1B + QR1B) {
        dev_gemm_f32out<16>(XB, WB1 + 256 * 128, BP1 + 256, QR1, N1, b - KV1B);
    } else {
        int t = (b - KV1B - QR1B) * 256 + threadIdx.x;
        if (t < E1C) atomicAdd(&cnt1[d1[t]], 1);
        else {
            t -= E1C;
            if (t < E2C) atomicAdd(&cnt2[d2[t]], 1);
        }
    }
}

__global__ __launch_bounds__(256) void gemm_l2(
    const unsigned short* __restrict__ H,
    const unsigned short* __restrict__ WB2, const float* __restrict__ BP2,
    unsigned short* __restrict__ KV2, float* __restrict__ QR2) {
    __shared__ unsigned short sbuf[4 * 16 * LDSS];
    int b = blockIdx.x;
    if (b < KV2B) dev_gemm_bf16out<16>(H, WB2, BP2, KV2, N1, b, sbuf);
    else dev_gemm_f32out<12>(H, WB2 + 256 * 128, BP2 + 256, QR2, N2, b - KV2B);
}

// ---------------------------------------------------------------------------
// bsum_scan / bscan_both / fill_both (unchanged)
// ---------------------------------------------------------------------------
__global__ __launch_bounds__(256) void bsum_scan(
    const int* __restrict__ cnt1, int* __restrict__ bs1,
    const int* __restrict__ cnt2, int* __restrict__ bs2, int* __restrict__ done) {
    __shared__ int s[256];
    __shared__ int amlast;
    int b = blockIdx.x;
    const int* cnt; int* bs; int n, lb;
    if (b < NB1) { cnt = cnt1; bs = bs1; n = N1; lb = b; }
    else { cnt = cnt2; bs = bs2; n = N2; lb = b - NB1; }
    int t = lb * 256 + threadIdx.x;
    s[threadIdx.x] = (t < n) ? cnt[t] : 0;
    __syncthreads();
    for (int off = 128; off; off >>= 1) {
        if (threadIdx.x < off) s[threadIdx.x] += s[threadIdx.x + off];
        __syncthreads();
    }
    if (threadIdx.x == 0) {
        atomicExch(&bs[lb], s[0]);
        __threadfence();
        int prev = atomicAdd(done, 1);
        amlast = (prev == NB1 + NB2 - 1) ? 1 : 0;
    }
    __syncthreads();
    if (!amlast) return;
    int tt = threadIdx.x;
    int v1 = (tt < NB1) ? atomicAdd(&bs1[tt], 0) : 0;
    s[tt] = v1;
    __syncthreads();
    for (int off = 1; off < 256; off <<= 1) {
        int u = (tt >= off) ? s[tt - off] : 0;
        __syncthreads();
        s[tt] += u;
        __syncthreads();
    }
    if (tt < NB1) bs1[tt] = s[tt] - v1;
    __syncthreads();
    int v2 = (tt < NB2) ? atomicAdd(&bs2[tt], 0) : 0;
    s[tt] = v2;
    __syncthreads();
    for (int off = 1; off < 256; off <<= 1) {
        int u = (tt >= off) ? s[tt - off] : 0;
        __syncthreads();
        s[tt] += u;
        __syncthreads();
    }
    if (tt < NB2) bs2[tt] = s[tt] - v2;
}

__global__ __launch_bounds__(256) void bscan_both(
    int* __restrict__ cnt1, const int* __restrict__ bs1, int* __restrict__ rp1,
    int* __restrict__ cnt2, const int* __restrict__ bs2, int* __restrict__ rp2) {
    __shared__ int s[256];
    int b = blockIdx.x;
    int* cnt; const int* bs; int* rp; int n, lb;
    if (b < NB1) { cnt = cnt1; bs = bs1; rp = rp1; n = N1; lb = b; }
    else { cnt = cnt2; bs = bs2; rp = rp2; n = N2; lb = b - NB1; }
    int t = lb * 256 + threadIdx.x;
    int v = (t < n) ? cnt[t] : 0;
    if (t < n) cnt[t] = 0;
    s[threadIdx.x] = v;
    __syncthreads();
    for (int off = 1; off < 256; off <<= 1) {
        int u = (threadIdx.x >= off) ? s[threadIdx.x - off] : 0;
        __syncthreads();
        s[threadIdx.x] += u;
        __syncthreads();
    }
    int incl = s[threadIdx.x];
    int base = bs[lb];
    if (t < n) rp[t] = base + incl - v;
    if (t == n - 1) rp[n] = base + incl;
}

__global__ __launch_bounds__(256) void fill_both(
    const int* __restrict__ d1, const int* __restrict__ rp1,
    int* __restrict__ cur1, int* __restrict__ eix1,
    const int* __restrict__ d2, const int* __restrict__ rp2,
    int* __restrict__ cur2, int* __restrict__ eix2) {
    int t = blockIdx.x * 256 + threadIdx.x;
    if (t < E1C) {
        int d = d1[t];
        eix1[rp1[d] + atomicAdd(&cur1[d], 1)] = t;
    } else {
        t -= E1C;
        if (t < E2C) {
            int d = d2[t];
            eix2[rp2[d] + atomicAdd(&cur2[d], 1)] = t;
        }
    }
}

// ---------------------------------------------------------------------------
// Fused aggregation with index prefetch (software pipeline over the
// eidx -> src/et/ets -> KV dependent-load chain)
// ---------------------------------------------------------------------------
__global__ __launch_bounds__(256) void agg_layer1(
    const int* __restrict__ rowptr, const int* __restrict__ eidx,
    const int* __restrict__ src, const int* __restrict__ et, const int* __restrict__ ets,
    const float* __restrict__ TA, const float* __restrict__ TB,
    const float* __restrict__ QR, const unsigned short* __restrict__ KV,
    const float* __restrict__ Wbeta,
    const float* __restrict__ ln_g, const float* __restrict__ ln_b,
    unsigned short* __restrict__ hout, int n) {
    int wid = (blockIdx.x * blockDim.x + threadIdx.x) >> 6;
    int lane = threadIdx.x & 63;
    if (wid >= n) return;
    int s = lane >> 5, cg = lane & 15;
    int co = ((lane >> 4) & 1) * 64 + 4 * cg;
    int beg = rowptr[wid], end = rowptr[wid + 1];
    float4 q4 = *(const float4*)(QR + (size_t)wid * 256 + co);
    float ax = 0.f, ay = 0.f, az = 0.f, aw = 0.f, suma = 0.f;
    int p = beg + s;
    if (p < end) {
        int e = eidx[p];
        int sn = src[e], t = et[e], ts = ets[e];
        for (;;) {
            int pn = p + 2;
            bool more = pn < end;
            int en = eidx[more ? pn : beg];
            int snn = src[en], tn = et[en], tsn = ets[en];
            float4 ta = *(const float4*)(TA + t * 128 + co);
            float4 tb = *(const float4*)(TB + ts * 128 + co);
            float e0 = ta.x + tb.x, e1 = ta.y + tb.y, e2 = ta.z + tb.z, e3 = ta.w + tb.w;
            const unsigned short* kv = KV + (size_t)sn * 256;
            ushort4 ku = *(const ushort4*)(kv + co);
            ushort4 vu = *(const ushort4*)(kv + 128 + co);
            float pp = q4.x * (b2f(ku.x) + e0) + q4.y * (b2f(ku.y) + e1)
                     + q4.z * (b2f(ku.z) + e2) + q4.w * (b2f(ku.w) + e3);
            pp += __shfl_xor(pp, 1); pp += __shfl_xor(pp, 2);
            pp += __shfl_xor(pp, 4); pp += __shfl_xor(pp, 8);
            float a = expf(pp * 0.125f);
            ax += a * (b2f(vu.x) + e0); ay += a * (b2f(vu.y) + e1);
            az += a * (b2f(vu.z) + e2); aw += a * (b2f(vu.w) + e3);
            suma += a;
            if (!more) break;
            p = pn; sn = snn; t = tn; ts = tsn;
        }
    }
    ax += __shfl_xor(ax, 32); ay += __shfl_xor(ay, 32);
    az += __shfl_xor(az, 32); aw += __shfl_xor(aw, 32);
    suma += __shfl_xor(suma, 32);
    float inv_s = 1.f / (suma + 1e-16f);
    float ox = ax * inv_s, oy = ay * inv_s, oz = az * inv_s, ow = aw * inv_s;
    float4 r4 = *(const float4*)(QR + (size_t)wid * 256 + 128 + co);
    float4 wo = *(const float4*)(Wbeta + co);
    float4 wr = *(const float4*)(Wbeta + 128 + co);
    float4 wd = *(const float4*)(Wbeta + 256 + co);
    float pb = wo.x * ox + wr.x * r4.x + wd.x * (ox - r4.x)
             + wo.y * oy + wr.y * r4.y + wd.y * (oy - r4.y)
             + wo.z * oz + wr.z * r4.z + wd.z * (oz - r4.z)
             + wo.w * ow + wr.w * r4.w + wd.w * (ow - r4.w);
    pb += __shfl_xor(pb, 1); pb += __shfl_xor(pb, 2); pb += __shfl_xor(pb, 4);
    pb += __shfl_xor(pb, 8); pb += __shfl_xor(pb, 16);
    float beta = 1.f / (1.f + expf(-pb));
    float gx = beta * r4.x + (1.f - beta) * ox;
    float gy = beta * r4.y + (1.f - beta) * oy;
    float gz = beta * r4.z + (1.f - beta) * oz;
    float gw = beta * r4.w + (1.f - beta) * ow;
    float sm = gx + gy + gz + gw;
    float sq = gx * gx + gy * gy + gz * gz + gw * gw;
    sm += __shfl_xor(sm, 1); sq += __shfl_xor(sq, 1);
    sm += __shfl_xor(sm, 2); sq += __shfl_xor(sq, 2);
    sm += __shfl_xor(sm, 4); sq += __shfl_xor(sq, 4);
    sm += __shfl_xor(sm, 8); sq += __shfl_xor(sq, 8);
    sm += __shfl_xor(sm, 16); sq += __shfl_xor(sq, 16);
    float mu = sm * (1.f / 128.f);
    float var = sq * (1.f / 128.f) - mu * mu;
    float inv = rsqrtf(var + 1e-5f);
    float4 lg = *(const float4*)(ln_g + co);
    float4 lb = *(const float4*)(ln_b + co);
    float yx = (gx - mu) * inv * lg.x + lb.x;
    float yy = (gy - mu) * inv * lg.y + lb.y;
    float yz = (gz - mu) * inv * lg.z + lb.z;
    float yw = (gw - mu) * inv * lg.w + lb.w;
    const float ISQ2 = 0.70710678118654752f;
    yx = 0.5f * yx * (1.f + erff(yx * ISQ2));
    yy = 0.5f * yy * (1.f + erff(yy * ISQ2));
    yz = 0.5f * yz * (1.f + erff(yz * ISQ2));
    yw = 0.5f * yw * (1.f + erff(yw * ISQ2));
    if (s == 0) {
        ushort4 hv;
        hv.x = f2b(yx); hv.y = f2b(yy); hv.z = f2b(yz); hv.w = f2b(yw);
        *(ushort4*)(hout + (size_t)wid * 128 + co) = hv;
    }
}

__global__ __launch_bounds__(256) void agg_layer2(
    const int* __restrict__ rowptr, const int* __restrict__ eidx,
    const int* __restrict__ src, const int* __restrict__ et, const int* __restrict__ ets,
    const float* __restrict__ TA, const float* __restrict__ TB,
    const float* __restrict__ QR, const unsigned short* __restrict__ KV,
    const float* __restrict__ Wbeta,
    float* __restrict__ o, int n) {
    int wid = (blockIdx.x * blockDim.x + threadIdx.x) >> 6;
    int lane = threadIdx.x & 63;
    if (wid >= n) return;
    int s = lane >> 5, cg = lane & 15;
    int co = ((lane >> 4) & 1) * 64 + 4 * cg;
    int beg = rowptr[wid], end = rowptr[wid + 1];
    float4 q4 = *(const float4*)(QR + (size_t)wid * 192 + co);
    float ax = 0.f, ay = 0.f, az = 0.f, aw = 0.f, suma = 0.f;
    int p = beg + s;
    if (p < end) {
        int e = eidx[p];
        int sn = src[e], t = et[e], ts = ets[e];
        for (;;) {
            int pn = p + 2;
            bool more = pn < end;
            int en = eidx[more ? pn : beg];
            int snn = src[en], tn = et[en], tsn = ets[en];
            float4 ta = *(const float4*)(TA + t * 128 + co);
            float4 tb = *(const float4*)(TB + ts * 128 + co);
            float e0 = ta.x + tb.x, e1 = ta.y + tb.y, e2 = ta.z + tb.z, e3 = ta.w + tb.w;
            const unsigned short* kv = KV + (size_t)sn * 256;
            ushort4 ku = *(const ushort4*)(kv + co);
            ushort4 vu = *(const ushort4*)(kv + 128 + co);
            float pp = q4.x * (b2f(ku.x) + e0) + q4.y * (b2f(ku.y) + e1)
                     + q4.z * (b2f(ku.z) + e2) + q4.w * (b2f(ku.w) + e3);
            pp += __shfl_xor(pp, 1); pp += __shfl_xor(pp, 2);
            pp += __shfl_xor(pp, 4); pp += __shfl_xor(pp, 8);
            float a = expf(pp * 0.125f);
            ax += a * (b2f(vu.x) + e0); ay += a * (b2f(vu.y) + e1);
            az += a * (b2f(vu.z) + e2); aw += a * (b2f(vu.w) + e3);
            suma += a;
            if (!more) break;
            p = pn; sn = snn; t = tn; ts = tsn;
        }
    }
    ax += __shfl_xor(ax, 32); ay += __shfl_xor(ay, 32);
    az += __shfl_xor(az, 32); aw += __shfl_xor(aw, 32);
    suma += __shfl_xor(suma, 32);
    float inv_s = 1.f / (suma + 1e-16f);
    float ox = ax * inv_s, oy = ay * inv_s, oz = az * inv_s, ow = aw * inv_s;
    ox = 0.5f * (ox + __shfl_xor(ox, 16));
    oy = 0.5f * (oy + __shfl_xor(oy, 16));
    oz = 0.5f * (oz + __shfl_xor(oz, 16));
    ow = 0.5f * (ow + __shfl_xor(ow, 16));
    float4 r4 = *(const float4*)(QR + (size_t)wid * 192 + 128 + 4 * cg);
    float4 wo = *(const float4*)(Wbeta + 4 * cg);
    float4 wr = *(const float4*)(Wbeta + 64 + 4 * cg);
    float4 wd = *(const float4*)(Wbeta + 128 + 4 * cg);
    float pb = wo.x * ox + wr.x * r4.x + wd.x * (ox - r4.x)
             + wo.y * oy + wr.y * r4.y + wd.y * (oy - r4.y)
             + wo.z * oz + wr.z * r4.z + wd.z * (oz - r4.z)
             + wo.w * ow + wr.w * r4.w + wd.w * (ow - r4.w);
    pb += __shfl_xor(pb, 1); pb += __shfl_xor(pb, 2);
    pb += __shfl_xor(pb, 4); pb += __shfl_xor(pb, 8);
    float beta = 1.f / (1.f + expf(-pb));
    float vx = beta * r4.x + (1.f - beta) * ox;
    float vy = beta * r4.y + (1.f - beta) * oy;
    float vz = beta * r4.z + (1.f - beta) * oz;
    float vw = beta * r4.w + (1.f - beta) * ow;
    float m = fmaxf(fmaxf(vx, vy), fmaxf(vz, vw));
    m = fmaxf(m, __shfl_xor(m, 1)); m = fmaxf(m, __shfl_xor(m, 2));
    m = fmaxf(m, __shfl_xor(m, 4)); m = fmaxf(m, __shfl_xor(m, 8));
    float se = expf(vx - m) + expf(vy - m) + expf(vz - m) + expf(vw - m);
    se += __shfl_xor(se, 1); se += __shfl_xor(se, 2);
    se += __shfl_xor(se, 4); se += __shfl_xor(se, 8);
    float lse = m + logf(se);
    if (lane < 16)
        *(float4*)(o + (size_t)wid * 64 + 4 * cg) =
            make_float4(vx - lse, vy - lse, vz - lse, vw - lse);
}

extern "C" void kernel_launch(void* const* d_in, const int* in_sizes, int n_in,
                              void* d_out, int out_size, void* d_ws, size_t ws_size,
                              hipStream_t stream) {
    const float* x        = (const float*)d_in[0];
    const int*   ei1_src  = (const int*)d_in[1];
    const int*   ei1_dst  = (const int*)d_in[2];
    const int*   et1      = (const int*)d_in[3];
    const int*   ets1     = (const int*)d_in[4];
    const int*   ei2_src  = (const int*)d_in[5];
    const int*   ei2_dst  = (const int*)d_in[6];
    const int*   et2      = (const int*)d_in[7];
    const int*   ets2     = (const int*)d_in[8];
    const float* edge_W   = (const float*)d_in[9];
    const float* edge_b   = (const float*)d_in[10];
    const float* time_W   = (const float*)d_in[11];
    const float* time_b   = (const float*)d_in[12];
    const float* Wq1      = (const float*)d_in[13];
    const float* bq1      = (const float*)d_in[14];
    const float* Wk1      = (const float*)d_in[15];
    const float* bk1      = (const float*)d_in[16];
    const float* Wv1      = (const float*)d_in[17];
    const float* bv1      = (const float*)d_in[18];
    const float* We1      = (const float*)d_in[19];
    const float* Wskip1   = (const float*)d_in[20];
    const float* bskip1   = (const float*)d_in[21];
    const float* Wbeta1   = (const float*)d_in[22];
    const float* ln_g     = (const float*)d_in[23];
    const float* ln_b     = (const float*)d_in[24];
    const float* Wq2      = (const float*)d_in[25];
    const float* bq2      = (const float*)d_in[26];
    const float* Wk2      = (const float*)d_in[27];
    const float* bk2      = (const float*)d_in[28];
    const float* Wv2      = (const float*)d_in[29];
    const float* bv2      = (const float*)d_in[30];
    const float* We2      = (const float*)d_in[31];
    const float* Wskip2   = (const float*)d_in[32];
    const float* bskip2   = (const float*)d_in[33];
    const float* Wbeta2   = (const float*)d_in[34];

    float* ws = (float*)d_ws;
    unsigned short* xb  = (unsigned short*)(ws + OFF_XB);
    float* qr1          = ws + OFF_QR1;
    unsigned short* kv1 = (unsigned short*)(ws + OFF_KV1);
    unsigned short* h   = (unsigned short*)(ws + OFF_H);
    float* qr2          = ws + OFF_QR2;
    unsigned short* kv2 = (unsigned short*)(ws + OFF_KV2);
    unsigned short* wb1 = (unsigned short*)(ws + OFF_WB1);
    float* bp1          = ws + OFF_BP1;
    unsigned short* wb2 = (unsigned short*)(ws + OFF_WB2);
    float* bp2          = ws + OFF_BP2;
    float* ta1          = ws + OFF_TA1;
    float* tb1          = ws + OFF_TB1;
    float* ta2          = ws + OFF_TA2;
    float* tb2          = ws + OFF_TB2;
    int*   rp1          = (int*)(ws + OFF_RP1);
    int*   cur1         = (int*)(ws + OFF_CUR1);
    int*   eix1         = (int*)(ws + OFF_EIX1);
    int*   bs1          = (int*)(ws + OFF_BS1);
    int*   rp2          = (int*)(ws + OFF_RP2);
    int*   cur2         = (int*)(ws + OFF_CUR2);
    int*   eix2         = (int*)(ws + OFF_EIX2);
    int*   bs2          = (int*)(ws + OFF_BS2);
    int*   done         = (int*)(ws + OFF_DONE);

    prep<<<2048, 256, 0, stream>>>(
        x, xb,
        Wk1, Wv1, Wq1, Wskip1, bk1, bv1, bq1, bskip1,
        Wk2, Wv2, Wq2, Wskip2, bk2, bv2, bq2, bskip2,
        wb1, bp1, wb2, bp2,
        edge_W, edge_b, time_W, time_b, We1, We2,
        ta1, tb1, ta2, tb2, cur1, cur2, done);
    mega_l1<<<KV1B + QR1B + CNTB, 256, 0, stream>>>(
        xb, wb1, bp1, kv1, qr1, ei1_dst, ei2_dst, cur1, cur2);
    bsum_scan<<<NB1 + NB2, 256, 0, stream>>>(cur1, bs1, cur2, bs2, done);
    bscan_both<<<NB1 + NB2, 256, 0, stream>>>(cur1, bs1, rp1, cur2, bs2, rp2);
    fill_both<<<FILLB, 256, 0, stream>>>(ei1_dst, rp1, cur1, eix1,
                                         ei2_dst, rp2, cur2, eix2);
    agg_layer1<<<(N1 + 3) / 4, 256, 0, stream>>>(rp1, eix1, ei1_src, et1, ets1,
        ta1, tb1, qr1, kv1, Wbeta1, ln_g, ln_b, h, N1);
    gemm_l2<<<KV2B + QR2B, 256, 0, stream>>>(h, wb2, bp2, kv2, qr2);
    agg_layer2<<<(N2 + 3) / 4, 256, 0, stream>>>(rp2, eix2, ei2_src, et2, ets2,
        ta2, tb2, qr2, kv2, Wbeta2, (float*)d_out, N2);
}

// Round 8
// 408.147 us; speedup vs baseline: 10.2435x; 1.0862x over previous
//
#include <hip/hip_runtime.h>
#include <math.h>

// Problem constants
#define N0 80000
#define N1 40000
#define N2 20000
#define E1C 500000
#define E2C 250000
#define NTYPE 23
#define NTS 1158

// derived grid constants
#define NB1 157           // ceil(N1/256)
#define NB2 79            // ceil(N2/256)
#define KV1B 1250         // ceil(N0/64)
#define QR1B 625          // ceil(N1/64)
#define CNTB 2930         // ceil((E1C+E2C)/256)
#define KV2B 625          // ceil(N1/64)
#define QR2B 313          // ceil(N2/64)
#define FILLB 2930        // ceil((E1C+E2C)/256)

// ---------------- Workspace layout (float offsets) ----------------
#define OFF_XB    0u           // N0*128 bf16
#define OFF_QR1   5120000u     // N1*256 f32 (q|xr)
#define OFF_KV1   15360000u    // N0*256 bf16
#define OFF_H     25600000u    // N1*128 bf16
#define OFF_QR2   28160000u    // N2*192 f32
#define OFF_KV2   32000000u    // N1*256 bf16
#define OFF_WB1   37120000u    // 512*128 bf16 (fragment-linear)
#define OFF_BP1   37160000u    // 512 f32
#define OFF_WB2   37170000u    // 448*128 bf16 (fragment-linear)
#define OFF_BP2   37200000u    // 448 f32
#define OFF_TA1   37210000u
#define OFF_TB1   37213000u
#define OFF_TA2   37370000u
#define OFF_TB2   37373000u
#define OFF_RP1   37530000u    // N1+1 ints
#define OFF_CUR1  37580000u    // N1 ints
#define OFF_EIX1  37630000u    // E1 ints
#define OFF_BS1   38140000u    // 256 ints
#define OFF_RP2   38150000u    // N2+1 ints
#define OFF_CUR2  38180000u    // N2 ints
#define OFF_EIX2  38210000u    // E2 ints
#define OFF_BS2   38470000u    // 256 ints
#define OFF_DONE  38480000u    // 1 int

typedef __bf16 bf16x8 __attribute__((ext_vector_type(8)));
typedef float f32x4 __attribute__((ext_vector_type(4)));

static __device__ __forceinline__ float b2f(unsigned short u) {
    union { unsigned int i; float f; } c;
    c.i = ((unsigned int)u) << 16;
    return c.f;
}
static __device__ __forceinline__ unsigned short f2b(float f) {
    unsigned int u = __float_as_uint(f);
    unsigned int r = (u + 0x7fffu + ((u >> 16) & 1u)) >> 16;
    return (unsigned short)r;
}
static __device__ __forceinline__ bf16x8 ldfrag(const unsigned short* p) {
    return *reinterpret_cast<const bf16x8*>(p);
}

// ---------------------------------------------------------------------------
// Device GEMM bodies (MFMA 16x16x32 bf16).
// WB is FRAGMENT-LINEAR: WB[((t*4+ks)*64 + lane)*8 + j] so each B-load is a
// single coalesced 1KB wave transaction.
// ---------------------------------------------------------------------------
#define LDSS 136   // 16B-aligned padded row (ushorts)

template <int NTILES>
static __device__ __forceinline__ void dev_gemm_bf16out(
    const unsigned short* __restrict__ XB, const unsigned short* __restrict__ WB,
    const float* __restrict__ BP, unsigned short* __restrict__ Y, int n, int blk,
    unsigned short* sb) {
    constexpr int COLS = NTILES * 16;
    constexpr int HALF = NTILES / 2;
    constexpr int HCOLS = HALF * 16;
    int wave = threadIdx.x >> 6, lane = threadIdx.x & 63;
    int m = lane & 15, quad = lane >> 4;
    int rowbase = blk * 64 + wave * 16;
    int arow = rowbase + m; if (arow >= n) arow = n - 1;
    unsigned short* swave = sb + wave * 16 * LDSS;
    const unsigned short* xrow = XB + (size_t)arow * 128 + quad * 8;
    bf16x8 a0 = ldfrag(xrow), a1 = ldfrag(xrow + 32);
    bf16x8 a2 = ldfrag(xrow + 64), a3 = ldfrag(xrow + 96);
    f32x4 acc[NTILES];
#pragma unroll
    for (int t = 0; t < NTILES; t++) acc[t] = (f32x4){0.f, 0.f, 0.f, 0.f};
#pragma unroll
    for (int t = 0; t < NTILES; t++) {
        const unsigned short* wt = WB + (size_t)t * 2048 + lane * 8;
        acc[t] = __builtin_amdgcn_mfma_f32_16x16x32_bf16(a0, ldfrag(wt), acc[t], 0, 0, 0);
        acc[t] = __builtin_amdgcn_mfma_f32_16x16x32_bf16(a1, ldfrag(wt + 512), acc[t], 0, 0, 0);
        acc[t] = __builtin_amdgcn_mfma_f32_16x16x32_bf16(a2, ldfrag(wt + 1024), acc[t], 0, 0, 0);
        acc[t] = __builtin_amdgcn_mfma_f32_16x16x32_bf16(a3, ldfrag(wt + 1536), acc[t], 0, 0, 0);
    }
    int tswz_bit = (quad >> 1) & 1;   // == (row>>3) for row = quad*4+r
#pragma unroll
    for (int half = 0; half < 2; half++) {
#pragma unroll
        for (int t = 0; t < HALF; t++) {
            int tt = half * HALF + t;
            int tsw = t ^ tswz_bit;
            float b = BP[tt * 16 + m];
#pragma unroll
            for (int r = 0; r < 4; r++)
                swave[(quad * 4 + r) * LDSS + tsw * 16 + m] = f2b(acc[tt][r] + b);
        }
        // per-wave LDS; DS ops execute in order per wave -> no barrier
#pragma unroll
        for (int i = 0; i < 4; i++) {
            int idx = i * 64 + lane;
            int r = idx / (HCOLS / 8), g = idx % (HCOLS / 8);
            int gs = g ^ (((r >> 3) & 1) << 1);
            int grow = rowbase + r;
            if (grow < n) {
                uint4 v = *(const uint4*)&swave[r * LDSS + gs * 8];
                *(uint4*)(Y + (size_t)grow * COLS + half * HCOLS + g * 8) = v;
            }
        }
    }
}

template <int NTILES>
static __device__ __forceinline__ void dev_gemm_f32out(
    const unsigned short* __restrict__ XB, const unsigned short* __restrict__ WB,
    const float* __restrict__ BP, float* __restrict__ Y, int n, int blk) {
    constexpr int COLS = NTILES * 16;
    int wave = threadIdx.x >> 6, lane = threadIdx.x & 63;
    int m = lane & 15, quad = lane >> 4;
    int rowbase = blk * 64 + wave * 16;
    int arow = rowbase + m; if (arow >= n) arow = n - 1;
    const unsigned short* xrow = XB + (size_t)arow * 128 + quad * 8;
    bf16x8 a0 = ldfrag(xrow), a1 = ldfrag(xrow + 32);
    bf16x8 a2 = ldfrag(xrow + 64), a3 = ldfrag(xrow + 96);
    f32x4 acc[NTILES];
#pragma unroll
    for (int t = 0; t < NTILES; t++) acc[t] = (f32x4){0.f, 0.f, 0.f, 0.f};
#pragma unroll
    for (int t = 0; t < NTILES; t++) {
        const unsigned short* wt = WB + (size_t)t * 2048 + lane * 8;
        acc[t] = __builtin_amdgcn_mfma_f32_16x16x32_bf16(a0, ldfrag(wt), acc[t], 0, 0, 0);
        acc[t] = __builtin_amdgcn_mfma_f32_16x16x32_bf16(a1, ldfrag(wt + 512), acc[t], 0, 0, 0);
        acc[t] = __builtin_amdgcn_mfma_f32_16x16x32_bf16(a2, ldfrag(wt + 1024), acc[t], 0, 0, 0);
        acc[t] = __builtin_amdgcn_mfma_f32_16x16x32_bf16(a3, ldfrag(wt + 1536), acc[t], 0, 0, 0);
    }
#pragma unroll
    for (int t = 0; t < NTILES; t++) {
        float b = BP[t * 16 + m];
#pragma unroll
        for (int r = 0; r < 4; r++) {
            int grow = rowbase + quad * 4 + r;
            if (grow < n) Y[(size_t)grow * COLS + t * 16 + m] = acc[t][r] + b;
        }
    }
}

// ---------------------------------------------------------------------------
// prep: pack weights (fragment-linear), convert x->bf16, edge tables, zero cnt
// ---------------------------------------------------------------------------
__global__ __launch_bounds__(256) void prep(
    const float* __restrict__ x, unsigned short* __restrict__ XB,
    const float* __restrict__ Wk1, const float* __restrict__ Wv1,
    const float* __restrict__ Wq1, const float* __restrict__ Wskip1,
    const float* __restrict__ bk1, const float* __restrict__ bv1,
    const float* __restrict__ bq1, const float* __restrict__ bskip1,
    const float* __restrict__ Wk2, const float* __restrict__ Wv2,
    const float* __restrict__ Wq2, const float* __restrict__ Wskip2,
    const float* __restrict__ bk2, const float* __restrict__ bv2,
    const float* __restrict__ bq2, const float* __restrict__ bskip2,
    unsigned short* __restrict__ WB1, float* __restrict__ BP1,
    unsigned short* __restrict__ WB2, float* __restrict__ BP2,
    const float* __restrict__ edge_W, const float* __restrict__ edge_b,
    const float* __restrict__ time_W, const float* __restrict__ time_b,
    const float* __restrict__ We1, const float* __restrict__ We2,
    float* __restrict__ TA1, float* __restrict__ TB1,
    float* __restrict__ TA2, float* __restrict__ TB2,
    int* __restrict__ cnt1, int* __restrict__ cnt2, int* __restrict__ done) {
    int tid = blockIdx.x * blockDim.x + threadIdx.x;
    int stride = gridDim.x * blockDim.x;
    for (int i = tid; i < N0 * 32; i += stride) {
        float4 v = *(const float4*)(x + (size_t)i * 4);
        ushort4 u;
        u.x = f2b(v.x); u.y = f2b(v.y); u.z = f2b(v.z); u.w = f2b(v.w);
        *(ushort4*)(XB + (size_t)i * 4) = u;
    }
    // fragment-linear pack: WB[((t*4+ks)*64+l)*8+j] = W[t*16+(l&15)][ks*32+((l>>4)&3)*8+j]
    for (int i = tid; i < 512 * 128; i += stride) {
        int j = i & 7, l = (i >> 3) & 63, ks = (i >> 9) & 3, t = i >> 11;
        int row = t * 16 + (l & 15);
        int col = ks * 32 + ((l >> 4) & 3) * 8 + j;
        const float* w; int off;
        if (row < 128) { w = Wk1; off = 0; }
        else if (row < 256) { w = Wv1; off = 128; }
        else if (row < 384) { w = Wq1; off = 256; }
        else { w = Wskip1; off = 384; }
        WB1[i] = f2b(w[(size_t)(row - off) * 128 + col]);
    }
    for (int i = tid; i < 512; i += stride) {
        const float* b; int off;
        if (i < 128) { b = bk1; off = 0; }
        else if (i < 256) { b = bv1; off = 128; }
        else if (i < 384) { b = bq1; off = 256; }
        else { b = bskip1; off = 384; }
        BP1[i] = b[i - off];
    }
    for (int i = tid; i < 448 * 128; i += stride) {
        int j = i & 7, l = (i >> 3) & 63, ks = (i >> 9) & 3, t = i >> 11;
        int row = t * 16 + (l & 15);
        int col = ks * 32 + ((l >> 4) & 3) * 8 + j;
        const float* w; int off;
        if (row < 128) { w = Wk2; off = 0; }
        else if (row < 256) { w = Wv2; off = 128; }
        else if (row < 384) { w = Wq2; off = 256; }
        else { w = Wskip2; off = 384; }
        WB2[i] = f2b(w[(size_t)(row - off) * 128 + col]);
    }
    for (int i = tid; i < 448; i += stride) {
        const float* b; int off;
        if (i < 128) { b = bk2; off = 0; }
        else if (i < 256) { b = bv2; off = 128; }
        else if (i < 384) { b = bq2; off = 256; }
        else { b = bskip2; off = 384; }
        BP2[i] = b[i - off];
    }
    const int TBL = (NTYPE + NTS) * 128;
    for (int i = tid; i < TBL; i += stride) {
        if (i < NTYPE * 128) {
            int e = i >> 7, c = i & 127;
            float s1 = 0.f, s2 = 0.f;
#pragma unroll
            for (int j = 0; j < 10; j++) {
                float fj = edge_W[j * NTYPE + e] + edge_b[j];
                s1 += fj * We1[c * 20 + j];
                s2 += fj * We2[c * 20 + j];
            }
            TA1[i] = s1; TA2[i] = s2;
        } else {
            int u = i - NTYPE * 128;
            int ts = u >> 7, c = u & 127;
            float s1 = 0.f, s2 = 0.f;
#pragma unroll
            for (int j = 0; j < 10; j++) {
                float fj = time_W[j * NTS + ts] + time_b[j];
                s1 += fj * We1[c * 20 + 10 + j];
                s2 += fj * We2[c * 20 + 10 + j];
            }
            TB1[u] = s1; TB2[u] = s2;
        }
    }
    for (int i = tid; i < N1 + N2 + 1; i += stride) {
        if (i < N1) cnt1[i] = 0;
        else if (i < N1 + N2) cnt2[i - N1] = 0;
        else *done = 0;
    }
}

// ---------------------------------------------------------------------------
// mega_l1: KV1 GEMM | QR1 GEMM | degree count, block-partitioned
// ---------------------------------------------------------------------------
__global__ __launch_bounds__(256) void mega_l1(
    const unsigned short* __restrict__ XB,
    const unsigned short* __restrict__ WB1, const float* __restrict__ BP1,
    unsigned short* __restrict__ KV1, float* __restrict__ QR1,
    const int* __restrict__ d1, const int* __restrict__ d2,
    int* __restrict__ cnt1, int* __restrict__ cnt2) {
    __shared__ unsigned short sbuf[4 * 16 * LDSS];
    int b = blockIdx.x;
    if (b < KV1B) {
        dev_gemm_bf16out<16>(XB, WB1, BP1, KV1, N0, b, sbuf);
    } else if (b < KV1B + QR1B) {
        dev_gemm_f32out<16>(XB, WB1 + 256 * 128, BP1 + 256, QR1, N1, b - KV1B);
    } else {
        int t = (b - KV1B - QR1B) * 256 + threadIdx.x;
        if (t < E1C) atomicAdd(&cnt1[d1[t]], 1);
        else {
            t -= E1C;
            if (t < E2C) atomicAdd(&cnt2[d2[t]], 1);
        }
    }
}

__global__ __launch_bounds__(256) void gemm_l2(
    const unsigned short* __restrict__ H,
    const unsigned short* __restrict__ WB2, const float* __restrict__ BP2,
    unsigned short* __restrict__ KV2, float* __restrict__ QR2) {
    __shared__ unsigned short sbuf[4 * 16 * LDSS];
    int b = blockIdx.x;
    if (b < KV2B) dev_gemm_bf16out<16>(H, WB2, BP2, KV2, N1, b, sbuf);
    else dev_gemm_f32out<12>(H, WB2 + 256 * 128, BP2 + 256, QR2, N2, b - KV2B);
}

// ---------------------------------------------------------------------------
// bsum_scan / bscan_both / fill_both (unchanged)
// ---------------------------------------------------------------------------
__global__ __launch_bounds__(256) void bsum_scan(
    const int* __restrict__ cnt1, int* __restrict__ bs1,
    const int* __restrict__ cnt2, int* __restrict__ bs2, int* __restrict__ done) {
    __shared__ int s[256];
    __shared__ int amlast;
    int b = blockIdx.x;
    const int* cnt; int* bs; int n, lb;
    if (b < NB1) { cnt = cnt1; bs = bs1; n = N1; lb = b; }
    else { cnt = cnt2; bs = bs2; n = N2; lb = b - NB1; }
    int t = lb * 256 + threadIdx.x;
    s[threadIdx.x] = (t < n) ? cnt[t] : 0;
    __syncthreads();
    for (int off = 128; off; off >>= 1) {
        if (threadIdx.x < off) s[threadIdx.x] += s[threadIdx.x + off];
        __syncthreads();
    }
    if (threadIdx.x == 0) {
        atomicExch(&bs[lb], s[0]);
        __threadfence();
        int prev = atomicAdd(done, 1);
        amlast = (prev == NB1 + NB2 - 1) ? 1 : 0;
    }
    __syncthreads();
    if (!amlast) return;
    int tt = threadIdx.x;
    int v1 = (tt < NB1) ? atomicAdd(&bs1[tt], 0) : 0;
    s[tt] = v1;
    __syncthreads();
    for (int off = 1; off < 256; off <<= 1) {
        int u = (tt >= off) ? s[tt - off] : 0;
        __syncthreads();
        s[tt] += u;
        __syncthreads();
    }
    if (tt < NB1) bs1[tt] = s[tt] - v1;
    __syncthreads();
    int v2 = (tt < NB2) ? atomicAdd(&bs2[tt], 0) : 0;
    s[tt] = v2;
    __syncthreads();
    for (int off = 1; off < 256; off <<= 1) {
        int u = (tt >= off) ? s[tt - off] : 0;
        __syncthreads();
        s[tt] += u;
        __syncthreads();
    }
    if (tt < NB2) bs2[tt] = s[tt] - v2;
}

__global__ __launch_bounds__(256) void bscan_both(
    int* __restrict__ cnt1, const int* __restrict__ bs1, int* __restrict__ rp1,
    int* __restrict__ cnt2, const int* __restrict__ bs2, int* __restrict__ rp2) {
    __shared__ int s[256];
    int b = blockIdx.x;
    int* cnt; const int* bs; int* rp; int n, lb;
    if (b < NB1) { cnt = cnt1; bs = bs1; rp = rp1; n = N1; lb = b; }
    else { cnt = cnt2; bs = bs2; rp = rp2; n = N2; lb = b - NB1; }
    int t = lb * 256 + threadIdx.x;
    int v = (t < n) ? cnt[t] : 0;
    if (t < n) cnt[t] = 0;
    s[threadIdx.x] = v;
    __syncthreads();
    for (int off = 1; off < 256; off <<= 1) {
        int u = (threadIdx.x >= off) ? s[threadIdx.x - off] : 0;
        __syncthreads();
        s[threadIdx.x] += u;
        __syncthreads();
    }
    int incl = s[threadIdx.x];
    int base = bs[lb];
    if (t < n) rp[t] = base + incl - v;
    if (t == n - 1) rp[n] = base + incl;
}

__global__ __launch_bounds__(256) void fill_both(
    const int* __restrict__ d1, const int* __restrict__ rp1,
    int* __restrict__ cur1, int* __restrict__ eix1,
    const int* __restrict__ d2, const int* __restrict__ rp2,
    int* __restrict__ cur2, int* __restrict__ eix2) {
    int t = blockIdx.x * 256 + threadIdx.x;
    if (t < E1C) {
        int d = d1[t];
        eix1[rp1[d] + atomicAdd(&cur1[d], 1)] = t;
    } else {
        t -= E1C;
        if (t < E2C) {
            int d = d2[t];
            eix2[rp2[d] + atomicAdd(&cur2[d], 1)] = t;
        }
    }
}

// ---------------------------------------------------------------------------
// Fused aggregation with index prefetch (unchanged from round 7)
// ---------------------------------------------------------------------------
__global__ __launch_bounds__(256) void agg_layer1(
    const int* __restrict__ rowptr, const int* __restrict__ eidx,
    const int* __restrict__ src, const int* __restrict__ et, const int* __restrict__ ets,
    const float* __restrict__ TA, const float* __restrict__ TB,
    const float* __restrict__ QR, const unsigned short* __restrict__ KV,
    const float* __restrict__ Wbeta,
    const float* __restrict__ ln_g, const float* __restrict__ ln_b,
    unsigned short* __restrict__ hout, int n) {
    int wid = (blockIdx.x * blockDim.x + threadIdx.x) >> 6;
    int lane = threadIdx.x & 63;
    if (wid >= n) return;
    int s = lane >> 5, cg = lane & 15;
    int co = ((lane >> 4) & 1) * 64 + 4 * cg;
    int beg = rowptr[wid], end = rowptr[wid + 1];
    float4 q4 = *(const float4*)(QR + (size_t)wid * 256 + co);
    float ax = 0.f, ay = 0.f, az = 0.f, aw = 0.f, suma = 0.f;
    int p = beg + s;
    if (p < end) {
        int e = eidx[p];
        int sn = src[e], t = et[e], ts = ets[e];
        for (;;) {
            int pn = p + 2;
            bool more = pn < end;
            int en = eidx[more ? pn : beg];
            int snn = src[en], tn = et[en], tsn = ets[en];
            float4 ta = *(const float4*)(TA + t * 128 + co);
            float4 tb = *(const float4*)(TB + ts * 128 + co);
            float e0 = ta.x + tb.x, e1 = ta.y + tb.y, e2 = ta.z + tb.z, e3 = ta.w + tb.w;
            const unsigned short* kv = KV + (size_t)sn * 256;
            ushort4 ku = *(const ushort4*)(kv + co);
            ushort4 vu = *(const ushort4*)(kv + 128 + co);
            float pp = q4.x * (b2f(ku.x) + e0) + q4.y * (b2f(ku.y) + e1)
                     + q4.z * (b2f(ku.z) + e2) + q4.w * (b2f(ku.w) + e3);
            pp += __shfl_xor(pp, 1); pp += __shfl_xor(pp, 2);
            pp += __shfl_xor(pp, 4); pp += __shfl_xor(pp, 8);
            float a = expf(pp * 0.125f);
            ax += a * (b2f(vu.x) + e0); ay += a * (b2f(vu.y) + e1);
            az += a * (b2f(vu.z) + e2); aw += a * (b2f(vu.w) + e3);
            suma += a;
            if (!more) break;
            p = pn; sn = snn; t = tn; ts = tsn;
        }
    }
    ax += __shfl_xor(ax, 32); ay += __shfl_xor(ay, 32);
    az += __shfl_xor(az, 32); aw += __shfl_xor(aw, 32);
    suma += __shfl_xor(suma, 32);
    float inv_s = 1.f / (suma + 1e-16f);
    float ox = ax * inv_s, oy = ay * inv_s, oz = az * inv_s, ow = aw * inv_s;
    float4 r4 = *(const float4*)(QR + (size_t)wid * 256 + 128 + co);
    float4 wo = *(const float4*)(Wbeta + co);
    float4 wr = *(const float4*)(Wbeta + 128 + co);
    float4 wd = *(const float4*)(Wbeta + 256 + co);
    float pb = wo.x * ox + wr.x * r4.x + wd.x * (ox - r4.x)
             + wo.y * oy + wr.y * r4.y + wd.y * (oy - r4.y)
             + wo.z * oz + wr.z * r4.z + wd.z * (oz - r4.z)
             + wo.w * ow + wr.w * r4.w + wd.w * (ow - r4.w);
    pb += __shfl_xor(pb, 1); pb += __shfl_xor(pb, 2); pb += __shfl_xor(pb, 4);
    pb += __shfl_xor(pb, 8); pb += __shfl_xor(pb, 16);
    float beta = 1.f / (1.f + expf(-pb));
    float gx = beta * r4.x + (1.f - beta) * ox;
    float gy = beta * r4.y + (1.f - beta) * oy;
    float gz = beta * r4.z + (1.f - beta) * oz;
    float gw = beta * r4.w + (1.f - beta) * ow;
    float sm = gx + gy + gz + gw;
    float sq = gx * gx + gy * gy + gz * gz + gw * gw;
    sm += __shfl_xor(sm, 1); sq += __shfl_xor(sq, 1);
    sm += __shfl_xor(sm, 2); sq += __shfl_xor(sq, 2);
    sm += __shfl_xor(sm, 4); sq += __shfl_xor(sq, 4);
    sm += __shfl_xor(sm, 8); sq += __shfl_xor(sq, 8);
    sm += __shfl_xor(sm, 16); sq += __shfl_xor(sq, 16);
    float mu = sm * (1.f / 128.f);
    float var = sq * (1.f / 128.f) - mu * mu;
    float inv = rsqrtf(var + 1e-5f);
    float4 lg = *(const float4*)(ln_g + co);
    float4 lb = *(const float4*)(ln_b + co);
    float yx = (gx - mu) * inv * lg.x + lb.x;
    float yy = (gy - mu) * inv * lg.y + lb.y;
    float yz = (gz - mu) * inv * lg.z + lb.z;
    float yw = (gw - mu) * inv * lg.w + lb.w;
    const float ISQ2 = 0.70710678118654752f;
    yx = 0.5f * yx * (1.f + erff(yx * ISQ2));
    yy = 0.5f * yy * (1.f + erff(yy * ISQ2));
    yz = 0.5f * yz * (1.f + erff(yz * ISQ2));
    yw = 0.5f * yw * (1.f + erff(yw * ISQ2));
    if (s == 0) {
        ushort4 hv;
        hv.x = f2b(yx); hv.y = f2b(yy); hv.z = f2b(yz); hv.w = f2b(yw);
        *(ushort4*)(hout + (size_t)wid * 128 + co) = hv;
    }
}

__global__ __launch_bounds__(256) void agg_layer2(
    const int* __restrict__ rowptr, const int* __restrict__ eidx,
    const int* __restrict__ src, const int* __restrict__ et, const int* __restrict__ ets,
    const float* __restrict__ TA, const float* __restrict__ TB,
    const float* __restrict__ QR, const unsigned short* __restrict__ KV,
    const float* __restrict__ Wbeta,
    float* __restrict__ o, int n) {
    int wid = (blockIdx.x * blockDim.x + threadIdx.x) >> 6;
    int lane = threadIdx.x & 63;
    if (wid >= n) return;
    int s = lane >> 5, cg = lane & 15;
    int co = ((lane >> 4) & 1) * 64 + 4 * cg;
    int beg = rowptr[wid], end = rowptr[wid + 1];
    float4 q4 = *(const float4*)(QR + (size_t)wid * 192 + co);
    float ax = 0.f, ay = 0.f, az = 0.f, aw = 0.f, suma = 0.f;
    int p = beg + s;
    if (p < end) {
        int e = eidx[p];
        int sn = src[e], t = et[e], ts = ets[e];
        for (;;) {
            int pn = p + 2;
            bool more = pn < end;
            int en = eidx[more ? pn : beg];
            int snn = src[en], tn = et[en], tsn = ets[en];
            float4 ta = *(const float4*)(TA + t * 128 + co);
            float4 tb = *(const float4*)(TB + ts * 128 + co);
            float e0 = ta.x + tb.x, e1 = ta.y + tb.y, e2 = ta.z + tb.z, e3 = ta.w + tb.w;
            const unsigned short* kv = KV + (size_t)sn * 256;
            ushort4 ku = *(const ushort4*)(kv + co);
            ushort4 vu = *(const ushort4*)(kv + 128 + co);
            float pp = q4.x * (b2f(ku.x) + e0) + q4.y * (b2f(ku.y) + e1)
                     + q4.z * (b2f(ku.z) + e2) + q4.w * (b2f(ku.w) + e3);
            pp += __shfl_xor(pp, 1); pp += __shfl_xor(pp, 2);
            pp += __shfl_xor(pp, 4); pp += __shfl_xor(pp, 8);
            float a = expf(pp * 0.125f);
            ax += a * (b2f(vu.x) + e0); ay += a * (b2f(vu.y) + e1);
            az += a * (b2f(vu.z) + e2); aw += a * (b2f(vu.w) + e3);
            suma += a;
            if (!more) break;
            p = pn; sn = snn; t = tn; ts = tsn;
        }
    }
    ax += __shfl_xor(ax, 32); ay += __shfl_xor(ay, 32);
    az += __shfl_xor(az, 32); aw += __shfl_xor(aw, 32);
    suma += __shfl_xor(suma, 32);
    float inv_s = 1.f / (suma + 1e-16f);
    float ox = ax * inv_s, oy = ay * inv_s, oz = az * inv_s, ow = aw * inv_s;
    ox = 0.5f * (ox + __shfl_xor(ox, 16));
    oy = 0.5f * (oy + __shfl_xor(oy, 16));
    oz = 0.5f * (oz + __shfl_xor(oz, 16));
    ow = 0.5f * (ow + __shfl_xor(ow, 16));
    float4 r4 = *(const float4*)(QR + (size_t)wid * 192 + 128 + 4 * cg);
    float4 wo = *(const float4*)(Wbeta + 4 * cg);
    float4 wr = *(const float4*)(Wbeta + 64 + 4 * cg);
    float4 wd = *(const float4*)(Wbeta + 128 + 4 * cg);
    float pb = wo.x * ox + wr.x * r4.x + wd.x * (ox - r4.x)
             + wo.y * oy + wr.y * r4.y + wd.y * (oy - r4.y)
             + wo.z * oz + wr.z * r4.z + wd.z * (oz - r4.z)
             + wo.w * ow + wr.w * r4.w + wd.w * (ow - r4.w);
    pb += __shfl_xor(pb, 1); pb += __shfl_xor(pb, 2);
    pb += __shfl_xor(pb, 4); pb += __shfl_xor(pb, 8);
    float beta = 1.f / (1.f + expf(-pb));
    float vx = beta * r4.x + (1.f - beta) * ox;
    float vy = beta * r4.y + (1.f - beta) * oy;
    float vz = beta * r4.z + (1.f - beta) * oz;
    float vw = beta * r4.w + (1.f - beta) * ow;
    float m = fmaxf(fmaxf(vx, vy), fmaxf(vz, vw));
    m = fmaxf(m, __shfl_xor(m, 1)); m = fmaxf(m, __shfl_xor(m, 2));
    m = fmaxf(m, __shfl_xor(m, 4)); m = fmaxf(m, __shfl_xor(m, 8));
    float se = expf(vx - m) + expf(vy - m) + expf(vz - m) + expf(vw - m);
    se += __shfl_xor(se, 1); se += __shfl_xor(se, 2);
    se += __shfl_xor(se, 4); se += __shfl_xor(se, 8);
    float lse = m + logf(se);
    if (lane < 16)
        *(float4*)(o + (size_t)wid * 64 + 4 * cg) =
            make_float4(vx - lse, vy - lse, vz - lse, vw - lse);
}

extern "C" void kernel_launch(void* const* d_in, const int* in_sizes, int n_in,
                              void* d_out, int out_size, void* d_ws, size_t ws_size,
                              hipStream_t stream) {
    const float* x        = (const float*)d_in[0];
    const int*   ei1_src  = (const int*)d_in[1];
    const int*   ei1_dst  = (const int*)d_in[2];
    const int*   et1      = (const int*)d_in[3];
    const int*   ets1     = (const int*)d_in[4];
    const int*   ei2_src  = (const int*)d_in[5];
    const int*   ei2_dst  = (const int*)d_in[6];
    const int*   et2      = (const int*)d_in[7];
    const int*   ets2     = (const int*)d_in[8];
    const float* edge_W   = (const float*)d_in[9];
    const float* edge_b   = (const float*)d_in[10];
    const float* time_W   = (const float*)d_in[11];
    const float* time_b   = (const float*)d_in[12];
    const float* Wq1      = (const float*)d_in[13];
    const float* bq1      = (const float*)d_in[14];
    const float* Wk1      = (const float*)d_in[15];
    const float* bk1      = (const float*)d_in[16];
    const float* Wv1      = (const float*)d_in[17];
    const float* bv1      = (const float*)d_in[18];
    const float* We1      = (const float*)d_in[19];
    const float* Wskip1   = (const float*)d_in[20];
    const float* bskip1   = (const float*)d_in[21];
    const float* Wbeta1   = (const float*)d_in[22];
    const float* ln_g     = (const float*)d_in[23];
    const float* ln_b     = (const float*)d_in[24];
    const float* Wq2      = (const float*)d_in[25];
    const float* bq2      = (const float*)d_in[26];
    const float* Wk2      = (const float*)d_in[27];
    const float* bk2      = (const float*)d_in[28];
    const float* Wv2      = (const float*)d_in[29];
    const float* bv2      = (const float*)d_in[30];
    const float* We2      = (const float*)d_in[31];
    const float* Wskip2   = (const float*)d_in[32];
    const float* bskip2   = (const float*)d_in[33];
    const float* Wbeta2   = (const float*)d_in[34];

    float* ws = (float*)d_ws;
    unsigned short* xb  = (unsigned short*)(ws + OFF_XB);
    float* qr1          = ws + OFF_QR1;
    unsigned short* kv1 = (unsigned short*)(ws + OFF_KV1);
    unsigned short* h   = (unsigned short*)(ws + OFF_H);
    float* qr2          = ws + OFF_QR2;
    unsigned short* kv2 = (unsigned short*)(ws + OFF_KV2);
    unsigned short* wb1 = (unsigned short*)(ws + OFF_WB1);
    float* bp1          = ws + OFF_BP1;
    unsigned short* wb2 = (unsigned short*)(ws + OFF_WB2);
    float* bp2          = ws + OFF_BP2;
    float* ta1          = ws + OFF_TA1;
    float* tb1          = ws + OFF_TB1;
    float* ta2          = ws + OFF_TA2;
    float* tb2          = ws + OFF_TB2;
    int*   rp1          = (int*)(ws + OFF_RP1);
    int*   cur1         = (int*)(ws + OFF_CUR1);
    int*   eix1         = (int*)(ws + OFF_EIX1);
    int*   bs1          = (int*)(ws + OFF_BS1);
    int*   rp2          = (int*)(ws + OFF_RP2);
    int*   cur2         = (int*)(ws + OFF_CUR2);
    int*   eix2         = (int*)(ws + OFF_EIX2);
    int*   bs2          = (int*)(ws + OFF_BS2);
    int*   done         = (int*)(ws + OFF_DONE);

    prep<<<2048, 256, 0, stream>>>(
        x, xb,
        Wk1, Wv1, Wq1, Wskip1, bk1, bv1, bq1, bskip1,
        Wk2, Wv2, Wq2, Wskip2, bk2, bv2, bq2, bskip2,
        wb1, bp1, wb2, bp2,
        edge_W, edge_b, time_W, time_b, We1, We2,
        ta1, tb1, ta2, tb2, cur1, cur2, done);
    mega_l1<<<KV1B + QR1B + CNTB, 256, 0, stream>>>(
        xb, wb1, bp1, kv1, qr1, ei1_dst, ei2_dst, cur1, cur2);
    bsum_scan<<<NB1 + NB2, 256, 0, stream>>>(cur1, bs1, cur2, bs2, done);
    bscan_both<<<NB1 + NB2, 256, 0, stream>>>(cur1, bs1, rp1, cur2, bs2, rp2);
    fill_both<<<FILLB, 256, 0, stream>>>(ei1_dst, rp1, cur1, eix1,
                                         ei2_dst, rp2, cur2, eix2);
    agg_layer1<<<(N1 + 3) / 4, 256, 0, stream>>>(rp1, eix1, ei1_src, et1, ets1,
        ta1, tb1, qr1, kv1, Wbeta1, ln_g, ln_b, h, N1);
    gemm_l2<<<KV2B + QR2B, 256, 0, stream>>>(h, wb2, bp2, kv2, qr2);
    agg_layer2<<<(N2 + 3) / 4, 256, 0, stream>>>(rp2, eix2, ei2_src, et2, ets2,
        ta2, tb2, qr2, kv2, Wbeta2, (float*)d_out, N2);
}

// Round 10
// 401.349 us; speedup vs baseline: 10.4171x; 1.0169x over previous
//
#include <hip/hip_runtime.h>
#include <math.h>

// Problem constants
#define N0 80000
#define N1 40000
#define N2 20000
#define E1C 500000
#define E2C 250000
#define NTYPE 23
#define NTS 1158

// derived grid constants
#define NB1 157           // ceil(N1/256)
#define NB2 79            // ceil(N2/256)
#define KV1B 1250         // ceil(N0/64)
#define QR1B 625          // ceil(N1/64)
#define CNTB 2930         // ceil((E1C+E2C)/256)
#define KV2B 625          // ceil(N1/64)
#define QR2B 313          // ceil(N2/64)
#define FILLB 2930        // ceil((E1C+E2C)/256)

// ---------------- Workspace layout (float offsets) ----------------
#define OFF_XB    0u           // N0*128 bf16
#define OFF_QR1   5120000u     // N1*256 f32 (q|xr)
#define OFF_KV1   15360000u    // N0*256 bf16
#define OFF_H     25600000u    // N1*128 bf16
#define OFF_QR2   28160000u    // N2*192 f32
#define OFF_KV2   32000000u    // N1*256 bf16
#define OFF_WB1   37120000u    // 512*128 bf16 (fragment-linear)
#define OFF_BP1   37160000u    // 512 f32
#define OFF_WB2   37170000u    // 448*128 bf16 (fragment-linear)
#define OFF_BP2   37200000u    // 448 f32
#define OFF_TA1   37210000u
#define OFF_TB1   37213000u
#define OFF_TA2   37370000u
#define OFF_TB2   37373000u
#define OFF_RP1   37530000u    // N1+1 ints
#define OFF_CUR1  37580000u    // N1 ints
#define OFF_EIX1  37630000u    // E1 ints
#define OFF_BS1   38140000u    // 256 ints
#define OFF_RP2   38150000u    // N2+1 ints
#define OFF_CUR2  38180000u    // N2 ints
#define OFF_EIX2  38210000u    // E2 ints
#define OFF_BS2   38470000u    // 256 ints
#define OFF_DONE  38480000u    // 1 int

typedef __bf16 bf16x8 __attribute__((ext_vector_type(8)));
typedef float f32x4 __attribute__((ext_vector_type(4)));

static __device__ __forceinline__ float b2f(unsigned short u) {
    union { unsigned int i; float f; } c;
    c.i = ((unsigned int)u) << 16;
    return c.f;
}
static __device__ __forceinline__ unsigned short f2b(float f) {
    unsigned int u = __float_as_uint(f);
    unsigned int r = (u + 0x7fffu + ((u >> 16) & 1u)) >> 16;
    return (unsigned short)r;
}
static __device__ __forceinline__ bf16x8 ldfrag(const unsigned short* p) {
    return *reinterpret_cast<const bf16x8*>(p);
}

// DPP 16-lane reductions (row = 16 lanes). VALU-pipe only, no DS round trip.
// CTRL must be a compile-time constant -> template parameter.
template <int CTRL>
static __device__ __forceinline__ float dpp_addstep(float v) {
    int x = __builtin_amdgcn_mov_dpp(__float_as_int(v), CTRL, 0xF, 0xF, true);
    return v + __int_as_float(x);
}
static __device__ __forceinline__ float red16(float v) {
    v = dpp_addstep<0xB1>(v);    // quad_perm [1,0,3,2]  (xor1)
    v = dpp_addstep<0x4E>(v);    // quad_perm [2,3,0,1]  (xor2)
    v = dpp_addstep<0x141>(v);   // row_half_mirror      (pairs 0-7)
    v = dpp_addstep<0x140>(v);   // row_mirror           (halves 0-15)
    return v;
}
template <int CTRL>
static __device__ __forceinline__ float dpp_maxstep(float v) {
    int x = __builtin_amdgcn_mov_dpp(__float_as_int(v), CTRL, 0xF, 0xF, true);
    return fmaxf(v, __int_as_float(x));
}
static __device__ __forceinline__ float red16max(float v) {
    v = dpp_maxstep<0xB1>(v);
    v = dpp_maxstep<0x4E>(v);
    v = dpp_maxstep<0x141>(v);
    v = dpp_maxstep<0x140>(v);
    return v;
}

// ---------------------------------------------------------------------------
// Device GEMM bodies (MFMA 16x16x32 bf16).
// WB is FRAGMENT-LINEAR: WB[((t*4+ks)*64 + lane)*8 + j] so each B-load is a
// single coalesced 1KB wave transaction.
// ---------------------------------------------------------------------------
#define LDSS 136   // 16B-aligned padded row (ushorts)

template <int NTILES>
static __device__ __forceinline__ void dev_gemm_bf16out(
    const unsigned short* __restrict__ XB, const unsigned short* __restrict__ WB,
    const float* __restrict__ BP, unsigned short* __restrict__ Y, int n, int blk,
    unsigned short* sb) {
    constexpr int COLS = NTILES * 16;
    constexpr int HALF = NTILES / 2;
    constexpr int HCOLS = HALF * 16;
    int wave = threadIdx.x >> 6, lane = threadIdx.x & 63;
    int m = lane & 15, quad = lane >> 4;
    int rowbase = blk * 64 + wave * 16;
    int arow = rowbase + m; if (arow >= n) arow = n - 1;
    unsigned short* swave = sb + wave * 16 * LDSS;
    const unsigned short* xrow = XB + (size_t)arow * 128 + quad * 8;
    bf16x8 a0 = ldfrag(xrow), a1 = ldfrag(xrow + 32);
    bf16x8 a2 = ldfrag(xrow + 64), a3 = ldfrag(xrow + 96);
    f32x4 acc[NTILES];
#pragma unroll
    for (int t = 0; t < NTILES; t++) acc[t] = (f32x4){0.f, 0.f, 0.f, 0.f};
#pragma unroll
    for (int t = 0; t < NTILES; t++) {
        const unsigned short* wt = WB + (size_t)t * 2048 + lane * 8;
        acc[t] = __builtin_amdgcn_mfma_f32_16x16x32_bf16(a0, ldfrag(wt), acc[t], 0, 0, 0);
        acc[t] = __builtin_amdgcn_mfma_f32_16x16x32_bf16(a1, ldfrag(wt + 512), acc[t], 0, 0, 0);
        acc[t] = __builtin_amdgcn_mfma_f32_16x16x32_bf16(a2, ldfrag(wt + 1024), acc[t], 0, 0, 0);
        acc[t] = __builtin_amdgcn_mfma_f32_16x16x32_bf16(a3, ldfrag(wt + 1536), acc[t], 0, 0, 0);
    }
    int tswz_bit = (quad >> 1) & 1;   // == (row>>3) for row = quad*4+r
#pragma unroll
    for (int half = 0; half < 2; half++) {
#pragma unroll
        for (int t = 0; t < HALF; t++) {
            int tt = half * HALF + t;
            int tsw = t ^ tswz_bit;
            float b = BP[tt * 16 + m];
#pragma unroll
            for (int r = 0; r < 4; r++)
                swave[(quad * 4 + r) * LDSS + tsw * 16 + m] = f2b(acc[tt][r] + b);
        }
        // per-wave LDS; DS ops execute in order per wave -> no barrier
#pragma unroll
        for (int i = 0; i < 4; i++) {
            int idx = i * 64 + lane;
            int r = idx / (HCOLS / 8), g = idx % (HCOLS / 8);
            int gs = g ^ (((r >> 3) & 1) << 1);
            int grow = rowbase + r;
            if (grow < n) {
                uint4 v = *(const uint4*)&swave[r * LDSS + gs * 8];
                *(uint4*)(Y + (size_t)grow * COLS + half * HCOLS + g * 8) = v;
            }
        }
    }
}

template <int NTILES>
static __device__ __forceinline__ void dev_gemm_f32out(
    const unsigned short* __restrict__ XB, const unsigned short* __restrict__ WB,
    const float* __restrict__ BP, float* __restrict__ Y, int n, int blk) {
    constexpr int COLS = NTILES * 16;
    int wave = threadIdx.x >> 6, lane = threadIdx.x & 63;
    int m = lane & 15, quad = lane >> 4;
    int rowbase = blk * 64 + wave * 16;
    int arow = rowbase + m; if (arow >= n) arow = n - 1;
    const unsigned short* xrow = XB + (size_t)arow * 128 + quad * 8;
    bf16x8 a0 = ldfrag(xrow), a1 = ldfrag(xrow + 32);
    bf16x8 a2 = ldfrag(xrow + 64), a3 = ldfrag(xrow + 96);
    f32x4 acc[NTILES];
#pragma unroll
    for (int t = 0; t < NTILES; t++) acc[t] = (f32x4){0.f, 0.f, 0.f, 0.f};
#pragma unroll
    for (int t = 0; t < NTILES; t++) {
        const unsigned short* wt = WB + (size_t)t * 2048 + lane * 8;
        acc[t] = __builtin_amdgcn_mfma_f32_16x16x32_bf16(a0, ldfrag(wt), acc[t], 0, 0, 0);
        acc[t] = __builtin_amdgcn_mfma_f32_16x16x32_bf16(a1, ldfrag(wt + 512), acc[t], 0, 0, 0);
        acc[t] = __builtin_amdgcn_mfma_f32_16x16x32_bf16(a2, ldfrag(wt + 1024), acc[t], 0, 0, 0);
        acc[t] = __builtin_amdgcn_mfma_f32_16x16x32_bf16(a3, ldfrag(wt + 1536), acc[t], 0, 0, 0);
    }
#pragma unroll
    for (int t = 0; t < NTILES; t++) {
        float b = BP[t * 16 + m];
#pragma unroll
        for (int r = 0; r < 4; r++) {
            int grow = rowbase + quad * 4 + r;
            if (grow < n) Y[(size_t)grow * COLS + t * 16 + m] = acc[t][r] + b;
        }
    }
}

// ---------------------------------------------------------------------------
// prep: pack weights (fragment-linear), convert x->bf16, edge tables, zero cnt
// ---------------------------------------------------------------------------
__global__ __launch_bounds__(256) void prep(
    const float* __restrict__ x, unsigned short* __restrict__ XB,
    const float* __restrict__ Wk1, const float* __restrict__ Wv1,
    const float* __restrict__ Wq1, const float* __restrict__ Wskip1,
    const float* __restrict__ bk1, const float* __restrict__ bv1,
    const float* __restrict__ bq1, const float* __restrict__ bskip1,
    const float* __restrict__ Wk2, const float* __restrict__ Wv2,
    const float* __restrict__ Wq2, const float* __restrict__ Wskip2,
    const float* __restrict__ bk2, const float* __restrict__ bv2,
    const float* __restrict__ bq2, const float* __restrict__ bskip2,
    unsigned short* __restrict__ WB1, float* __restrict__ BP1,
    unsigned short* __restrict__ WB2, float* __restrict__ BP2,
    const float* __restrict__ edge_W, const float* __restrict__ edge_b,
    const float* __restrict__ time_W, const float* __restrict__ time_b,
    const float* __restrict__ We1, const float* __restrict__ We2,
    float* __restrict__ TA1, float* __restrict__ TB1,
    float* __restrict__ TA2, float* __restrict__ TB2,
    int* __restrict__ cnt1, int* __restrict__ cnt2, int* __restrict__ done) {
    int tid = blockIdx.x * blockDim.x + threadIdx.x;
    int stride = gridDim.x * blockDim.x;
    for (int i = tid; i < N0 * 32; i += stride) {
        float4 v = *(const float4*)(x + (size_t)i * 4);
        ushort4 u;
        u.x = f2b(v.x); u.y = f2b(v.y); u.z = f2b(v.z); u.w = f2b(v.w);
        *(ushort4*)(XB + (size_t)i * 4) = u;
    }
    // fragment-linear pack: WB[((t*4+ks)*64+l)*8+j] = W[t*16+(l&15)][ks*32+((l>>4)&3)*8+j]
    for (int i = tid; i < 512 * 128; i += stride) {
        int j = i & 7, l = (i >> 3) & 63, ks = (i >> 9) & 3, t = i >> 11;
        int row = t * 16 + (l & 15);
        int col = ks * 32 + ((l >> 4) & 3) * 8 + j;
        const float* w; int off;
        if (row < 128) { w = Wk1; off = 0; }
        else if (row < 256) { w = Wv1; off = 128; }
        else if (row < 384) { w = Wq1; off = 256; }
        else { w = Wskip1; off = 384; }
        WB1[i] = f2b(w[(size_t)(row - off) * 128 + col]);
    }
    for (int i = tid; i < 512; i += stride) {
        const float* b; int off;
        if (i < 128) { b = bk1; off = 0; }
        else if (i < 256) { b = bv1; off = 128; }
        else if (i < 384) { b = bq1; off = 256; }
        else { b = bskip1; off = 384; }
        BP1[i] = b[i - off];
    }
    for (int i = tid; i < 448 * 128; i += stride) {
        int j = i & 7, l = (i >> 3) & 63, ks = (i >> 9) & 3, t = i >> 11;
        int row = t * 16 + (l & 15);
        int col = ks * 32 + ((l >> 4) & 3) * 8 + j;
        const float* w; int off;
        if (row < 128) { w = Wk2; off = 0; }
        else if (row < 256) { w = Wv2; off = 128; }
        else if (row < 384) { w = Wq2; off = 256; }
        else { w = Wskip2; off = 384; }
        WB2[i] = f2b(w[(size_t)(row - off) * 128 + col]);
    }
    for (int i = tid; i < 448; i += stride) {
        const float* b; int off;
        if (i < 128) { b = bk2; off = 0; }
        else if (i < 256) { b = bv2; off = 128; }
        else if (i < 384) { b = bq2; off = 256; }
        else { b = bskip2; off = 384; }
        BP2[i] = b[i - off];
    }
    const int TBL = (NTYPE + NTS) * 128;
    for (int i = tid; i < TBL; i += stride) {
        if (i < NTYPE * 128) {
            int e = i >> 7, c = i & 127;
            float s1 = 0.f, s2 = 0.f;
#pragma unroll
            for (int j = 0; j < 10; j++) {
                float fj = edge_W[j * NTYPE + e] + edge_b[j];
                s1 += fj * We1[c * 20 + j];
                s2 += fj * We2[c * 20 + j];
            }
            TA1[i] = s1; TA2[i] = s2;
        } else {
            int u = i - NTYPE * 128;
            int ts = u >> 7, c = u & 127;
            float s1 = 0.f, s2 = 0.f;
#pragma unroll
            for (int j = 0; j < 10; j++) {
                float fj = time_W[j * NTS + ts] + time_b[j];
                s1 += fj * We1[c * 20 + 10 + j];
                s2 += fj * We2[c * 20 + 10 + j];
            }
            TB1[u] = s1; TB2[u] = s2;
        }
    }
    for (int i = tid; i < N1 + N2 + 1; i += stride) {
        if (i < N1) cnt1[i] = 0;
        else if (i < N1 + N2) cnt2[i - N1] = 0;
        else *done = 0;
    }
}

// ---------------------------------------------------------------------------
// mega_l1: KV1 GEMM | QR1 GEMM | degree count, block-partitioned
// ---------------------------------------------------------------------------
__global__ __launch_bounds__(256) void mega_l1(
    const unsigned short* __restrict__ XB,
    const unsigned short* __restrict__ WB1, const float* __restrict__ BP1,
    unsigned short* __restrict__ KV1, float* __restrict__ QR1,
    const int* __restrict__ d1, const int* __restrict__ d2,
    int* __restrict__ cnt1, int* __restrict__ cnt2) {
    __shared__ unsigned short sbuf[4 * 16 * LDSS];
    int b = blockIdx.x;
    if (b < KV1B) {
        dev_gemm_bf16out<16>(XB, WB1, BP1, KV1, N0, b, sbuf);
    } else if (b < KV1B + QR1B) {
        dev_gemm_f32out<16>(XB, WB1 + 256 * 128, BP1 + 256, QR1, N1, b - KV1B);
    } else {
        int t = (b - KV1B - QR1B) * 256 + threadIdx.x;
        if (t < E1C) atomicAdd(&cnt1[d1[t]], 1);
        else {
            t -= E1C;
            if (t < E2C) atomicAdd(&cnt2[d2[t]], 1);
        }
    }
}

__global__ __launch_bounds__(256) void gemm_l2(
    const unsigned short* __restrict__ H,
    const unsigned short* __restrict__ WB2, const float* __restrict__ BP2,
    unsigned short* __restrict__ KV2, float* __restrict__ QR2) {
    __shared__ unsigned short sbuf[4 * 16 * LDSS];
    int b = blockIdx.x;
    if (b < KV2B) dev_gemm_bf16out<16>(H, WB2, BP2, KV2, N1, b, sbuf);
    else dev_gemm_f32out<12>(H, WB2 + 256 * 128, BP2 + 256, QR2, N2, b - KV2B);
}

// ---------------------------------------------------------------------------
// bsum_scan / bscan_both / fill_both (unchanged)
// ---------------------------------------------------------------------------
__global__ __launch_bounds__(256) void bsum_scan(
    const int* __restrict__ cnt1, int* __restrict__ bs1,
    const int* __restrict__ cnt2, int* __restrict__ bs2, int* __restrict__ done) {
    __shared__ int s[256];
    __shared__ int amlast;
    int b = blockIdx.x;
    const int* cnt; int* bs; int n, lb;
    if (b < NB1) { cnt = cnt1; bs = bs1; n = N1; lb = b; }
    else { cnt = cnt2; bs = bs2; n = N2; lb = b - NB1; }
    int t = lb * 256 + threadIdx.x;
    s[threadIdx.x] = (t < n) ? cnt[t] : 0;
    __syncthreads();
    for (int off = 128; off; off >>= 1) {
        if (threadIdx.x < off) s[threadIdx.x] += s[threadIdx.x + off];
        __syncthreads();
    }
    if (threadIdx.x == 0) {
        atomicExch(&bs[lb], s[0]);
        __threadfence();
        int prev = atomicAdd(done, 1);
        amlast = (prev == NB1 + NB2 - 1) ? 1 : 0;
    }
    __syncthreads();
    if (!amlast) return;
    int tt = threadIdx.x;
    int v1 = (tt < NB1) ? atomicAdd(&bs1[tt], 0) : 0;
    s[tt] = v1;
    __syncthreads();
    for (int off = 1; off < 256; off <<= 1) {
        int u = (tt >= off) ? s[tt - off] : 0;
        __syncthreads();
        s[tt] += u;
        __syncthreads();
    }
    if (tt < NB1) bs1[tt] = s[tt] - v1;
    __syncthreads();
    int v2 = (tt < NB2) ? atomicAdd(&bs2[tt], 0) : 0;
    s[tt] = v2;
    __syncthreads();
    for (int off = 1; off < 256; off <<= 1) {
        int u = (tt >= off) ? s[tt - off] : 0;
        __syncthreads();
        s[tt] += u;
        __syncthreads();
    }
    if (tt < NB2) bs2[tt] = s[tt] - v2;
}

__global__ __launch_bounds__(256) void bscan_both(
    int* __restrict__ cnt1, const int* __restrict__ bs1, int* __restrict__ rp1,
    int* __restrict__ cnt2, const int* __restrict__ bs2, int* __restrict__ rp2) {
    __shared__ int s[256];
    int b = blockIdx.x;
    int* cnt; const int* bs; int* rp; int n, lb;
    if (b < NB1) { cnt = cnt1; bs = bs1; rp = rp1; n = N1; lb = b; }
    else { cnt = cnt2; bs = bs2; rp = rp2; n = N2; lb = b - NB1; }
    int t = lb * 256 + threadIdx.x;
    int v = (t < n) ? cnt[t] : 0;
    if (t < n) cnt[t] = 0;
    s[threadIdx.x] = v;
    __syncthreads();
    for (int off = 1; off < 256; off <<= 1) {
        int u = (threadIdx.x >= off) ? s[threadIdx.x - off] : 0;
        __syncthreads();
        s[threadIdx.x] += u;
        __syncthreads();
    }
    int incl = s[threadIdx.x];
    int base = bs[lb];
    if (t < n) rp[t] = base + incl - v;
    if (t == n - 1) rp[n] = base + incl;
}

__global__ __launch_bounds__(256) void fill_both(
    const int* __restrict__ d1, const int* __restrict__ rp1,
    int* __restrict__ cur1, int* __restrict__ eix1,
    const int* __restrict__ d2, const int* __restrict__ rp2,
    int* __restrict__ cur2, int* __restrict__ eix2) {
    int t = blockIdx.x * 256 + threadIdx.x;
    if (t < E1C) {
        int d = d1[t];
        eix1[rp1[d] + atomicAdd(&cur1[d], 1)] = t;
    } else {
        t -= E1C;
        if (t < E2C) {
            int d = d2[t];
            eix2[rp2[d] + atomicAdd(&cur2[d], 1)] = t;
        }
    }
}

// ---------------------------------------------------------------------------
// Fused aggregation: 2-deep index prefetch + 1-deep vector prefetch + DPP
// reductions. Wave layout: s=lane>>5 (edge parity), h=(lane>>4)&1, cg=lane&15.
// ---------------------------------------------------------------------------
__global__ __launch_bounds__(256) void agg_layer1(
    const int* __restrict__ rowptr, const int* __restrict__ eidx,
    const int* __restrict__ src, const int* __restrict__ et, const int* __restrict__ ets,
    const float* __restrict__ TA, const float* __restrict__ TB,
    const float* __restrict__ QR, const unsigned short* __restrict__ KV,
    const float* __restrict__ Wbeta,
    const float* __restrict__ ln_g, const float* __restrict__ ln_b,
    unsigned short* __restrict__ hout, int n) {
    int wid = (blockIdx.x * blockDim.x + threadIdx.x) >> 6;
    int lane = threadIdx.x & 63;
    if (wid >= n) return;
    int s = lane >> 5, cg = lane & 15;
    int co = ((lane >> 4) & 1) * 64 + 4 * cg;
    int beg = rowptr[wid], end = rowptr[wid + 1];
    float4 q4 = *(const float4*)(QR + (size_t)wid * 256 + co);
    float ax = 0.f, ay = 0.f, az = 0.f, aw = 0.f, suma = 0.f;
    int p = beg + s;
    if (p < end) {
        // stage 0: indices for p, p+2; vectors for p
        int e0 = eidx[p];
        int sn0 = src[e0], t0 = et[e0], ts0 = ets[e0];
        int p1 = p + 2;
        bool m1 = p1 < end;
        int e1 = eidx[m1 ? p1 : beg];
        int sn1 = src[e1], t1 = et[e1], ts1 = ets[e1];
        float4 ta0 = *(const float4*)(TA + t0 * 128 + co);
        float4 tb0 = *(const float4*)(TB + ts0 * 128 + co);
        const unsigned short* kv0 = KV + (size_t)sn0 * 256;
        ushort4 ku0 = *(const ushort4*)(kv0 + co);
        ushort4 vu0 = *(const ushort4*)(kv0 + 128 + co);
        for (;;) {
            // prefetch indices for p+4
            int p2 = p1 + 2;
            bool m2 = p2 < end;
            int e2 = eidx[m2 ? p2 : beg];
            int sn2 = src[e2], t2 = et[e2], ts2 = ets[e2];
            // prefetch vectors for p+2
            float4 ta1 = *(const float4*)(TA + t1 * 128 + co);
            float4 tb1 = *(const float4*)(TB + ts1 * 128 + co);
            const unsigned short* kv1 = KV + (size_t)sn1 * 256;
            ushort4 ku1 = *(const ushort4*)(kv1 + co);
            ushort4 vu1 = *(const ushort4*)(kv1 + 128 + co);
            // compute current edge
            float e0c = ta0.x + tb0.x, e1c = ta0.y + tb0.y;
            float e2c = ta0.z + tb0.z, e3c = ta0.w + tb0.w;
            float pp = q4.x * (b2f(ku0.x) + e0c) + q4.y * (b2f(ku0.y) + e1c)
                     + q4.z * (b2f(ku0.z) + e2c) + q4.w * (b2f(ku0.w) + e3c);
            pp = red16(pp);
            float a = __expf(pp * 0.125f);
            ax += a * (b2f(vu0.x) + e0c); ay += a * (b2f(vu0.y) + e1c);
            az += a * (b2f(vu0.z) + e2c); aw += a * (b2f(vu0.w) + e3c);
            suma += a;
            if (!m1) break;
            p1 = p2; m1 = m2;
            sn1 = sn2; t1 = t2; ts1 = ts2;
            ta0 = ta1; tb0 = tb1; ku0 = ku1; vu0 = vu1;
        }
    }
    // merge edge-parity subwaves
    ax += __shfl_xor(ax, 32); ay += __shfl_xor(ay, 32);
    az += __shfl_xor(az, 32); aw += __shfl_xor(aw, 32);
    suma += __shfl_xor(suma, 32);
    float inv_s = 1.f / (suma + 1e-16f);
    float ox = ax * inv_s, oy = ay * inv_s, oz = az * inv_s, ow = aw * inv_s;
    float4 r4 = *(const float4*)(QR + (size_t)wid * 256 + 128 + co);
    float4 wo = *(const float4*)(Wbeta + co);
    float4 wr = *(const float4*)(Wbeta + 128 + co);
    float4 wd = *(const float4*)(Wbeta + 256 + co);
    float pb = wo.x * ox + wr.x * r4.x + wd.x * (ox - r4.x)
             + wo.y * oy + wr.y * r4.y + wd.y * (oy - r4.y)
             + wo.z * oz + wr.z * r4.z + wd.z * (oz - r4.z)
             + wo.w * ow + wr.w * r4.w + wd.w * (ow - r4.w);
    pb = red16(pb);
    pb += __shfl_xor(pb, 16);
    float beta = 1.f / (1.f + __expf(-pb));
    float gx = beta * r4.x + (1.f - beta) * ox;
    float gy = beta * r4.y + (1.f - beta) * oy;
    float gz = beta * r4.z + (1.f - beta) * oz;
    float gw = beta * r4.w + (1.f - beta) * ow;
    float sm = gx + gy + gz + gw;
    float sq = gx * gx + gy * gy + gz * gz + gw * gw;
    sm = red16(sm); sm += __shfl_xor(sm, 16);
    sq = red16(sq); sq += __shfl_xor(sq, 16);
    float mu = sm * (1.f / 128.f);
    float var = sq * (1.f / 128.f) - mu * mu;
    float inv = rsqrtf(var + 1e-5f);
    float4 lg = *(const float4*)(ln_g + co);
    float4 lb = *(const float4*)(ln_b + co);
    float yx = (gx - mu) * inv * lg.x + lb.x;
    float yy = (gy - mu) * inv * lg.y + lb.y;
    float yz = (gz - mu) * inv * lg.z + lb.z;
    float yw = (gw - mu) * inv * lg.w + lb.w;
    const float ISQ2 = 0.70710678118654752f;
    yx = 0.5f * yx * (1.f + erff(yx * ISQ2));
    yy = 0.5f * yy * (1.f + erff(yy * ISQ2));
    yz = 0.5f * yz * (1.f + erff(yz * ISQ2));
    yw = 0.5f * yw * (1.f + erff(yw * ISQ2));
    if (s == 0) {
        ushort4 hv;
        hv.x = f2b(yx); hv.y = f2b(yy); hv.z = f2b(yz); hv.w = f2b(yw);
        *(ushort4*)(hout + (size_t)wid * 128 + co) = hv;
    }
}

__global__ __launch_bounds__(256) void agg_layer2(
    const int* __restrict__ rowptr, const int* __restrict__ eidx,
    const int* __restrict__ src, const int* __restrict__ et, const int* __restrict__ ets,
    const float* __restrict__ TA, const float* __restrict__ TB,
    const float* __restrict__ QR, const unsigned short* __restrict__ KV,
    const float* __restrict__ Wbeta,
    float* __restrict__ o, int n) {
    int wid = (blockIdx.x * blockDim.x + threadIdx.x) >> 6;
    int lane = threadIdx.x & 63;
    if (wid >= n) return;
    int s = lane >> 5, cg = lane & 15;
    int co = ((lane >> 4) & 1) * 64 + 4 * cg;
    int beg = rowptr[wid], end = rowptr[wid + 1];
    float4 q4 = *(const float4*)(QR + (size_t)wid * 192 + co);
    float ax = 0.f, ay = 0.f, az = 0.f, aw = 0.f, suma = 0.f;
    int p = beg + s;
    if (p < end) {
        int e0 = eidx[p];
        int sn0 = src[e0], t0 = et[e0], ts0 = ets[e0];
        int p1 = p + 2;
        bool m1 = p1 < end;
        int e1 = eidx[m1 ? p1 : beg];
        int sn1 = src[e1], t1 = et[e1], ts1 = ets[e1];
        float4 ta0 = *(const float4*)(TA + t0 * 128 + co);
        float4 tb0 = *(const float4*)(TB + ts0 * 128 + co);
        const unsigned short* kv0 = KV + (size_t)sn0 * 256;
        ushort4 ku0 = *(const ushort4*)(kv0 + co);
        ushort4 vu0 = *(const ushort4*)(kv0 + 128 + co);
        for (;;) {
            int p2 = p1 + 2;
            bool m2 = p2 < end;
            int e2 = eidx[m2 ? p2 : beg];
            int sn2 = src[e2], t2 = et[e2], ts2 = ets[e2];
            float4 ta1 = *(const float4*)(TA + t1 * 128 + co);
            float4 tb1 = *(const float4*)(TB + ts1 * 128 + co);
            const unsigned short* kv1 = KV + (size_t)sn1 * 256;
            ushort4 ku1 = *(const ushort4*)(kv1 + co);
            ushort4 vu1 = *(const ushort4*)(kv1 + 128 + co);
            float e0c = ta0.x + tb0.x, e1c = ta0.y + tb0.y;
            float e2c = ta0.z + tb0.z, e3c = ta0.w + tb0.w;
            float pp = q4.x * (b2f(ku0.x) + e0c) + q4.y * (b2f(ku0.y) + e1c)
                     + q4.z * (b2f(ku0.z) + e2c) + q4.w * (b2f(ku0.w) + e3c);
            pp = red16(pp);
            float a = __expf(pp * 0.125f);
            ax += a * (b2f(vu0.x) + e0c); ay += a * (b2f(vu0.y) + e1c);
            az += a * (b2f(vu0.z) + e2c); aw += a * (b2f(vu0.w) + e3c);
            suma += a;
            if (!m1) break;
            p1 = p2; m1 = m2;
            sn1 = sn2; t1 = t2; ts1 = ts2;
            ta0 = ta1; tb0 = tb1; ku0 = ku1; vu0 = vu1;
        }
    }
    ax += __shfl_xor(ax, 32); ay += __shfl_xor(ay, 32);
    az += __shfl_xor(az, 32); aw += __shfl_xor(aw, 32);
    suma += __shfl_xor(suma, 32);
    float inv_s = 1.f / (suma + 1e-16f);
    float ox = ax * inv_s, oy = ay * inv_s, oz = az * inv_s, ow = aw * inv_s;
    // head mean: partner lane differs in h bit (xor 16)
    ox = 0.5f * (ox + __shfl_xor(ox, 16));
    oy = 0.5f * (oy + __shfl_xor(oy, 16));
    oz = 0.5f * (oz + __shfl_xor(oz, 16));
    ow = 0.5f * (ow + __shfl_xor(ow, 16));
    float4 r4 = *(const float4*)(QR + (size_t)wid * 192 + 128 + 4 * cg);
    float4 wo = *(const float4*)(Wbeta + 4 * cg);
    float4 wr = *(const float4*)(Wbeta + 64 + 4 * cg);
    float4 wd = *(const float4*)(Wbeta + 128 + 4 * cg);
    float pb = wo.x * ox + wr.x * r4.x + wd.x * (ox - r4.x)
             + wo.y * oy + wr.y * r4.y + wd.y * (oy - r4.y)
             + wo.z * oz + wr.z * r4.z + wd.z * (oz - r4.z)
             + wo.w * ow + wr.w * r4.w + wd.w * (ow - r4.w);
    pb = red16(pb);
    float beta = 1.f / (1.f + __expf(-pb));
    float vx = beta * r4.x + (1.f - beta) * ox;
    float vy = beta * r4.y + (1.f - beta) * oy;
    float vz = beta * r4.z + (1.f - beta) * oz;
    float vw = beta * r4.w + (1.f - beta) * ow;
    float m = fmaxf(fmaxf(vx, vy), fmaxf(vz, vw));
    m = red16max(m);
    float se = __expf(vx - m) + __expf(vy - m) + __expf(vz - m) + __expf(vw - m);
    se = red16(se);
    float lse = m + logf(se);
    if (lane < 16)
        *(float4*)(o + (size_t)wid * 64 + 4 * cg) =
            make_float4(vx - lse, vy - lse, vz - lse, vw - lse);
}

extern "C" void kernel_launch(void* const* d_in, const int* in_sizes, int n_in,
                              void* d_out, int out_size, void* d_ws, size_t ws_size,
                              hipStream_t stream) {
    const float* x        = (const float*)d_in[0];
    const int*   ei1_src  = (const int*)d_in[1];
    const int*   ei1_dst  = (const int*)d_in[2];
    const int*   et1      = (const int*)d_in[3];
    const int*   ets1     = (const int*)d_in[4];
    const int*   ei2_src  = (const int*)d_in[5];
    const int*   ei2_dst  = (const int*)d_in[6];
    const int*   et2      = (const int*)d_in[7];
    const int*   ets2     = (const int*)d_in[8];
    const float* edge_W   = (const float*)d_in[9];
    const float* edge_b   = (const float*)d_in[10];
    const float* time_W   = (const float*)d_in[11];
    const float* time_b   = (const float*)d_in[12];
    const float* Wq1      = (const float*)d_in[13];
    const float* bq1      = (const float*)d_in[14];
    const float* Wk1      = (const float*)d_in[15];
    const float* bk1      = (const float*)d_in[16];
    const float* Wv1      = (const float*)d_in[17];
    const float* bv1      = (const float*)d_in[18];
    const float* We1      = (const float*)d_in[19];
    const float* Wskip1   = (const float*)d_in[20];
    const float* bskip1   = (const float*)d_in[21];
    const float* Wbeta1   = (const float*)d_in[22];
    const float* ln_g     = (const float*)d_in[23];
    const float* ln_b     = (const float*)d_in[24];
    const float* Wq2      = (const float*)d_in[25];
    const float* bq2      = (const float*)d_in[26];
    const float* Wk2      = (const float*)d_in[27];
    const float* bk2      = (const float*)d_in[28];
    const float* Wv2      = (const float*)d_in[29];
    const float* bv2      = (const float*)d_in[30];
    const float* We2      = (const float*)d_in[31];
    const float* Wskip2   = (const float*)d_in[32];
    const float* bskip2   = (const float*)d_in[33];
    const float* Wbeta2   = (const float*)d_in[34];

    float* ws = (float*)d_ws;
    unsigned short* xb  = (unsigned short*)(ws + OFF_XB);
    float* qr1          = ws + OFF_QR1;
    unsigned short* kv1 = (unsigned short*)(ws + OFF_KV1);
    unsigned short* h   = (unsigned short*)(ws + OFF_H);
    float* qr2          = ws + OFF_QR2;
    unsigned short* kv2 = (unsigned short*)(ws + OFF_KV2);
    unsigned short* wb1 = (unsigned short*)(ws + OFF_WB1);
    float* bp1          = ws + OFF_BP1;
    unsigned short* wb2 = (unsigned short*)(ws + OFF_WB2);
    float* bp2          = ws + OFF_BP2;
    float* ta1          = ws + OFF_TA1;
    float* tb1          = ws + OFF_TB1;
    float* ta2          = ws + OFF_TA2;
    float* tb2          = ws + OFF_TB2;
    int*   rp1          = (int*)(ws + OFF_RP1);
    int*   cur1         = (int*)(ws + OFF_CUR1);
    int*   eix1         = (int*)(ws + OFF_EIX1);
    int*   bs1          = (int*)(ws + OFF_BS1);
    int*   rp2          = (int*)(ws + OFF_RP2);
    int*   cur2         = (int*)(ws + OFF_CUR2);
    int*   eix2         = (int*)(ws + OFF_EIX2);
    int*   bs2          = (int*)(ws + OFF_BS2);
    int*   done         = (int*)(ws + OFF_DONE);

    prep<<<2048, 256, 0, stream>>>(
        x, xb,
        Wk1, Wv1, Wq1, Wskip1, bk1, bv1, bq1, bskip1,
        Wk2, Wv2, Wq2, Wskip2, bk2, bv2, bq2, bskip2,
        wb1, bp1, wb2, bp2,
        edge_W, edge_b, time_W, time_b, We1, We2,
        ta1, tb1, ta2, tb2, cur1, cur2, done);
    mega_l1<<<KV1B + QR1B + CNTB, 256, 0, stream>>>(
        xb, wb1, bp1, kv1, qr1, ei1_dst, ei2_dst, cur1, cur2);
    bsum_scan<<<NB1 + NB2, 256, 0, stream>>>(cur1, bs1, cur2, bs2, done);
    bscan_both<<<NB1 + NB2, 256, 0, stream>>>(cur1, bs1, rp1, cur2, bs2, rp2);
    fill_both<<<FILLB, 256, 0, stream>>>(ei1_dst, rp1, cur1, eix1,
                                         ei2_dst, rp2, cur2, eix2);
    agg_layer1<<<(N1 + 3) / 4, 256, 0, stream>>>(rp1, eix1, ei1_src, et1, ets1,
        ta1, tb1, qr1, kv1, Wbeta1, ln_g, ln_b, h, N1);
    gemm_l2<<<KV2B + QR2B, 256, 0, stream>>>(h, wb2, bp2, kv2, qr2);
    agg_layer2<<<(N2 + 3) / 4, 256, 0, stream>>>(rp2, eix2, ei2_src, et2, ets2,
        ta2, tb2, qr2, kv2, Wbeta2, (float*)d_out, N2);
}

// Round 11
// 392.371 us; speedup vs baseline: 10.6554x; 1.0229x over previous
//
#include <hip/hip_runtime.h>
#include <math.h>

// Problem constants
#define N0 80000
#define N1 40000
#define N2 20000
#define E1C 500000
#define E2C 250000
#define NTYPE 23
#define NTS 1158

// derived grid constants
#define NB1 157           // ceil(N1/256)
#define NB2 79            // ceil(N2/256)
#define KV1B 1250         // ceil(N0/64)
#define QR1B 625          // ceil(N1/64)
#define CNTB 2930         // ceil((E1C+E2C)/256)
#define KV2B 625          // ceil(N1/64)
#define QR2B 313          // ceil(N2/64)
#define FILLB 2930        // ceil((E1C+E2C)/256)

// ---------------- Workspace layout (float offsets) ----------------
#define OFF_XB    0u           // N0*128 bf16
#define OFF_QR1   5120000u     // N1*256 f32 (q|xr)
#define OFF_KV1   15360000u    // N0*256 bf16
#define OFF_H     25600000u    // N1*128 bf16
#define OFF_QR2   28160000u    // N2*192 f32
#define OFF_KV2   32000000u    // N1*256 bf16
#define OFF_WB1   37120000u    // 512*128 bf16 (fragment-linear)
#define OFF_BP1   37160000u    // 512 f32
#define OFF_WB2   37170000u    // 448*128 bf16 (fragment-linear)
#define OFF_BP2   37200000u    // 448 f32
#define OFF_TA1   37210000u
#define OFF_TB1   37213000u
#define OFF_TA2   37370000u
#define OFF_TB2   37373000u
#define OFF_RP1   37530000u    // N1+1 ints
#define OFF_CUR1  37580000u    // N1 ints
#define OFF_ED1   37630000u    // E1 uint2 (packed src|et|ets), 1,000,000 slots
#define OFF_BS1   38640000u    // 256 ints
#define OFF_RP2   38650000u    // N2+1 ints
#define OFF_CUR2  38680000u    // N2 ints
#define OFF_ED2   38710000u    // E2 uint2, 500,000 slots
#define OFF_BS2   39220000u    // 256 ints
#define OFF_DONE  39230000u    // 2 ints (ticket, scan-done flag)
// total ≈ 39.23M floats ≈ 157 MB

typedef __bf16 bf16x8 __attribute__((ext_vector_type(8)));
typedef float f32x4 __attribute__((ext_vector_type(4)));

static __device__ __forceinline__ float b2f(unsigned short u) {
    union { unsigned int i; float f; } c;
    c.i = ((unsigned int)u) << 16;
    return c.f;
}
static __device__ __forceinline__ unsigned short f2b(float f) {
    unsigned int u = __float_as_uint(f);
    unsigned int r = (u + 0x7fffu + ((u >> 16) & 1u)) >> 16;
    return (unsigned short)r;
}
static __device__ __forceinline__ bf16x8 ldfrag(const unsigned short* p) {
    return *reinterpret_cast<const bf16x8*>(p);
}

// DPP 16-lane reductions (row = 16 lanes). VALU-pipe only, no DS round trip.
template <int CTRL>
static __device__ __forceinline__ float dpp_addstep(float v) {
    int x = __builtin_amdgcn_mov_dpp(__float_as_int(v), CTRL, 0xF, 0xF, true);
    return v + __int_as_float(x);
}
static __device__ __forceinline__ float red16(float v) {
    v = dpp_addstep<0xB1>(v);    // quad_perm xor1
    v = dpp_addstep<0x4E>(v);    // quad_perm xor2
    v = dpp_addstep<0x141>(v);   // row_half_mirror
    v = dpp_addstep<0x140>(v);   // row_mirror
    return v;
}
template <int CTRL>
static __device__ __forceinline__ float dpp_maxstep(float v) {
    int x = __builtin_amdgcn_mov_dpp(__float_as_int(v), CTRL, 0xF, 0xF, true);
    return fmaxf(v, __int_as_float(x));
}
static __device__ __forceinline__ float red16max(float v) {
    v = dpp_maxstep<0xB1>(v);
    v = dpp_maxstep<0x4E>(v);
    v = dpp_maxstep<0x141>(v);
    v = dpp_maxstep<0x140>(v);
    return v;
}

// ---------------------------------------------------------------------------
// Device GEMM bodies (MFMA 16x16x32 bf16), fragment-linear B.
// ---------------------------------------------------------------------------
#define LDSS 136

template <int NTILES>
static __device__ __forceinline__ void dev_gemm_bf16out(
    const unsigned short* __restrict__ XB, const unsigned short* __restrict__ WB,
    const float* __restrict__ BP, unsigned short* __restrict__ Y, int n, int blk,
    unsigned short* sb) {
    constexpr int COLS = NTILES * 16;
    constexpr int HALF = NTILES / 2;
    constexpr int HCOLS = HALF * 16;
    int wave = threadIdx.x >> 6, lane = threadIdx.x & 63;
    int m = lane & 15, quad = lane >> 4;
    int rowbase = blk * 64 + wave * 16;
    int arow = rowbase + m; if (arow >= n) arow = n - 1;
    unsigned short* swave = sb + wave * 16 * LDSS;
    const unsigned short* xrow = XB + (size_t)arow * 128 + quad * 8;
    bf16x8 a0 = ldfrag(xrow), a1 = ldfrag(xrow + 32);
    bf16x8 a2 = ldfrag(xrow + 64), a3 = ldfrag(xrow + 96);
    f32x4 acc[NTILES];
#pragma unroll
    for (int t = 0; t < NTILES; t++) acc[t] = (f32x4){0.f, 0.f, 0.f, 0.f};
#pragma unroll
    for (int t = 0; t < NTILES; t++) {
        const unsigned short* wt = WB + (size_t)t * 2048 + lane * 8;
        acc[t] = __builtin_amdgcn_mfma_f32_16x16x32_bf16(a0, ldfrag(wt), acc[t], 0, 0, 0);
        acc[t] = __builtin_amdgcn_mfma_f32_16x16x32_bf16(a1, ldfrag(wt + 512), acc[t], 0, 0, 0);
        acc[t] = __builtin_amdgcn_mfma_f32_16x16x32_bf16(a2, ldfrag(wt + 1024), acc[t], 0, 0, 0);
        acc[t] = __builtin_amdgcn_mfma_f32_16x16x32_bf16(a3, ldfrag(wt + 1536), acc[t], 0, 0, 0);
    }
    int tswz_bit = (quad >> 1) & 1;
#pragma unroll
    for (int half = 0; half < 2; half++) {
#pragma unroll
        for (int t = 0; t < HALF; t++) {
            int tt = half * HALF + t;
            int tsw = t ^ tswz_bit;
            float b = BP[tt * 16 + m];
#pragma unroll
            for (int r = 0; r < 4; r++)
                swave[(quad * 4 + r) * LDSS + tsw * 16 + m] = f2b(acc[tt][r] + b);
        }
#pragma unroll
        for (int i = 0; i < 4; i++) {
            int idx = i * 64 + lane;
            int r = idx / (HCOLS / 8), g = idx % (HCOLS / 8);
            int gs = g ^ (((r >> 3) & 1) << 1);
            int grow = rowbase + r;
            if (grow < n) {
                uint4 v = *(const uint4*)&swave[r * LDSS + gs * 8];
                *(uint4*)(Y + (size_t)grow * COLS + half * HCOLS + g * 8) = v;
            }
        }
    }
}

template <int NTILES>
static __device__ __forceinline__ void dev_gemm_f32out(
    const unsigned short* __restrict__ XB, const unsigned short* __restrict__ WB,
    const float* __restrict__ BP, float* __restrict__ Y, int n, int blk) {
    constexpr int COLS = NTILES * 16;
    int wave = threadIdx.x >> 6, lane = threadIdx.x & 63;
    int m = lane & 15, quad = lane >> 4;
    int rowbase = blk * 64 + wave * 16;
    int arow = rowbase + m; if (arow >= n) arow = n - 1;
    const unsigned short* xrow = XB + (size_t)arow * 128 + quad * 8;
    bf16x8 a0 = ldfrag(xrow), a1 = ldfrag(xrow + 32);
    bf16x8 a2 = ldfrag(xrow + 64), a3 = ldfrag(xrow + 96);
    f32x4 acc[NTILES];
#pragma unroll
    for (int t = 0; t < NTILES; t++) acc[t] = (f32x4){0.f, 0.f, 0.f, 0.f};
#pragma unroll
    for (int t = 0; t < NTILES; t++) {
        const unsigned short* wt = WB + (size_t)t * 2048 + lane * 8;
        acc[t] = __builtin_amdgcn_mfma_f32_16x16x32_bf16(a0, ldfrag(wt), acc[t], 0, 0, 0);
        acc[t] = __builtin_amdgcn_mfma_f32_16x16x32_bf16(a1, ldfrag(wt + 512), acc[t], 0, 0, 0);
        acc[t] = __builtin_amdgcn_mfma_f32_16x16x32_bf16(a2, ldfrag(wt + 1024), acc[t], 0, 0, 0);
        acc[t] = __builtin_amdgcn_mfma_f32_16x16x32_bf16(a3, ldfrag(wt + 1536), acc[t], 0, 0, 0);
    }
#pragma unroll
    for (int t = 0; t < NTILES; t++) {
        float b = BP[t * 16 + m];
#pragma unroll
        for (int r = 0; r < 4; r++) {
            int grow = rowbase + quad * 4 + r;
            if (grow < n) Y[(size_t)grow * COLS + t * 16 + m] = acc[t][r] + b;
        }
    }
}

// ---------------------------------------------------------------------------
// prep: pack weights (fragment-linear), convert x->bf16, edge tables, zero cnt
// ---------------------------------------------------------------------------
__global__ __launch_bounds__(256) void prep(
    const float* __restrict__ x, unsigned short* __restrict__ XB,
    const float* __restrict__ Wk1, const float* __restrict__ Wv1,
    const float* __restrict__ Wq1, const float* __restrict__ Wskip1,
    const float* __restrict__ bk1, const float* __restrict__ bv1,
    const float* __restrict__ bq1, const float* __restrict__ bskip1,
    const float* __restrict__ Wk2, const float* __restrict__ Wv2,
    const float* __restrict__ Wq2, const float* __restrict__ Wskip2,
    const float* __restrict__ bk2, const float* __restrict__ bv2,
    const float* __restrict__ bq2, const float* __restrict__ bskip2,
    unsigned short* __restrict__ WB1, float* __restrict__ BP1,
    unsigned short* __restrict__ WB2, float* __restrict__ BP2,
    const float* __restrict__ edge_W, const float* __restrict__ edge_b,
    const float* __restrict__ time_W, const float* __restrict__ time_b,
    const float* __restrict__ We1, const float* __restrict__ We2,
    float* __restrict__ TA1, float* __restrict__ TB1,
    float* __restrict__ TA2, float* __restrict__ TB2,
    int* __restrict__ cnt1, int* __restrict__ cnt2, int* __restrict__ done) {
    int tid = blockIdx.x * blockDim.x + threadIdx.x;
    int stride = gridDim.x * blockDim.x;
    for (int i = tid; i < N0 * 32; i += stride) {
        float4 v = *(const float4*)(x + (size_t)i * 4);
        ushort4 u;
        u.x = f2b(v.x); u.y = f2b(v.y); u.z = f2b(v.z); u.w = f2b(v.w);
        *(ushort4*)(XB + (size_t)i * 4) = u;
    }
    // fragment-linear pack: WB[((t*4+ks)*64+l)*8+j] = W[t*16+(l&15)][ks*32+((l>>4)&3)*8+j]
    for (int i = tid; i < 512 * 128; i += stride) {
        int j = i & 7, l = (i >> 3) & 63, ks = (i >> 9) & 3, t = i >> 11;
        int row = t * 16 + (l & 15);
        int col = ks * 32 + ((l >> 4) & 3) * 8 + j;
        const float* w; int off;
        if (row < 128) { w = Wk1; off = 0; }
        else if (row < 256) { w = Wv1; off = 128; }
        else if (row < 384) { w = Wq1; off = 256; }
        else { w = Wskip1; off = 384; }
        WB1[i] = f2b(w[(size_t)(row - off) * 128 + col]);
    }
    for (int i = tid; i < 512; i += stride) {
        const float* b; int off;
        if (i < 128) { b = bk1; off = 0; }
        else if (i < 256) { b = bv1; off = 128; }
        else if (i < 384) { b = bq1; off = 256; }
        else { b = bskip1; off = 384; }
        BP1[i] = b[i - off];
    }
    for (int i = tid; i < 448 * 128; i += stride) {
        int j = i & 7, l = (i >> 3) & 63, ks = (i >> 9) & 3, t = i >> 11;
        int row = t * 16 + (l & 15);
        int col = ks * 32 + ((l >> 4) & 3) * 8 + j;
        const float* w; int off;
        if (row < 128) { w = Wk2; off = 0; }
        else if (row < 256) { w = Wv2; off = 128; }
        else if (row < 384) { w = Wq2; off = 256; }
        else { w = Wskip2; off = 384; }
        WB2[i] = f2b(w[(size_t)(row - off) * 128 + col]);
    }
    for (int i = tid; i < 448; i += stride) {
        const float* b; int off;
        if (i < 128) { b = bk2; off = 0; }
        else if (i < 256) { b = bv2; off = 128; }
        else if (i < 384) { b = bq2; off = 256; }
        else { b = bskip2; off = 384; }
        BP2[i] = b[i - off];
    }
    const int TBL = (NTYPE + NTS) * 128;
    for (int i = tid; i < TBL; i += stride) {
        if (i < NTYPE * 128) {
            int e = i >> 7, c = i & 127;
            float s1 = 0.f, s2 = 0.f;
#pragma unroll
            for (int j = 0; j < 10; j++) {
                float fj = edge_W[j * NTYPE + e] + edge_b[j];
                s1 += fj * We1[c * 20 + j];
                s2 += fj * We2[c * 20 + j];
            }
            TA1[i] = s1; TA2[i] = s2;
        } else {
            int u = i - NTYPE * 128;
            int ts = u >> 7, c = u & 127;
            float s1 = 0.f, s2 = 0.f;
#pragma unroll
            for (int j = 0; j < 10; j++) {
                float fj = time_W[j * NTS + ts] + time_b[j];
                s1 += fj * We1[c * 20 + 10 + j];
                s2 += fj * We2[c * 20 + 10 + j];
            }
            TB1[u] = s1; TB2[u] = s2;
        }
    }
    for (int i = tid; i < N1 + N2 + 2; i += stride) {
        if (i < N1) cnt1[i] = 0;
        else if (i < N1 + N2) cnt2[i - N1] = 0;
        else done[i - N1 - N2] = 0;
    }
}

// ---------------------------------------------------------------------------
// mega_l1: KV1 GEMM | QR1 GEMM | degree count, block-partitioned
// ---------------------------------------------------------------------------
__global__ __launch_bounds__(256) void mega_l1(
    const unsigned short* __restrict__ XB,
    const unsigned short* __restrict__ WB1, const float* __restrict__ BP1,
    unsigned short* __restrict__ KV1, float* __restrict__ QR1,
    const int* __restrict__ d1, const int* __restrict__ d2,
    int* __restrict__ cnt1, int* __restrict__ cnt2) {
    __shared__ unsigned short sbuf[4 * 16 * LDSS];
    int b = blockIdx.x;
    if (b < KV1B) {
        dev_gemm_bf16out<16>(XB, WB1, BP1, KV1, N0, b, sbuf);
    } else if (b < KV1B + QR1B) {
        dev_gemm_f32out<16>(XB, WB1 + 256 * 128, BP1 + 256, QR1, N1, b - KV1B);
    } else {
        int t = (b - KV1B - QR1B) * 256 + threadIdx.x;
        if (t < E1C) atomicAdd(&cnt1[d1[t]], 1);
        else {
            t -= E1C;
            if (t < E2C) atomicAdd(&cnt2[d2[t]], 1);
        }
    }
}

__global__ __launch_bounds__(256) void gemm_l2(
    const unsigned short* __restrict__ H,
    const unsigned short* __restrict__ WB2, const float* __restrict__ BP2,
    unsigned short* __restrict__ KV2, float* __restrict__ QR2) {
    __shared__ unsigned short sbuf[4 * 16 * LDSS];
    int b = blockIdx.x;
    if (b < KV2B) dev_gemm_bf16out<16>(H, WB2, BP2, KV2, N1, b, sbuf);
    else dev_gemm_f32out<12>(H, WB2 + 256 * 128, BP2 + 256, QR2, N2, b - KV2B);
}

// ---------------------------------------------------------------------------
// csr_scan: block sums -> (ticket) last block scans -> all blocks (spin,
// co-resident: 236 blocks) compute rowptr and re-zero cursors. One dispatch.
// ---------------------------------------------------------------------------
__global__ __launch_bounds__(256) void csr_scan(
    int* __restrict__ cnt1, int* __restrict__ bs1, int* __restrict__ rp1,
    int* __restrict__ cnt2, int* __restrict__ bs2, int* __restrict__ rp2,
    int* __restrict__ done) {
    __shared__ int s[256];
    __shared__ int amlast;
    int b = blockIdx.x;
    int* cnt; int* bs; int* rp; int n, lb;
    if (b < NB1) { cnt = cnt1; bs = bs1; rp = rp1; n = N1; lb = b; }
    else { cnt = cnt2; bs = bs2; rp = rp2; n = N2; lb = b - NB1; }
    int t = lb * 256 + threadIdx.x;
    int v = (t < n) ? cnt[t] : 0;
    s[threadIdx.x] = v;
    __syncthreads();
    for (int off = 128; off; off >>= 1) {
        if (threadIdx.x < off) s[threadIdx.x] += s[threadIdx.x + off];
        __syncthreads();
    }
    if (threadIdx.x == 0) {
        atomicExch(&bs[lb], s[0]);
        __threadfence();
        int prev = atomicAdd(&done[0], 1);
        amlast = (prev == NB1 + NB2 - 1) ? 1 : 0;
    }
    __syncthreads();
    if (amlast) {
        int tt = threadIdx.x;
        int v1 = (tt < NB1) ? atomicAdd(&bs1[tt], 0) : 0;
        s[tt] = v1;
        __syncthreads();
        for (int off = 1; off < 256; off <<= 1) {
            int u = (tt >= off) ? s[tt - off] : 0;
            __syncthreads();
            s[tt] += u;
            __syncthreads();
        }
        if (tt < NB1) atomicExch(&bs1[tt], s[tt] - v1);
        __syncthreads();
        int v2 = (tt < NB2) ? atomicAdd(&bs2[tt], 0) : 0;
        s[tt] = v2;
        __syncthreads();
        for (int off = 1; off < 256; off <<= 1) {
            int u = (tt >= off) ? s[tt - off] : 0;
            __syncthreads();
            s[tt] += u;
            __syncthreads();
        }
        if (tt < NB2) atomicExch(&bs2[tt], s[tt] - v2);
        __threadfence();
        __syncthreads();
        if (tt == 0) atomicExch(&done[1], 1);
    }
    // all blocks wait for the scan (co-resident => no deadlock)
    if (threadIdx.x == 0) {
        while (atomicAdd(&done[1], 0) == 0) __builtin_amdgcn_s_sleep(1);
    }
    __syncthreads();
    __threadfence();
    int base = atomicAdd(&bs[lb], 0);
    s[threadIdx.x] = v;
    __syncthreads();
    for (int off = 1; off < 256; off <<= 1) {
        int u = (threadIdx.x >= off) ? s[threadIdx.x - off] : 0;
        __syncthreads();
        s[threadIdx.x] += u;
        __syncthreads();
    }
    int incl = s[threadIdx.x];
    if (t < n) { rp[t] = base + incl - v; cnt[t] = 0; }
    if (t == n - 1) rp[n] = base + incl;
}

// ---------------------------------------------------------------------------
// fill_both: scatter PACKED edge data {src, et|ets<<16} into CSR slots
// ---------------------------------------------------------------------------
__global__ __launch_bounds__(256) void fill_both(
    const int* __restrict__ d1, const int* __restrict__ s1,
    const int* __restrict__ et1, const int* __restrict__ ets1,
    const int* __restrict__ rp1, int* __restrict__ cur1, uint2* __restrict__ ed1,
    const int* __restrict__ d2, const int* __restrict__ s2,
    const int* __restrict__ et2, const int* __restrict__ ets2,
    const int* __restrict__ rp2, int* __restrict__ cur2, uint2* __restrict__ ed2) {
    int t = blockIdx.x * 256 + threadIdx.x;
    if (t < E1C) {
        int d = d1[t];
        int pos = rp1[d] + atomicAdd(&cur1[d], 1);
        ed1[pos] = make_uint2((unsigned)s1[t],
                              (unsigned)(et1[t] | (ets1[t] << 16)));
    } else {
        t -= E1C;
        if (t < E2C) {
            int d = d2[t];
            int pos = rp2[d] + atomicAdd(&cur2[d], 1);
            ed2[pos] = make_uint2((unsigned)s2[t],
                                  (unsigned)(et2[t] | (ets2[t] << 16)));
        }
    }
}

// ---------------------------------------------------------------------------
// Fused aggregation: packed edge stream + prefetch + DPP reductions.
// Wave layout: s=lane>>5 (edge parity), h=(lane>>4)&1, cg=lane&15.
// ---------------------------------------------------------------------------
__global__ __launch_bounds__(256) void agg_layer1(
    const int* __restrict__ rowptr, const uint2* __restrict__ ED,
    const float* __restrict__ TA, const float* __restrict__ TB,
    const float* __restrict__ QR, const unsigned short* __restrict__ KV,
    const float* __restrict__ Wbeta,
    const float* __restrict__ ln_g, const float* __restrict__ ln_b,
    unsigned short* __restrict__ hout, int n) {
    int wid = (blockIdx.x * blockDim.x + threadIdx.x) >> 6;
    int lane = threadIdx.x & 63;
    if (wid >= n) return;
    int s = lane >> 5, cg = lane & 15;
    int co = ((lane >> 4) & 1) * 64 + 4 * cg;
    int beg = rowptr[wid], end = rowptr[wid + 1];
    float4 q4 = *(const float4*)(QR + (size_t)wid * 256 + co);
    float ax = 0.f, ay = 0.f, az = 0.f, aw = 0.f, suma = 0.f;
    int p = beg + s;
    if (p < end) {
        uint2 d0 = ED[p];
        int p1 = p + 2;
        bool m1 = p1 < end;
        uint2 dn = ED[m1 ? p1 : beg];
        int sn0 = (int)d0.x, t0 = (int)(d0.y & 0xFFFF), ts0 = (int)(d0.y >> 16);
        float4 ta0 = *(const float4*)(TA + t0 * 128 + co);
        float4 tb0 = *(const float4*)(TB + ts0 * 128 + co);
        const unsigned short* kv0 = KV + (size_t)sn0 * 256;
        ushort4 ku0 = *(const ushort4*)(kv0 + co);
        ushort4 vu0 = *(const ushort4*)(kv0 + 128 + co);
        for (;;) {
            // prefetch packed data for p+4
            int p2 = p1 + 2;
            bool m2 = p2 < end;
            uint2 dnn = ED[m2 ? p2 : beg];
            // prefetch vectors for p+2
            int sn1 = (int)dn.x, t1 = (int)(dn.y & 0xFFFF), ts1 = (int)(dn.y >> 16);
            float4 ta1 = *(const float4*)(TA + t1 * 128 + co);
            float4 tb1 = *(const float4*)(TB + ts1 * 128 + co);
            const unsigned short* kv1 = KV + (size_t)sn1 * 256;
            ushort4 ku1 = *(const ushort4*)(kv1 + co);
            ushort4 vu1 = *(const ushort4*)(kv1 + 128 + co);
            // compute current edge
            float e0c = ta0.x + tb0.x, e1c = ta0.y + tb0.y;
            float e2c = ta0.z + tb0.z, e3c = ta0.w + tb0.w;
            float pp = q4.x * (b2f(ku0.x) + e0c) + q4.y * (b2f(ku0.y) + e1c)
                     + q4.z * (b2f(ku0.z) + e2c) + q4.w * (b2f(ku0.w) + e3c);
            pp = red16(pp);
            float a = __expf(pp * 0.125f);
            ax += a * (b2f(vu0.x) + e0c); ay += a * (b2f(vu0.y) + e1c);
            az += a * (b2f(vu0.z) + e2c); aw += a * (b2f(vu0.w) + e3c);
            suma += a;
            if (!m1) break;
            p1 = p2; m1 = m2; dn = dnn;
            ta0 = ta1; tb0 = tb1; ku0 = ku1; vu0 = vu1;
        }
    }
    // merge edge-parity subwaves
    ax += __shfl_xor(ax, 32); ay += __shfl_xor(ay, 32);
    az += __shfl_xor(az, 32); aw += __shfl_xor(aw, 32);
    suma += __shfl_xor(suma, 32);
    float inv_s = 1.f / (suma + 1e-16f);
    float ox = ax * inv_s, oy = ay * inv_s, oz = az * inv_s, ow = aw * inv_s;
    float4 r4 = *(const float4*)(QR + (size_t)wid * 256 + 128 + co);
    float4 wo = *(const float4*)(Wbeta + co);
    float4 wr = *(const float4*)(Wbeta + 128 + co);
    float4 wd = *(const float4*)(Wbeta + 256 + co);
    float pb = wo.x * ox + wr.x * r4.x + wd.x * (ox - r4.x)
             + wo.y * oy + wr.y * r4.y + wd.y * (oy - r4.y)
             + wo.z * oz + wr.z * r4.z + wd.z * (oz - r4.z)
             + wo.w * ow + wr.w * r4.w + wd.w * (ow - r4.w);
    pb = red16(pb);
    pb += __shfl_xor(pb, 16);
    float beta = 1.f / (1.f + __expf(-pb));
    float gx = beta * r4.x + (1.f - beta) * ox;
    float gy = beta * r4.y + (1.f - beta) * oy;
    float gz = beta * r4.z + (1.f - beta) * oz;
    float gw = beta * r4.w + (1.f - beta) * ow;
    float sm = gx + gy + gz + gw;
    float sq = gx * gx + gy * gy + gz * gz + gw * gw;
    sm = red16(sm); sm += __shfl_xor(sm, 16);
    sq = red16(sq); sq += __shfl_xor(sq, 16);
    float mu = sm * (1.f / 128.f);
    float var = sq * (1.f / 128.f) - mu * mu;
    float inv = rsqrtf(var + 1e-5f);
    float4 lg = *(const float4*)(ln_g + co);
    float4 lb = *(const float4*)(ln_b + co);
    float yx = (gx - mu) * inv * lg.x + lb.x;
    float yy = (gy - mu) * inv * lg.y + lb.y;
    float yz = (gz - mu) * inv * lg.z + lb.z;
    float yw = (gw - mu) * inv * lg.w + lb.w;
    const float ISQ2 = 0.70710678118654752f;
    yx = 0.5f * yx * (1.f + erff(yx * ISQ2));
    yy = 0.5f * yy * (1.f + erff(yy * ISQ2));
    yz = 0.5f * yz * (1.f + erff(yz * ISQ2));
    yw = 0.5f * yw * (1.f + erff(yw * ISQ2));
    if (s == 0) {
        ushort4 hv;
        hv.x = f2b(yx); hv.y = f2b(yy); hv.z = f2b(yz); hv.w = f2b(yw);
        *(ushort4*)(hout + (size_t)wid * 128 + co) = hv;
    }
}

__global__ __launch_bounds__(256) void agg_layer2(
    const int* __restrict__ rowptr, const uint2* __restrict__ ED,
    const float* __restrict__ TA, const float* __restrict__ TB,
    const float* __restrict__ QR, const unsigned short* __restrict__ KV,
    const float* __restrict__ Wbeta,
    float* __restrict__ o, int n) {
    int wid = (blockIdx.x * blockDim.x + threadIdx.x) >> 6;
    int lane = threadIdx.x & 63;
    if (wid >= n) return;
    int s = lane >> 5, cg = lane & 15;
    int co = ((lane >> 4) & 1) * 64 + 4 * cg;
    int beg = rowptr[wid], end = rowptr[wid + 1];
    float4 q4 = *(const float4*)(QR + (size_t)wid * 192 + co);
    float ax = 0.f, ay = 0.f, az = 0.f, aw = 0.f, suma = 0.f;
    int p = beg + s;
    if (p < end) {
        uint2 d0 = ED[p];
        int p1 = p + 2;
        bool m1 = p1 < end;
        uint2 dn = ED[m1 ? p1 : beg];
        int sn0 = (int)d0.x, t0 = (int)(d0.y & 0xFFFF), ts0 = (int)(d0.y >> 16);
        float4 ta0 = *(const float4*)(TA + t0 * 128 + co);
        float4 tb0 = *(const float4*)(TB + ts0 * 128 + co);
        const unsigned short* kv0 = KV + (size_t)sn0 * 256;
        ushort4 ku0 = *(const ushort4*)(kv0 + co);
        ushort4 vu0 = *(const ushort4*)(kv0 + 128 + co);
        for (;;) {
            int p2 = p1 + 2;
            bool m2 = p2 < end;
            uint2 dnn = ED[m2 ? p2 : beg];
            int sn1 = (int)dn.x, t1 = (int)(dn.y & 0xFFFF), ts1 = (int)(dn.y >> 16);
            float4 ta1 = *(const float4*)(TA + t1 * 128 + co);
            float4 tb1 = *(const float4*)(TB + ts1 * 128 + co);
            const unsigned short* kv1 = KV + (size_t)sn1 * 256;
            ushort4 ku1 = *(const ushort4*)(kv1 + co);
            ushort4 vu1 = *(const ushort4*)(kv1 + 128 + co);
            float e0c = ta0.x + tb0.x, e1c = ta0.y + tb0.y;
            float e2c = ta0.z + tb0.z, e3c = ta0.w + tb0.w;
            float pp = q4.x * (b2f(ku0.x) + e0c) + q4.y * (b2f(ku0.y) + e1c)
                     + q4.z * (b2f(ku0.z) + e2c) + q4.w * (b2f(ku0.w) + e3c);
            pp = red16(pp);
            float a = __expf(pp * 0.125f);
            ax += a * (b2f(vu0.x) + e0c); ay += a * (b2f(vu0.y) + e1c);
            az += a * (b2f(vu0.z) + e2c); aw += a * (b2f(vu0.w) + e3c);
            suma += a;
            if (!m1) break;
            p1 = p2; m1 = m2; dn = dnn;
            ta0 = ta1; tb0 = tb1; ku0 = ku1; vu0 = vu1;
        }
    }
    ax += __shfl_xor(ax, 32); ay += __shfl_xor(ay, 32);
    az += __shfl_xor(az, 32); aw += __shfl_xor(aw, 32);
    suma += __shfl_xor(suma, 32);
    float inv_s = 1.f / (suma + 1e-16f);
    float ox = ax * inv_s, oy = ay * inv_s, oz = az * inv_s, ow = aw * inv_s;
    ox = 0.5f * (ox + __shfl_xor(ox, 16));
    oy = 0.5f * (oy + __shfl_xor(oy, 16));
    oz = 0.5f * (oz + __shfl_xor(oz, 16));
    ow = 0.5f * (ow + __shfl_xor(ow, 16));
    float4 r4 = *(const float4*)(QR + (size_t)wid * 192 + 128 + 4 * cg);
    float4 wo = *(const float4*)(Wbeta + 4 * cg);
    float4 wr = *(const float4*)(Wbeta + 64 + 4 * cg);
    float4 wd = *(const float4*)(Wbeta + 128 + 4 * cg);
    float pb = wo.x * ox + wr.x * r4.x + wd.x * (ox - r4.x)
             + wo.y * oy + wr.y * r4.y + wd.y * (oy - r4.y)
             + wo.z * oz + wr.z * r4.z + wd.z * (oz - r4.z)
             + wo.w * ow + wr.w * r4.w + wd.w * (ow - r4.w);
    pb = red16(pb);
    float beta = 1.f / (1.f + __expf(-pb));
    float vx = beta * r4.x + (1.f - beta) * ox;
    float vy = beta * r4.y + (1.f - beta) * oy;
    float vz = beta * r4.z + (1.f - beta) * oz;
    float vw = beta * r4.w + (1.f - beta) * ow;
    float m = fmaxf(fmaxf(vx, vy), fmaxf(vz, vw));
    m = red16max(m);
    float se = __expf(vx - m) + __expf(vy - m) + __expf(vz - m) + __expf(vw - m);
    se = red16(se);
    float lse = m + logf(se);
    if (lane < 16)
        *(float4*)(o + (size_t)wid * 64 + 4 * cg) =
            make_float4(vx - lse, vy - lse, vz - lse, vw - lse);
}

extern "C" void kernel_launch(void* const* d_in, const int* in_sizes, int n_in,
                              void* d_out, int out_size, void* d_ws, size_t ws_size,
                              hipStream_t stream) {
    const float* x        = (const float*)d_in[0];
    const int*   ei1_src  = (const int*)d_in[1];
    const int*   ei1_dst  = (const int*)d_in[2];
    const int*   et1      = (const int*)d_in[3];
    const int*   ets1     = (const int*)d_in[4];
    const int*   ei2_src  = (const int*)d_in[5];
    const int*   ei2_dst  = (const int*)d_in[6];
    const int*   et2      = (const int*)d_in[7];
    const int*   ets2     = (const int*)d_in[8];
    const float* edge_W   = (const float*)d_in[9];
    const float* edge_b   = (const float*)d_in[10];
    const float* time_W   = (const float*)d_in[11];
    const float* time_b   = (const float*)d_in[12];
    const float* Wq1      = (const float*)d_in[13];
    const float* bq1      = (const float*)d_in[14];
    const float* Wk1      = (const float*)d_in[15];
    const float* bk1      = (const float*)d_in[16];
    const float* Wv1      = (const float*)d_in[17];
    const float* bv1      = (const float*)d_in[18];
    const float* We1      = (const float*)d_in[19];
    const float* Wskip1   = (const float*)d_in[20];
    const float* bskip1   = (const float*)d_in[21];
    const float* Wbeta1   = (const float*)d_in[22];
    const float* ln_g     = (const float*)d_in[23];
    const float* ln_b     = (const float*)d_in[24];
    const float* Wq2      = (const float*)d_in[25];
    const float* bq2      = (const float*)d_in[26];
    const float* Wk2      = (const float*)d_in[27];
    const float* bk2      = (const float*)d_in[28];
    const float* Wv2      = (const float*)d_in[29];
    const float* bv2      = (const float*)d_in[30];
    const float* We2      = (const float*)d_in[31];
    const float* Wskip2   = (const float*)d_in[32];
    const float* bskip2   = (const float*)d_in[33];
    const float* Wbeta2   = (const float*)d_in[34];

    float* ws = (float*)d_ws;
    unsigned short* xb  = (unsigned short*)(ws + OFF_XB);
    float* qr1          = ws + OFF_QR1;
    unsigned short* kv1 = (unsigned short*)(ws + OFF_KV1);
    unsigned short* h   = (unsigned short*)(ws + OFF_H);
    float* qr2          = ws + OFF_QR2;
    unsigned short* kv2 = (unsigned short*)(ws + OFF_KV2);
    unsigned short* wb1 = (unsigned short*)(ws + OFF_WB1);
    float* bp1          = ws + OFF_BP1;
    unsigned short* wb2 = (unsigned short*)(ws + OFF_WB2);
    float* bp2          = ws + OFF_BP2;
    float* ta1          = ws + OFF_TA1;
    float* tb1          = ws + OFF_TB1;
    float* ta2          = ws + OFF_TA2;
    float* tb2          = ws + OFF_TB2;
    int*   rp1          = (int*)(ws + OFF_RP1);
    int*   cur1         = (int*)(ws + OFF_CUR1);
    uint2* ed1          = (uint2*)(ws + OFF_ED1);
    int*   bs1          = (int*)(ws + OFF_BS1);
    int*   rp2          = (int*)(ws + OFF_RP2);
    int*   cur2         = (int*)(ws + OFF_CUR2);
    uint2* ed2          = (uint2*)(ws + OFF_ED2);
    int*   bs2          = (int*)(ws + OFF_BS2);
    int*   done         = (int*)(ws + OFF_DONE);

    prep<<<2048, 256, 0, stream>>>(
        x, xb,
        Wk1, Wv1, Wq1, Wskip1, bk1, bv1, bq1, bskip1,
        Wk2, Wv2, Wq2, Wskip2, bk2, bv2, bq2, bskip2,
        wb1, bp1, wb2, bp2,
        edge_W, edge_b, time_W, time_b, We1, We2,
        ta1, tb1, ta2, tb2, cur1, cur2, done);
    mega_l1<<<KV1B + QR1B + CNTB, 256, 0, stream>>>(
        xb, wb1, bp1, kv1, qr1, ei1_dst, ei2_dst, cur1, cur2);
    csr_scan<<<NB1 + NB2, 256, 0, stream>>>(cur1, bs1, rp1, cur2, bs2, rp2, done);
    fill_both<<<FILLB, 256, 0, stream>>>(
        ei1_dst, ei1_src, et1, ets1, rp1, cur1, ed1,
        ei2_dst, ei2_src, et2, ets2, rp2, cur2, ed2);
    agg_layer1<<<(N1 + 3) / 4, 256, 0, stream>>>(rp1, ed1,
        ta1, tb1, qr1, kv1, Wbeta1, ln_g, ln_b, h, N1);
    gemm_l2<<<KV2B + QR2B, 256, 0, stream>>>(h, wb2, bp2, kv2, qr2);
    agg_layer2<<<(N2 + 3) / 4, 256, 0, stream>>>(rp2, ed2,
        ta2, tb2, qr2, kv2, Wbeta2, (float*)d_out, N2);
}